// Round 1
// baseline (2281.282 us; speedup 1.0000x reference)
//
#include <hip/hip_runtime.h>
#include <math.h>

#define NEG_INF -3.402823466e38f

// ---------------- GEMM: C = A(Mx512) @ B(512x512) + bias ----------------
__global__ __launch_bounds__(256) void gemm_bias_512(
    const float* __restrict__ A, const float* __restrict__ B,
    const float* __restrict__ bias, float* __restrict__ C, int M)
{
  const int K = 512, N = 512;
  __shared__ float As[16][68];
  __shared__ float Bs[16][68];
  int bm = blockIdx.x * 64, bn = blockIdx.y * 64;
  int tid = threadIdx.x;
  int tx = tid & 15, ty = tid >> 4;
  int ar = tid >> 2, ak = (tid & 3) << 2;    // A tile: 64 rows x 16 k
  int bk = tid >> 4, bn4 = (tid & 15) << 2;  // B tile: 16 k x 64 cols
  float acc[4][4] = {};
  for (int kt = 0; kt < K; kt += 16) {
    float4 av = *(const float4*)&A[(bm + ar) * K + kt + ak];
    float4 bv = *(const float4*)&B[(kt + bk) * N + bn + bn4];
    As[ak + 0][ar] = av.x; As[ak + 1][ar] = av.y;
    As[ak + 2][ar] = av.z; As[ak + 3][ar] = av.w;
    *(float4*)&Bs[bk][bn4] = bv;
    __syncthreads();
#pragma unroll
    for (int kk = 0; kk < 16; ++kk) {
      float a[4], b[4];
#pragma unroll
      for (int u = 0; u < 4; ++u) { a[u] = As[kk][ty * 4 + u]; b[u] = Bs[kk][tx * 4 + u]; }
#pragma unroll
      for (int u = 0; u < 4; ++u)
#pragma unroll
        for (int v = 0; v < 4; ++v) acc[u][v] += a[u] * b[v];
    }
    __syncthreads();
  }
#pragma unroll
  for (int u = 0; u < 4; ++u)
#pragma unroll
    for (int v = 0; v < 4; ++v)
      C[(bm + ty * 4 + u) * N + bn + tx * 4 + v] = acc[u][v] + bias[bn + tx * 4 + v];
}

// ---------------- BN stats: per-block partial column sums ----------------
__global__ __launch_bounds__(256) void bn_partial(
    const float* __restrict__ Y, float* __restrict__ partial, int rowsPerBlock)
{
  int b = blockIdx.x, t = threadIdx.x;
  int r0 = b * rowsPerBlock;
  float s0 = 0, q0 = 0, s1 = 0, q1 = 0;
  for (int r = 0; r < rowsPerBlock; ++r) {
    float v0 = Y[(r0 + r) * 512 + t];
    float v1 = Y[(r0 + r) * 512 + t + 256];
    s0 += v0; q0 += v0 * v0; s1 += v1; q1 += v1 * v1;
  }
  partial[b * 1024 + t] = s0;
  partial[b * 1024 + t + 256] = s1;
  partial[b * 1024 + 512 + t] = q0;
  partial[b * 1024 + 512 + t + 256] = q1;
}

__global__ void bn_finalize(
    const float* __restrict__ partial, const float* __restrict__ g,
    const float* __restrict__ beta, float* __restrict__ scale,
    float* __restrict__ shift, int nblk, int rows)
{
  int c = blockIdx.x * blockDim.x + threadIdx.x;
  if (c >= 512) return;
  float s = 0, s2 = 0;
  for (int b = 0; b < nblk; ++b) {
    s += partial[b * 1024 + c];
    s2 += partial[b * 1024 + 512 + c];
  }
  float m = s / rows;
  float v = s2 / rows - m * m;
  if (v < 0) v = 0;
  float sc = g[c] / sqrtf(v + 1e-5f);
  scale[c] = sc;
  shift[c] = beta[c] - m * sc;
}

__global__ void bn_swish(
    const float* __restrict__ Y, const float* __restrict__ scale,
    const float* __restrict__ shift, float* __restrict__ H, int total4)
{
  int i = blockIdx.x * blockDim.x + threadIdx.x;
  if (i >= total4) return;
  float4 y = ((const float4*)Y)[i];
  int c = (i * 4) & 511;
  float z;
  float4 o;
  z = y.x * scale[c + 0] + shift[c + 0]; o.x = z / (1.f + expf(-z));
  z = y.y * scale[c + 1] + shift[c + 1]; o.y = z / (1.f + expf(-z));
  z = y.z * scale[c + 2] + shift[c + 2]; o.z = z / (1.f + expf(-z));
  z = y.w * scale[c + 3] + shift[c + 3]; o.w = z / (1.f + expf(-z));
  ((float4*)H)[i] = o;
}

// ---------------- ordered compaction of positive labels ----------------
__global__ void compact_pos(const int* __restrict__ lbl, int n,
                            int* __restrict__ pos, int P)
{
  __shared__ int base;
  __shared__ int wsum[4];
  int tid = threadIdx.x;
  for (int t = tid; t < P; t += 256) pos[t] = 0;  // jnp.nonzero pads with 0
  if (tid == 0) base = 0;
  __syncthreads();
  for (int start = 0; start < n; start += 256) {
    int i = start + tid;
    int pred = (i < n) && (lbl[i] > 0);
    unsigned long long m = __ballot(pred);
    int wid = tid >> 6, lane = tid & 63;
    if (lane == 0) wsum[wid] = __popcll(m);
    __syncthreads();
    int wbase = 0;
    for (int w = 0; w < wid; ++w) wbase += wsum[w];
    int rank = base + wbase + __popcll(m & ((1ull << lane) - 1ull));
    if (pred && rank < P) pos[rank] = i;
    __syncthreads();
    if (tid == 0) base += wsum[0] + wsum[1] + wsum[2] + wsum[3];
    __syncthreads();
  }
}

// ---------------- gather positives + row squared norms ----------------
__global__ void gather_sq(const float* __restrict__ H, const int* __restrict__ pos,
                          float* __restrict__ X, float* __restrict__ sq)
{
  int r = blockIdx.x, t = threadIdx.x;  // 128 threads
  int src = pos[r];
  float4 v = *(const float4*)&H[src * 512 + t * 4];
  *(float4*)&X[r * 512 + t * 4] = v;
  float s = v.x * v.x + v.y * v.y + v.z * v.z + v.w * v.w;
#pragma unroll
  for (int off = 32; off > 0; off >>= 1) s += __shfl_down(s, off);
  __shared__ float red[2];
  if ((t & 63) == 0) red[t >> 6] = s;
  __syncthreads();
  if (t == 0) sq[r] = red[0] + red[1];
}

// ---------------- fused Gram + running top-3 (j-split across blocks) ----
__global__ __launch_bounds__(256) void gram_topk(
    const float* __restrict__ X, const float* __restrict__ sq, int P,
    float* __restrict__ ptv, int* __restrict__ pti)
{
  const int K = 512;
  __shared__ float As[16][68];
  __shared__ float Bs[16][68];
  __shared__ float dist[64][65];
  __shared__ float sqi[64], sqj[64];
  int bi = blockIdx.x * 64;
  int nsplit = gridDim.y;
  int jchunk = P / nsplit;
  int jlo = blockIdx.y * jchunk, jhi = jlo + jchunk;
  int tid = threadIdx.x;
  int tx = tid & 15, ty = tid >> 4;
  int ar = tid >> 2, ak = (tid & 3) << 2;
  if (tid < 64) sqi[tid] = sq[bi + tid];
  float t0 = NEG_INF, t1 = NEG_INF, t2 = NEG_INF;
  int j0i = 0x7fffffff, j1i = 0x7fffffff, j2i = 0x7fffffff;
  for (int j0 = jlo; j0 < jhi; j0 += 64) {
    if (tid < 64) sqj[tid] = sq[j0 + tid];
    float acc[4][4] = {};
    for (int kt = 0; kt < K; kt += 16) {
      float4 av = *(const float4*)&X[(bi + ar) * K + kt + ak];
      float4 bv = *(const float4*)&X[(j0 + ar) * K + kt + ak];
      As[ak + 0][ar] = av.x; As[ak + 1][ar] = av.y;
      As[ak + 2][ar] = av.z; As[ak + 3][ar] = av.w;
      Bs[ak + 0][ar] = bv.x; Bs[ak + 1][ar] = bv.y;
      Bs[ak + 2][ar] = bv.z; Bs[ak + 3][ar] = bv.w;
      __syncthreads();
#pragma unroll
      for (int kk = 0; kk < 16; ++kk) {
        float a[4], b[4];
#pragma unroll
        for (int u = 0; u < 4; ++u) { a[u] = As[kk][ty * 4 + u]; b[u] = Bs[kk][tx * 4 + u]; }
#pragma unroll
        for (int u = 0; u < 4; ++u)
#pragma unroll
          for (int v = 0; v < 4; ++v) acc[u][v] += a[u] * b[v];
      }
      __syncthreads();
    }
#pragma unroll
    for (int u = 0; u < 4; ++u)
#pragma unroll
      for (int v = 0; v < 4; ++v)
        dist[ty * 4 + u][tx * 4 + v] = 2.0f * acc[u][v] - sqi[ty * 4 + u] - sqj[tx * 4 + v];
    __syncthreads();
    if (tid < 64) {
      for (int jj = 0; jj < 64; ++jj) {
        float v = dist[tid][jj];
        int j = j0 + jj;
        if (v > t0)      { t2 = t1; j2i = j1i; t1 = t0; j1i = j0i; t0 = v; j0i = j; }
        else if (v > t1) { t2 = t1; j2i = j1i; t1 = v; j1i = j; }
        else if (v > t2) { t2 = v; j2i = j; }
      }
    }
    __syncthreads();
  }
  if (tid < 64) {
    int i = bi + tid;
    int base = (i * nsplit + blockIdx.y) * 3;
    ptv[base + 0] = t0; ptv[base + 1] = t1; ptv[base + 2] = t2;
    pti[base + 0] = j0i; pti[base + 1] = j1i; pti[base + 2] = j2i;
  }
}

__global__ void merge_topk(const float* __restrict__ ptv, const int* __restrict__ pti,
                           int* __restrict__ idx3, int P, int nsplit)
{
  int i = blockIdx.x * blockDim.x + threadIdx.x;
  if (i >= P) return;
  float v[12]; int jx[12];
  int n = nsplit * 3;
  for (int t = 0; t < n; ++t) { v[t] = ptv[i * n + t]; jx[t] = pti[i * n + t]; }
  for (int k = 0; k < 3; ++k) {
    int bt = 0;
    for (int t = 1; t < n; ++t)
      if (v[t] > v[bt] || (v[t] == v[bt] && (unsigned)jx[t] < (unsigned)jx[bt])) bt = t;
    idx3[i * 3 + k] = jx[bt];
    v[bt] = NEG_INF; jx[bt] = 0x7fffffff;
  }
}

// ---------------- SMOTE lerp rows ----------------
__global__ void make_newfea(const float* __restrict__ X, const int* __restrict__ idx3,
                            const float* __restrict__ lw, float* __restrict__ out)
{
  int r = blockIdx.x;           // 0..3P-1
  int i = r / 3, k = r - i * 3;
  int ai = idx3[i * 3 + 0];
  int bi = idx3[i * 3 + k];
  float w = lw[r];
  int t = threadIdx.x;          // 128 threads
  float4 av = *(const float4*)&X[ai * 512 + t * 4];
  float4 bv = *(const float4*)&X[bi * 512 + t * 4];
  float4 o;
  o.x = av.x + w * (bv.x - av.x);
  o.y = av.y + w * (bv.y - av.y);
  o.z = av.z + w * (bv.z - av.z);
  o.w = av.w + w * (bv.w - av.w);
  *(float4*)&out[(size_t)r * 512 + t * 4] = o;
}

__global__ void write_lbl(const int* __restrict__ lbl, float* __restrict__ out,
                          int n_in, int n_total)
{
  int i = blockIdx.x * blockDim.x + threadIdx.x;
  if (i < n_total) out[i] = (i < n_in) ? (float)lbl[i] : 1.0f;
}

// ---------------- launch ----------------
extern "C" void kernel_launch(void* const* d_in, const int* in_sizes, int n_in,
                              void* d_out, int out_size, void* d_ws, size_t ws_size,
                              hipStream_t stream)
{
  const float* fea   = (const float*)d_in[0];
  const int*   lbl   = (const int*)d_in[1];
  const float* W1    = (const float*)d_in[2];
  const float* b1    = (const float*)d_in[3];
  const float* g1    = (const float*)d_in[4];
  const float* beta1 = (const float*)d_in[5];
  const float* W2    = (const float*)d_in[6];
  const float* b2    = (const float*)d_in[7];
  const float* g2    = (const float*)d_in[8];
  const float* beta2 = (const float*)d_in[9];
  const float* lerp_w = (const float*)d_in[10];

  int bs = in_sizes[0] / 512;       // 32768
  int P  = in_sizes[10] / 3;        // 8192
  int n_total = bs + 3 * P;         // 57344

  float* out_f = (float*)d_out;
  float* Hout  = out_f;                         // h lives in d_out[0 : bs*512]
  float* newfea = out_f + (size_t)bs * 512;
  float* lbl_out = out_f + (size_t)n_total * 512;

  float* Y1      = (float*)d_ws;
  float* X       = Y1 + (size_t)bs * 512;
  float* partial = X + (size_t)P * 512;
  float* scale   = partial + 512 * 1024;
  float* shift   = scale + 512;
  float* sq      = shift + 512;
  int*   pos     = (int*)(sq + P);
  int*   idx3    = pos + P;
  float* ptv     = (float*)(idx3 + 3 * P);
  int*   pti     = (int*)(ptv + (size_t)P * 12);

  dim3 gemm_grid(bs / 64, 8);
  int nblk = bs / 64;  // rowsPerBlock = 64 -> 512 blocks

  // layer 1
  gemm_bias_512<<<gemm_grid, 256, 0, stream>>>(fea, W1, b1, Y1, bs);
  bn_partial<<<nblk, 256, 0, stream>>>(Y1, partial, 64);
  bn_finalize<<<2, 256, 0, stream>>>(partial, g1, beta1, scale, shift, nblk, bs);
  bn_swish<<<(bs * 512 / 4 + 255) / 256, 256, 0, stream>>>(Y1, scale, shift, Y1, bs * 512 / 4);
  // layer 2 (into d_out h-region)
  gemm_bias_512<<<gemm_grid, 256, 0, stream>>>(Y1, W2, b2, Hout, bs);
  bn_partial<<<nblk, 256, 0, stream>>>(Hout, partial, 64);
  bn_finalize<<<2, 256, 0, stream>>>(partial, g2, beta2, scale, shift, nblk, bs);
  bn_swish<<<(bs * 512 / 4 + 255) / 256, 256, 0, stream>>>(Hout, scale, shift, Hout, bs * 512 / 4);
  // SMOTE
  compact_pos<<<1, 256, 0, stream>>>(lbl, bs, pos, P);
  gather_sq<<<P, 128, 0, stream>>>(Hout, pos, X, sq);
  dim3 gram_grid(P / 64, 4);
  gram_topk<<<gram_grid, 256, 0, stream>>>(X, sq, P, ptv, pti);
  merge_topk<<<(P + 255) / 256, 256, 0, stream>>>(ptv, pti, idx3, P, 4);
  make_newfea<<<3 * P, 128, 0, stream>>>(X, idx3, lerp_w, newfea);
  write_lbl<<<(n_total + 255) / 256, 256, 0, stream>>>(lbl, lbl_out, bs, n_total);
}

// Round 2
// 1102.970 us; speedup vs baseline: 2.0683x; 2.0683x over previous
//
#include <hip/hip_runtime.h>
#include <math.h>

#define NEG_INF -3.402823466e38f
#define NSPLIT 8

typedef __attribute__((ext_vector_type(8))) short bf16x8;
typedef __attribute__((ext_vector_type(4))) float f32x4;

__device__ __forceinline__ void gload_lds16(const unsigned short* g, unsigned short* l) {
  __builtin_amdgcn_global_load_lds(
      (const __attribute__((address_space(1))) unsigned int*)g,
      (__attribute__((address_space(3))) unsigned int*)l, 16, 0, 0);
}

__device__ __forceinline__ unsigned short f2bf(float f) {
  union { float f; unsigned int u; } a; a.f = f;
  unsigned int u = a.u;
  return (unsigned short)((u + 0x7fffu + ((u >> 16) & 1u)) >> 16);
}

// ---------------- GEMM: C = A(Mx512) @ B(512x512) + bias ----------------
__global__ __launch_bounds__(256) void gemm_bias_512(
    const float* __restrict__ A, const float* __restrict__ B,
    const float* __restrict__ bias, float* __restrict__ C, int M)
{
  const int K = 512, N = 512;
  __shared__ float As[16][68];
  __shared__ float Bs[16][68];
  int bm = blockIdx.x * 64, bn = blockIdx.y * 64;
  int tid = threadIdx.x;
  int tx = tid & 15, ty = tid >> 4;
  int ar = tid >> 2, ak = (tid & 3) << 2;
  int bk = tid >> 4, bn4 = (tid & 15) << 2;
  float acc[4][4] = {};
  for (int kt = 0; kt < K; kt += 16) {
    float4 av = *(const float4*)&A[(bm + ar) * K + kt + ak];
    float4 bv = *(const float4*)&B[(kt + bk) * N + bn + bn4];
    As[ak + 0][ar] = av.x; As[ak + 1][ar] = av.y;
    As[ak + 2][ar] = av.z; As[ak + 3][ar] = av.w;
    *(float4*)&Bs[bk][bn4] = bv;
    __syncthreads();
#pragma unroll
    for (int kk = 0; kk < 16; ++kk) {
      float a[4], b[4];
#pragma unroll
      for (int u = 0; u < 4; ++u) { a[u] = As[kk][ty * 4 + u]; b[u] = Bs[kk][tx * 4 + u]; }
#pragma unroll
      for (int u = 0; u < 4; ++u)
#pragma unroll
        for (int v = 0; v < 4; ++v) acc[u][v] += a[u] * b[v];
    }
    __syncthreads();
  }
#pragma unroll
  for (int u = 0; u < 4; ++u)
#pragma unroll
    for (int v = 0; v < 4; ++v)
      C[(bm + ty * 4 + u) * N + bn + tx * 4 + v] = acc[u][v] + bias[bn + tx * 4 + v];
}

// ---------------- BN stats ----------------
__global__ __launch_bounds__(256) void bn_partial(
    const float* __restrict__ Y, float* __restrict__ partial, int rowsPerBlock)
{
  int b = blockIdx.x, t = threadIdx.x;
  int r0 = b * rowsPerBlock;
  float s0 = 0, q0 = 0, s1 = 0, q1 = 0;
  for (int r = 0; r < rowsPerBlock; ++r) {
    float v0 = Y[(r0 + r) * 512 + t];
    float v1 = Y[(r0 + r) * 512 + t + 256];
    s0 += v0; q0 += v0 * v0; s1 += v1; q1 += v1 * v1;
  }
  partial[b * 1024 + t] = s0;
  partial[b * 1024 + t + 256] = s1;
  partial[b * 1024 + 512 + t] = q0;
  partial[b * 1024 + 512 + t + 256] = q1;
}

__global__ void bn_finalize(
    const float* __restrict__ partial, const float* __restrict__ g,
    const float* __restrict__ beta, float* __restrict__ scale,
    float* __restrict__ shift, int nblk, int rows)
{
  int c = blockIdx.x * blockDim.x + threadIdx.x;
  if (c >= 512) return;
  float s = 0, s2 = 0;
  for (int b = 0; b < nblk; ++b) {
    s += partial[b * 1024 + c];
    s2 += partial[b * 1024 + 512 + c];
  }
  float m = s / rows;
  float v = s2 / rows - m * m;
  if (v < 0) v = 0;
  float sc = g[c] / sqrtf(v + 1e-5f);
  scale[c] = sc;
  shift[c] = beta[c] - m * sc;
}

__global__ void bn_swish(
    const float* __restrict__ Y, const float* __restrict__ scale,
    const float* __restrict__ shift, float* __restrict__ H, int total4)
{
  int i = blockIdx.x * blockDim.x + threadIdx.x;
  if (i >= total4) return;
  float4 y = ((const float4*)Y)[i];
  int c = (i * 4) & 511;
  float z;
  float4 o;
  z = y.x * scale[c + 0] + shift[c + 0]; o.x = z / (1.f + expf(-z));
  z = y.y * scale[c + 1] + shift[c + 1]; o.y = z / (1.f + expf(-z));
  z = y.z * scale[c + 2] + shift[c + 2]; o.z = z / (1.f + expf(-z));
  z = y.w * scale[c + 3] + shift[c + 3]; o.w = z / (1.f + expf(-z));
  ((float4*)H)[i] = o;
}

// ---------------- ordered compaction of positive labels ----------------
__global__ void compact_pos(const int* __restrict__ lbl, int n,
                            int* __restrict__ pos, int P)
{
  __shared__ int base;
  __shared__ int wsum[4];
  int tid = threadIdx.x;
  for (int t = tid; t < P; t += 256) pos[t] = 0;
  if (tid == 0) base = 0;
  __syncthreads();
  for (int start = 0; start < n; start += 256) {
    int i = start + tid;
    int pred = (i < n) && (lbl[i] > 0);
    unsigned long long m = __ballot(pred);
    int wid = tid >> 6, lane = tid & 63;
    if (lane == 0) wsum[wid] = __popcll(m);
    __syncthreads();
    int wbase = 0;
    for (int w = 0; w < wid; ++w) wbase += wsum[w];
    int rank = base + wbase + __popcll(m & ((1ull << lane) - 1ull));
    if (pred && rank < P) pos[rank] = i;
    __syncthreads();
    if (tid == 0) base += wsum[0] + wsum[1] + wsum[2] + wsum[3];
    __syncthreads();
  }
}

// ---------------- gather positives + sq norms + bf16 copy ----------------
__global__ void gather_sq(const float* __restrict__ H, const int* __restrict__ pos,
                          float* __restrict__ X, unsigned short* __restrict__ Xh,
                          float* __restrict__ sq)
{
  int r = blockIdx.x, t = threadIdx.x;  // 128 threads
  int src = pos[r];
  float4 v = *(const float4*)&H[src * 512 + t * 4];
  *(float4*)&X[r * 512 + t * 4] = v;
  ushort4 hv;
  hv.x = f2bf(v.x); hv.y = f2bf(v.y); hv.z = f2bf(v.z); hv.w = f2bf(v.w);
  *(ushort4*)&Xh[r * 512 + t * 4] = hv;
  float s = v.x * v.x + v.y * v.y + v.z * v.z + v.w * v.w;
#pragma unroll
  for (int off = 32; off > 0; off >>= 1) s += __shfl_down(s, off);
  __shared__ float red[2];
  if ((t & 63) == 0) red[t >> 6] = s;
  __syncthreads();
  if (t == 0) sq[r] = red[0] + red[1];
}

// ---------------- approx Gram (bf16 MFMA) + running top-8 ----------------
__global__ __launch_bounds__(256, 2) void gram8(
    const unsigned short* __restrict__ Xh, const float* __restrict__ sq, int P,
    float* __restrict__ p8v, int* __restrict__ p8j)
{
  __shared__ unsigned short Ah[128 * 64];   // [row][64 k] xor-swizzled rows of 128B
  __shared__ unsigned short Bh[128 * 64];
  __shared__ float dl[4][64][17];           // per-wave 64x16 dist slice, padded
  __shared__ float sqj_l[128];

  const int tid = threadIdx.x;
  const int w = tid >> 6, lane = tid & 63;
  const int wr = w >> 1, wc = w & 1;
  const int bi = blockIdx.x * 128;
  const int jchunk = P / NSPLIT;
  const int jlo = blockIdx.y * jchunk;

  const int srow = tid >> 3;           // staging row 0..31 (+32/iter)
  const int scb  = (tid & 7) << 4;     // staging byte-col within 128B row
  const int fr = lane & 15, fg = lane >> 4;

  float t[8]; int ji[8];
#pragma unroll
  for (int q = 0; q < 8; ++q) { t[q] = NEG_INF; ji[q] = 0x7fffffff; }

  for (int jt = 0; jt < jchunk; jt += 128) {
    const int j0 = jlo + jt;
    if (tid < 128) sqj_l[tid] = sq[j0 + tid];
    f32x4 acc[4][4];
#pragma unroll
    for (int mi = 0; mi < 4; ++mi)
#pragma unroll
      for (int ni = 0; ni < 4; ++ni) acc[mi][ni] = (f32x4){0.f, 0.f, 0.f, 0.f};

    for (int kt = 0; kt < 512; kt += 64) {
#pragma unroll
      for (int it = 0; it < 4; ++it) {
        int row = srow + it * 32;
        int cb = scb ^ ((row & 7) << 4);   // pre-swizzled source col (bytes)
        gload_lds16(&Xh[(size_t)(bi + row) * 512 + kt + (cb >> 1)],
                    &Ah[row * 64 + (scb >> 1)]);
        gload_lds16(&Xh[(size_t)(j0 + row) * 512 + kt + (cb >> 1)],
                    &Bh[row * 64 + (scb >> 1)]);
      }
      __syncthreads();   // drains vmcnt before reads
#pragma unroll
      for (int ks = 0; ks < 2; ++ks) {
        bf16x8 af[4], bfr[4];
        int kb = ks * 64 + fg * 16;   // byte col of this lane's 8 bf16
#pragma unroll
        for (int mi = 0; mi < 4; ++mi) {
          int row = wr * 64 + mi * 16 + fr;
          af[mi] = *(const bf16x8*)&Ah[row * 64 + ((kb ^ ((row & 7) << 4)) >> 1)];
        }
#pragma unroll
        for (int ni = 0; ni < 4; ++ni) {
          int row = wc * 64 + ni * 16 + fr;
          bfr[ni] = *(const bf16x8*)&Bh[row * 64 + ((kb ^ ((row & 7) << 4)) >> 1)];
        }
#pragma unroll
        for (int mi = 0; mi < 4; ++mi)
#pragma unroll
          for (int ni = 0; ni < 4; ++ni)
            acc[mi][ni] = __builtin_amdgcn_mfma_f32_16x16x32_bf16(
                af[mi], bfr[ni], acc[mi][ni], 0, 0, 0);
      }
      __syncthreads();
    }

    // top-8 scan, one ni-quarter (16 cols) at a time
#pragma unroll
    for (int qn = 0; qn < 4; ++qn) {
      float sqv = sqj_l[wc * 64 + qn * 16 + fr];
#pragma unroll
      for (int mi = 0; mi < 4; ++mi)
#pragma unroll
        for (int r = 0; r < 4; ++r)
          dl[w][mi * 16 + fg * 4 + r][fr] = 2.0f * acc[mi][qn][r] - sqv;
      __syncthreads();
      int jbase = j0 + wc * 64 + qn * 16;
      for (int c = 0; c < 16; ++c) {
        float v = dl[w][lane][c];
        if (v > t[7]) {
          t[7] = v; ji[7] = jbase + c;
#pragma unroll
          for (int q = 7; q > 0; --q) {
            if (t[q] > t[q - 1]) {
              float tv = t[q]; t[q] = t[q - 1]; t[q - 1] = tv;
              int tj = ji[q]; ji[q] = ji[q - 1]; ji[q - 1] = tj;
            }
          }
        }
      }
      __syncthreads();
    }
  }

  int row = bi + wr * 64 + lane;
  int set = blockIdx.y * 2 + wc;
  size_t base = ((size_t)row * (NSPLIT * 2) + set) * 8;
#pragma unroll
  for (int q = 0; q < 8; ++q) { p8v[base + q] = t[q]; p8j[base + q] = ji[q]; }
}

// ---------------- merge 16 sorted top-8 lists -> top-8 candidates ----------
__global__ void merge8(const float* __restrict__ p8v, const int* __restrict__ p8j,
                       int* __restrict__ cand, int P)
{
  int i = blockIdx.x * blockDim.x + threadIdx.x;
  if (i >= P) return;
  const int S = NSPLIT * 2;
  int head[S];
#pragma unroll
  for (int s = 0; s < S; ++s) head[s] = 0;
  const float* v = p8v + (size_t)i * S * 8;
  const int* j = p8j + (size_t)i * S * 8;
  for (int k = 0; k < 8; ++k) {
    float bv = NEG_INF; int bj = 0x7fffffff; int bs = 0;
#pragma unroll
    for (int s = 0; s < S; ++s) {
      if (head[s] < 8) {
        float vv = v[s * 8 + head[s]];
        int jj = j[s * 8 + head[s]];
        if (vv > bv || (vv == bv && jj < bj)) { bv = vv; bj = jj; bs = s; }
      }
    }
    head[bs]++;
    cand[i * 8 + k] = bj;
  }
}

// ---------------- exact fp32 rescore of 8 candidates -> top-3 --------------
__global__ __launch_bounds__(64) void rescore(
    const float* __restrict__ X, const float* __restrict__ sq,
    const int* __restrict__ cand, int* __restrict__ idx3)
{
  int i = blockIdx.x;
  int lane = threadIdx.x;
  f32x4 x0 = *(const f32x4*)&X[(size_t)i * 512 + lane * 8];
  f32x4 x1 = *(const f32x4*)&X[(size_t)i * 512 + lane * 8 + 4];
  float d[8]; int cj[8];
#pragma unroll
  for (int c = 0; c < 8; ++c) {
    int j = cand[i * 8 + c];
    cj[c] = j;
    f32x4 y0 = *(const f32x4*)&X[(size_t)j * 512 + lane * 8];
    f32x4 y1 = *(const f32x4*)&X[(size_t)j * 512 + lane * 8 + 4];
    float p = x0.x * y0.x + x0.y * y0.y + x0.z * y0.z + x0.w * y0.w
            + x1.x * y1.x + x1.y * y1.y + x1.z * y1.z + x1.w * y1.w;
#pragma unroll
    for (int off = 32; off > 0; off >>= 1) p += __shfl_xor(p, off);
    d[c] = 2.0f * p - sq[i] - sq[j];
  }
  if (lane == 0) {
    for (int k = 0; k < 3; ++k) {
      int b = 0;
#pragma unroll
      for (int c = 1; c < 8; ++c)
        if (d[c] > d[b] || (d[c] == d[b] && cj[c] < cj[b])) b = c;
      idx3[i * 3 + k] = cj[b];
      d[b] = NEG_INF; cj[b] = 0x7fffffff;
    }
  }
}

// ---------------- SMOTE lerp rows ----------------
__global__ void make_newfea(const float* __restrict__ X, const int* __restrict__ idx3,
                            const float* __restrict__ lw, float* __restrict__ out)
{
  int r = blockIdx.x;
  int i = r / 3, k = r - i * 3;
  int ai = idx3[i * 3 + 0];
  int bi = idx3[i * 3 + k];
  float w = lw[r];
  int t = threadIdx.x;
  float4 av = *(const float4*)&X[ai * 512 + t * 4];
  float4 bv = *(const float4*)&X[bi * 512 + t * 4];
  float4 o;
  o.x = av.x + w * (bv.x - av.x);
  o.y = av.y + w * (bv.y - av.y);
  o.z = av.z + w * (bv.z - av.z);
  o.w = av.w + w * (bv.w - av.w);
  *(float4*)&out[(size_t)r * 512 + t * 4] = o;
}

__global__ void write_lbl(const int* __restrict__ lbl, float* __restrict__ out,
                          int n_in, int n_total)
{
  int i = blockIdx.x * blockDim.x + threadIdx.x;
  if (i < n_total) out[i] = (i < n_in) ? (float)lbl[i] : 1.0f;
}

// ---------------- launch ----------------
extern "C" void kernel_launch(void* const* d_in, const int* in_sizes, int n_in,
                              void* d_out, int out_size, void* d_ws, size_t ws_size,
                              hipStream_t stream)
{
  const float* fea   = (const float*)d_in[0];
  const int*   lbl   = (const int*)d_in[1];
  const float* W1    = (const float*)d_in[2];
  const float* b1    = (const float*)d_in[3];
  const float* g1    = (const float*)d_in[4];
  const float* beta1 = (const float*)d_in[5];
  const float* W2    = (const float*)d_in[6];
  const float* b2    = (const float*)d_in[7];
  const float* g2    = (const float*)d_in[8];
  const float* beta2 = (const float*)d_in[9];
  const float* lerp_w = (const float*)d_in[10];

  int bs = in_sizes[0] / 512;       // 32768
  int P  = in_sizes[10] / 3;        // 8192
  int n_total = bs + 3 * P;         // 57344

  float* out_f = (float*)d_out;
  float* Hout = out_f;
  float* newfea = out_f + (size_t)bs * 512;
  float* lbl_out = out_f + (size_t)n_total * 512;

  float* Y1      = (float*)d_ws;                 // 64MB, dead after gemm2
  float* X       = Y1 + (size_t)bs * 512;
  float* partial = X + (size_t)P * 512;
  float* scale   = partial + 512 * 1024;
  float* shift   = scale + 512;
  float* sq      = shift + 512;
  int*   pos     = (int*)(sq + P);
  int*   idx3    = pos + P;
  // overlaid into the dead Y1 region (used only after gemm2):
  unsigned short* Xh  = (unsigned short*)d_ws;                       // 8MB
  float* p8v = (float*)((char*)d_ws + (size_t)8 * 1024 * 1024);      // 4MB
  int*   p8j = (int*)((char*)d_ws + (size_t)12 * 1024 * 1024);      // 4MB
  int*   cand = (int*)((char*)d_ws + (size_t)16 * 1024 * 1024);     // 256KB

  dim3 gemm_grid(bs / 64, 8);
  int nblk = bs / 64;

  gemm_bias_512<<<gemm_grid, 256, 0, stream>>>(fea, W1, b1, Y1, bs);
  bn_partial<<<nblk, 256, 0, stream>>>(Y1, partial, 64);
  bn_finalize<<<2, 256, 0, stream>>>(partial, g1, beta1, scale, shift, nblk, bs);
  bn_swish<<<(bs * 512 / 4 + 255) / 256, 256, 0, stream>>>(Y1, scale, shift, Y1, bs * 512 / 4);

  gemm_bias_512<<<gemm_grid, 256, 0, stream>>>(Y1, W2, b2, Hout, bs);
  bn_partial<<<nblk, 256, 0, stream>>>(Hout, partial, 64);
  bn_finalize<<<2, 256, 0, stream>>>(partial, g2, beta2, scale, shift, nblk, bs);
  bn_swish<<<(bs * 512 / 4 + 255) / 256, 256, 0, stream>>>(Hout, scale, shift, Hout, bs * 512 / 4);

  compact_pos<<<1, 256, 0, stream>>>(lbl, bs, pos, P);
  gather_sq<<<P, 128, 0, stream>>>(Hout, pos, X, Xh, sq);

  dim3 gram_grid(P / 128, NSPLIT);
  gram8<<<gram_grid, 256, 0, stream>>>(Xh, sq, P, p8v, p8j);
  merge8<<<(P + 255) / 256, 256, 0, stream>>>(p8v, p8j, cand, P);
  rescore<<<P, 64, 0, stream>>>(X, sq, cand, idx3);

  make_newfea<<<3 * P, 128, 0, stream>>>(X, idx3, lerp_w, newfea);
  write_lbl<<<(n_total + 255) / 256, 256, 0, stream>>>(lbl, lbl_out, bs, n_total);
}

// Round 4
// 760.804 us; speedup vs baseline: 2.9985x; 1.4497x over previous
//
#include <hip/hip_runtime.h>
#include <math.h>

#define NEG_INF -3.402823466e38f
#define NSPLIT 8

typedef __attribute__((ext_vector_type(8))) short bf16x8;
typedef __attribute__((ext_vector_type(4))) float f32x4;

__device__ __forceinline__ void gload_lds16(const unsigned short* g, unsigned short* l) {
  __builtin_amdgcn_global_load_lds(
      (const __attribute__((address_space(1))) unsigned int*)g,
      (__attribute__((address_space(3))) unsigned int*)l, 16, 0, 0);
}
__device__ __forceinline__ void gload_lds16f(const float* g, float* l) {
  __builtin_amdgcn_global_load_lds(
      (const __attribute__((address_space(1))) unsigned int*)g,
      (__attribute__((address_space(3))) unsigned int*)l, 16, 0, 0);
}

__device__ __forceinline__ unsigned short f2bf(float f) {
  union { float f; unsigned int u; } a; a.f = f;
  unsigned int u = a.u;
  return (unsigned short)((u + 0x7fffu + ((u >> 16) & 1u)) >> 16);
}

// pairwise 3-term truncation split: 8 f32 -> hi/mid/lo bf16x8.
// residual after 3 terms <= 2^-24 rel (fp32-class).
__device__ __forceinline__ void split3_8(f32x4 a, f32x4 b,
                                         bf16x8& hi, bf16x8& md, bf16x8& lo) {
  union { bf16x8 v; unsigned int u[4]; } H, M, L;
  float f[8];
  f[0]=a[0]; f[1]=a[1]; f[2]=a[2]; f[3]=a[3];
  f[4]=b[0]; f[5]=b[1]; f[6]=b[2]; f[7]=b[3];
#pragma unroll
  for (int p = 0; p < 4; ++p) {
    union { float f; unsigned int u; } x0, x1, h0, h1, r0, r1, m0, m1, s0, s1;
    x0.f = f[2*p]; x1.f = f[2*p+1];
    H.u[p] = (x0.u >> 16) | (x1.u & 0xffff0000u);
    h0.u = x0.u & 0xffff0000u; h1.u = x1.u & 0xffff0000u;
    r0.f = x0.f - h0.f;        r1.f = x1.f - h1.f;
    M.u[p] = (r0.u >> 16) | (r1.u & 0xffff0000u);
    m0.u = r0.u & 0xffff0000u; m1.u = r1.u & 0xffff0000u;
    s0.f = r0.f - m0.f;        s1.f = r1.f - m1.f;
    L.u[p] = (s0.u >> 16) | (s1.u & 0xffff0000u);
  }
  hi = H.v; md = M.v; lo = L.v;
}

// ------ split+transpose weights: W[512][512] -> Wt_{h,m,l}[n][k] (truncation) --
__global__ __launch_bounds__(256) void split_w_t3(const float* __restrict__ W,
    unsigned short* __restrict__ Th, unsigned short* __restrict__ Tm,
    unsigned short* __restrict__ Tl)
{
  __shared__ float T[64][65];
  int k0 = blockIdx.x * 64, n0 = blockIdx.y * 64;
  int tid = threadIdx.x;
  int r = tid >> 4, c4 = (tid & 15) << 2;
#pragma unroll
  for (int p = 0; p < 4; ++p) {
    int row = r + p * 16;
    float4 v = *(const float4*)&W[(size_t)(k0 + row) * 512 + n0 + c4];
    T[c4 + 0][row] = v.x; T[c4 + 1][row] = v.y;
    T[c4 + 2][row] = v.z; T[c4 + 3][row] = v.w;
  }
  __syncthreads();
  int nr = tid >> 2, kc = (tid & 3) << 4;
#pragma unroll
  for (int u = 0; u < 16; ++u) {
    union { float f; unsigned int u; } x, h, rr, m, ss;
    x.f = T[nr][kc + u];
    unsigned short hb = (unsigned short)(x.u >> 16);
    h.u = x.u & 0xffff0000u;
    rr.f = x.f - h.f;
    unsigned short mb = (unsigned short)(rr.u >> 16);
    m.u = rr.u & 0xffff0000u;
    ss.f = rr.f - m.f;
    unsigned short lb = (unsigned short)(ss.u >> 16);
    size_t o = (size_t)(n0 + nr) * 512 + k0 + kc + u;
    Th[o] = hb; Tm[o] = mb; Tl[o] = lb;
  }
}

// ------ GEMM: C = A(Mx512 fp32) @ (Bh+Bm+Bl)^T + bias, 6-MFMA fp32-emulation ---
// also emits per-wave BN column partials (sum, sumsq).
__global__ __launch_bounds__(256, 2) void gemm_split3(
    const float* __restrict__ A, const unsigned short* __restrict__ Bth,
    const unsigned short* __restrict__ Btm, const unsigned short* __restrict__ Btl,
    const float* __restrict__ bias, float* __restrict__ C, float* __restrict__ partial)
{
  __shared__ float sA[128 * 64];
  __shared__ unsigned short sBh[128 * 64];
  __shared__ unsigned short sBm[128 * 64];
  __shared__ unsigned short sBl[128 * 64];
  const int tid = threadIdx.x;
  const int w = tid >> 6, lane = tid & 63;
  const int wr = w >> 1, wc = w & 1;
  const int bm = blockIdx.x * 128, bn = blockIdx.y * 128;
  const int fr = lane & 15, fg = lane >> 4;
  const int arow = tid >> 4, acb = (tid & 15) << 4;  // A stage: 16 lanes x 16B/row
  const int brow = tid >> 3, bcb = (tid & 7) << 4;   // B stage: 8 lanes x 16B/row

  f32x4 acc[4][4];
#pragma unroll
  for (int mi = 0; mi < 4; ++mi)
#pragma unroll
    for (int ni = 0; ni < 4; ++ni) acc[mi][ni] = (f32x4){0.f, 0.f, 0.f, 0.f};

  for (int kt = 0; kt < 512; kt += 64) {
#pragma unroll
    for (int p = 0; p < 8; ++p) {
      int row = arow + p * 16;
      int swz = ((row & 3) << 5) | ((row & 4) << 2);   // 16B-granular, 8 slots mod 128
      int cb = acb ^ swz;
      gload_lds16f(&A[(size_t)(bm + row) * 512 + kt + (cb >> 2)],
                   &sA[row * 64 + (acb >> 2)]);
    }
#pragma unroll
    for (int p = 0; p < 4; ++p) {
      int row = brow + p * 32;
      int cb = bcb ^ ((row & 7) << 4);
      int so = (bcb >> 1);
      gload_lds16(&Bth[(size_t)(bn + row) * 512 + kt + (cb >> 1)], &sBh[row * 64 + so]);
      gload_lds16(&Btm[(size_t)(bn + row) * 512 + kt + (cb >> 1)], &sBm[row * 64 + so]);
      gload_lds16(&Btl[(size_t)(bn + row) * 512 + kt + (cb >> 1)], &sBl[row * 64 + so]);
    }
    __syncthreads();
#pragma unroll
    for (int ks = 0; ks < 2; ++ks) {
      int kbb = ks * 64 + fg * 16;
      bf16x8 bfh[4], bfm[4], bfl[4];
#pragma unroll
      for (int ni = 0; ni < 4; ++ni) {
        int row = wc * 64 + ni * 16 + fr;
        int off = row * 64 + ((kbb ^ ((row & 7) << 4)) >> 1);
        bfh[ni] = *(const bf16x8*)&sBh[off];
        bfm[ni] = *(const bf16x8*)&sBm[off];
        bfl[ni] = *(const bf16x8*)&sBl[off];
      }
      bf16x8 afh[4], afm[4], afl[4];
      int kba = ks * 128 + fg * 32;
#pragma unroll
      for (int mi = 0; mi < 4; ++mi) {
        int row = wr * 64 + mi * 16 + fr;
        int swz = ((row & 3) << 5) | ((row & 4) << 2);
        f32x4 f0 = *(const f32x4*)((const char*)sA + row * 256 + (kba ^ swz));
        f32x4 f1 = *(const f32x4*)((const char*)sA + row * 256 + ((kba + 16) ^ swz));
        split3_8(f0, f1, afh[mi], afm[mi], afl[mi]);
      }
#pragma unroll
      for (int mi = 0; mi < 4; ++mi)
#pragma unroll
        for (int ni = 0; ni < 4; ++ni) {
          acc[mi][ni] = __builtin_amdgcn_mfma_f32_16x16x32_bf16(afl[mi], bfh[ni], acc[mi][ni], 0, 0, 0);
          acc[mi][ni] = __builtin_amdgcn_mfma_f32_16x16x32_bf16(afm[mi], bfm[ni], acc[mi][ni], 0, 0, 0);
          acc[mi][ni] = __builtin_amdgcn_mfma_f32_16x16x32_bf16(afh[mi], bfl[ni], acc[mi][ni], 0, 0, 0);
          acc[mi][ni] = __builtin_amdgcn_mfma_f32_16x16x32_bf16(afm[mi], bfh[ni], acc[mi][ni], 0, 0, 0);
          acc[mi][ni] = __builtin_amdgcn_mfma_f32_16x16x32_bf16(afh[mi], bfm[ni], acc[mi][ni], 0, 0, 0);
          acc[mi][ni] = __builtin_amdgcn_mfma_f32_16x16x32_bf16(afh[mi], bfh[ni], acc[mi][ni], 0, 0, 0);
        }
    }
    __syncthreads();
  }
  float bno[4], s[4] = {0, 0, 0, 0}, q[4] = {0, 0, 0, 0};
#pragma unroll
  for (int ni = 0; ni < 4; ++ni) bno[ni] = bias[bn + wc * 64 + ni * 16 + fr];
#pragma unroll
  for (int mi = 0; mi < 4; ++mi) {
    int row = bm + wr * 64 + mi * 16 + fg * 4;
#pragma unroll
    for (int ni = 0; ni < 4; ++ni) {
      int col = bn + wc * 64 + ni * 16 + fr;
#pragma unroll
      for (int r = 0; r < 4; ++r) {
        float v = acc[mi][ni][r] + bno[ni];
        C[(size_t)(row + r) * 512 + col] = v;
        s[ni] += v; q[ni] += v * v;
      }
    }
  }
#pragma unroll
  for (int ni = 0; ni < 4; ++ni) {
    float ss = s[ni], qq = q[ni];
    ss += __shfl_xor(ss, 16); ss += __shfl_xor(ss, 32);
    qq += __shfl_xor(qq, 16); qq += __shfl_xor(qq, 32);
    if (fg == 0) {
      int slot = blockIdx.x * 2 + wr;
      int col = bn + wc * 64 + ni * 16 + fr;
      partial[(size_t)(slot * 2 + 0) * 512 + col] = ss;
      partial[(size_t)(slot * 2 + 1) * 512 + col] = qq;
    }
  }
}

__global__ void bn_finalize(
    const float* __restrict__ partial, const float* __restrict__ g,
    const float* __restrict__ beta, float* __restrict__ scale,
    float* __restrict__ shift, int nslot, int rows)
{
  int c = blockIdx.x * blockDim.x + threadIdx.x;
  if (c >= 512) return;
  float s = 0, s2 = 0;
  for (int b = 0; b < nslot; ++b) {
    s  += partial[(size_t)(b * 2 + 0) * 512 + c];
    s2 += partial[(size_t)(b * 2 + 1) * 512 + c];
  }
  float m = s / rows;
  float v = s2 / rows - m * m;
  if (v < 0) v = 0;
  float sc = g[c] / sqrtf(v + 1e-5f);
  scale[c] = sc;
  shift[c] = beta[c] - m * sc;
}

__global__ void bn_swish(
    const float* __restrict__ Y, const float* __restrict__ scale,
    const float* __restrict__ shift, float* __restrict__ H, int total4)
{
  int i = blockIdx.x * blockDim.x + threadIdx.x;
  if (i >= total4) return;
  float4 y = ((const float4*)Y)[i];
  int c = (i * 4) & 511;
  float z;
  float4 o;
  z = y.x * scale[c + 0] + shift[c + 0]; o.x = z / (1.f + expf(-z));
  z = y.y * scale[c + 1] + shift[c + 1]; o.y = z / (1.f + expf(-z));
  z = y.z * scale[c + 2] + shift[c + 2]; o.z = z / (1.f + expf(-z));
  z = y.w * scale[c + 3] + shift[c + 3]; o.w = z / (1.f + expf(-z));
  ((float4*)H)[i] = o;
}

// ---------------- ordered compaction of positive labels ----------------
__global__ void compact_pos(const int* __restrict__ lbl, int n,
                            int* __restrict__ pos, int P)
{
  __shared__ int base;
  __shared__ int wsum[16];
  int tid = threadIdx.x;
  int nthr = blockDim.x;
  for (int t = tid; t < P; t += nthr) pos[t] = 0;
  if (tid == 0) base = 0;
  __syncthreads();
  int nw = nthr >> 6;
  for (int start = 0; start < n; start += nthr) {
    int i = start + tid;
    int pred = (i < n) && (lbl[i] > 0);
    unsigned long long m = __ballot(pred);
    int wid = tid >> 6, lane = tid & 63;
    if (lane == 0) wsum[wid] = __popcll(m);
    __syncthreads();
    int wbase = 0;
    for (int w2 = 0; w2 < wid; ++w2) wbase += wsum[w2];
    int rank = base + wbase + __popcll(m & ((1ull << lane) - 1ull));
    if (pred && rank < P) pos[rank] = i;
    __syncthreads();
    if (tid == 0) { int t2 = 0; for (int w2 = 0; w2 < nw; ++w2) t2 += wsum[w2]; base += t2; }
    __syncthreads();
  }
}

// ---------------- gather positives + sq norms + bf16 copy ----------------
__global__ void gather_sq(const float* __restrict__ H, const int* __restrict__ pos,
                          float* __restrict__ X, unsigned short* __restrict__ Xh,
                          float* __restrict__ sq)
{
  int r = blockIdx.x, t = threadIdx.x;  // 128 threads
  int src = pos[r];
  float4 v = *(const float4*)&H[src * 512 + t * 4];
  *(float4*)&X[r * 512 + t * 4] = v;
  ushort4 hv;
  hv.x = f2bf(v.x); hv.y = f2bf(v.y); hv.z = f2bf(v.z); hv.w = f2bf(v.w);
  *(ushort4*)&Xh[r * 512 + t * 4] = hv;
  float s = v.x * v.x + v.y * v.y + v.z * v.z + v.w * v.w;
#pragma unroll
  for (int off = 32; off > 0; off >>= 1) s += __shfl_down(s, off);
  __shared__ float red[2];
  if ((t & 63) == 0) red[t >> 6] = s;
  __syncthreads();
  if (t == 0) sq[r] = red[0] + red[1];
}

// ---------------- approx Gram (bf16 MFMA) + running top-8 ----------------
__global__ __launch_bounds__(256, 2) void gram8(
    const unsigned short* __restrict__ Xh, const float* __restrict__ sq, int P,
    float* __restrict__ p8v, int* __restrict__ p8j)
{
  __shared__ unsigned short Ah[128 * 64];
  __shared__ unsigned short Bh[128 * 64];
  __shared__ float dl[4][64][17];
  __shared__ float sqj_l[128];

  const int tid = threadIdx.x;
  const int w = tid >> 6, lane = tid & 63;
  const int wr = w >> 1, wc = w & 1;
  const int bi = blockIdx.x * 128;
  const int jchunk = P / NSPLIT;
  const int jlo = blockIdx.y * jchunk;

  const int srow = tid >> 3;
  const int scb  = (tid & 7) << 4;
  const int fr = lane & 15, fg = lane >> 4;

  float t[8]; int ji[8];
#pragma unroll
  for (int q = 0; q < 8; ++q) { t[q] = NEG_INF; ji[q] = 0x7fffffff; }

  for (int jt = 0; jt < jchunk; jt += 128) {
    const int j0 = jlo + jt;
    if (tid < 128) sqj_l[tid] = sq[j0 + tid];
    f32x4 acc[4][4];
#pragma unroll
    for (int mi = 0; mi < 4; ++mi)
#pragma unroll
      for (int ni = 0; ni < 4; ++ni) acc[mi][ni] = (f32x4){0.f, 0.f, 0.f, 0.f};

    for (int kt = 0; kt < 512; kt += 64) {
#pragma unroll
      for (int it = 0; it < 4; ++it) {
        int row = srow + it * 32;
        int cb = scb ^ ((row & 7) << 4);
        gload_lds16(&Xh[(size_t)(bi + row) * 512 + kt + (cb >> 1)],
                    &Ah[row * 64 + (scb >> 1)]);
        gload_lds16(&Xh[(size_t)(j0 + row) * 512 + kt + (cb >> 1)],
                    &Bh[row * 64 + (scb >> 1)]);
      }
      __syncthreads();
#pragma unroll
      for (int ks = 0; ks < 2; ++ks) {
        bf16x8 af[4], bfr[4];
        int kb = ks * 64 + fg * 16;
#pragma unroll
        for (int mi = 0; mi < 4; ++mi) {
          int row = wr * 64 + mi * 16 + fr;
          af[mi] = *(const bf16x8*)&Ah[row * 64 + ((kb ^ ((row & 7) << 4)) >> 1)];
        }
#pragma unroll
        for (int ni = 0; ni < 4; ++ni) {
          int row = wc * 64 + ni * 16 + fr;
          bfr[ni] = *(const bf16x8*)&Bh[row * 64 + ((kb ^ ((row & 7) << 4)) >> 1)];
        }
#pragma unroll
        for (int mi = 0; mi < 4; ++mi)
#pragma unroll
          for (int ni = 0; ni < 4; ++ni)
            acc[mi][ni] = __builtin_amdgcn_mfma_f32_16x16x32_bf16(
                af[mi], bfr[ni], acc[mi][ni], 0, 0, 0);
      }
      __syncthreads();
    }

#pragma unroll
    for (int qn = 0; qn < 4; ++qn) {
      float sqv = sqj_l[wc * 64 + qn * 16 + fr];
#pragma unroll
      for (int mi = 0; mi < 4; ++mi)
#pragma unroll
        for (int r = 0; r < 4; ++r)
          dl[w][mi * 16 + fg * 4 + r][fr] = 2.0f * acc[mi][qn][r] - sqv;
      __syncthreads();
      int jbase = j0 + wc * 64 + qn * 16;
      for (int c = 0; c < 16; ++c) {
        float v = dl[w][lane][c];
        if (v > t[7]) {
          t[7] = v; ji[7] = jbase + c;
#pragma unroll
          for (int q = 7; q > 0; --q) {
            if (t[q] > t[q - 1]) {
              float tv = t[q]; t[q] = t[q - 1]; t[q - 1] = tv;
              int tj = ji[q]; ji[q] = ji[q - 1]; ji[q - 1] = tj;
            }
          }
        }
      }
      __syncthreads();
    }
  }

  int row = bi + wr * 64 + lane;
  int set = blockIdx.y * 2 + wc;
  size_t base = ((size_t)row * (NSPLIT * 2) + set) * 8;
#pragma unroll
  for (int q = 0; q < 8; ++q) { p8v[base + q] = t[q]; p8j[base + q] = ji[q]; }
}

// ---------------- merge 16 sorted top-8 lists -> top-8 candidates ----------
__global__ void merge8(const float* __restrict__ p8v, const int* __restrict__ p8j,
                       int* __restrict__ cand, int P)
{
  int i = blockIdx.x * blockDim.x + threadIdx.x;
  if (i >= P) return;
  const int S = NSPLIT * 2;
  int head[S];
#pragma unroll
  for (int s = 0; s < S; ++s) head[s] = 0;
  const float* v = p8v + (size_t)i * S * 8;
  const int* j = p8j + (size_t)i * S * 8;
  for (int k = 0; k < 8; ++k) {
    float bv = NEG_INF; int bj = 0x7fffffff; int bs = 0;
#pragma unroll
    for (int s = 0; s < S; ++s) {
      if (head[s] < 8) {
        float vv = v[s * 8 + head[s]];
        int jj = j[s * 8 + head[s]];
        if (vv > bv || (vv == bv && jj < bj)) { bv = vv; bj = jj; bs = s; }
      }
    }
    head[bs]++;
    cand[i * 8 + k] = bj;
  }
}

// ---------------- exact fp32 rescore of 8 candidates -> top-3 --------------
__global__ __launch_bounds__(64) void rescore(
    const float* __restrict__ X, const float* __restrict__ sq,
    const int* __restrict__ cand, int* __restrict__ idx3)
{
  int i = blockIdx.x;
  int lane = threadIdx.x;
  f32x4 x0 = *(const f32x4*)&X[(size_t)i * 512 + lane * 8];
  f32x4 x1 = *(const f32x4*)&X[(size_t)i * 512 + lane * 8 + 4];
  float d[8]; int cj[8];
#pragma unroll
  for (int c = 0; c < 8; ++c) {
    int j = cand[i * 8 + c];
    cj[c] = j;
    f32x4 y0 = *(const f32x4*)&X[(size_t)j * 512 + lane * 8];
    f32x4 y1 = *(const f32x4*)&X[(size_t)j * 512 + lane * 8 + 4];
    float p = x0.x * y0.x + x0.y * y0.y + x0.z * y0.z + x0.w * y0.w
            + x1.x * y1.x + x1.y * y1.y + x1.z * y1.z + x1.w * y1.w;
#pragma unroll
    for (int off = 32; off > 0; off >>= 1) p += __shfl_xor(p, off);
    d[c] = 2.0f * p - sq[i] - sq[j];
  }
  if (lane == 0) {
    for (int k = 0; k < 3; ++k) {
      int b = 0;
#pragma unroll
      for (int c = 1; c < 8; ++c)
        if (d[c] > d[b] || (d[c] == d[b] && cj[c] < cj[b])) b = c;
      idx3[i * 3 + k] = cj[b];
      d[b] = NEG_INF; cj[b] = 0x7fffffff;
    }
  }
}

// ---------------- SMOTE lerp rows ----------------
__global__ void make_newfea(const float* __restrict__ X, const int* __restrict__ idx3,
                            const float* __restrict__ lw, float* __restrict__ out)
{
  int r = blockIdx.x;
  int i = r / 3, k = r - i * 3;
  int ai = idx3[i * 3 + 0];
  int bi = idx3[i * 3 + k];
  float w = lw[r];
  int t = threadIdx.x;
  float4 av = *(const float4*)&X[ai * 512 + t * 4];
  float4 bv = *(const float4*)&X[bi * 512 + t * 4];
  float4 o;
  o.x = av.x + w * (bv.x - av.x);
  o.y = av.y + w * (bv.y - av.y);
  o.z = av.z + w * (bv.z - av.z);
  o.w = av.w + w * (bv.w - av.w);
  *(float4*)&out[(size_t)r * 512 + t * 4] = o;
}

__global__ void write_lbl(const int* __restrict__ lbl, float* __restrict__ out,
                          int n_in, int n_total)
{
  int i = blockIdx.x * blockDim.x + threadIdx.x;
  if (i < n_total) out[i] = (i < n_in) ? (float)lbl[i] : 1.0f;
}

// ---------------- launch ----------------
extern "C" void kernel_launch(void* const* d_in, const int* in_sizes, int n_in,
                              void* d_out, int out_size, void* d_ws, size_t ws_size,
                              hipStream_t stream)
{
  const float* fea   = (const float*)d_in[0];
  const int*   lbl   = (const int*)d_in[1];
  const float* W1    = (const float*)d_in[2];
  const float* b1    = (const float*)d_in[3];
  const float* g1    = (const float*)d_in[4];
  const float* beta1 = (const float*)d_in[5];
  const float* W2    = (const float*)d_in[6];
  const float* b2    = (const float*)d_in[7];
  const float* g2    = (const float*)d_in[8];
  const float* beta2 = (const float*)d_in[9];
  const float* lerp_w = (const float*)d_in[10];

  int bs = in_sizes[0] / 512;       // 32768
  int P  = in_sizes[10] / 3;        // 8192
  int n_total = bs + 3 * P;         // 57344

  float* out_f = (float*)d_out;
  float* Hout = out_f;
  float* newfea = out_f + (size_t)bs * 512;
  float* lbl_out = out_f + (size_t)n_total * 512;

  const size_t MB = 1024 * 1024;
  const size_t KB = 1024;
  char* ws = (char*)d_ws;
  float* Y1 = (float*)ws;                                  // 64MB fp32 y1 -> h1
  float* X  = (float*)(ws + 64 * MB);                      // 16MB (after weights dead)
  unsigned short* W1h = (unsigned short*)(ws + 64 * MB);
  unsigned short* W1m = (unsigned short*)(ws + 64 * MB + 512 * KB);
  unsigned short* W1l = (unsigned short*)(ws + 64 * MB + 1024 * KB);
  unsigned short* W2h = (unsigned short*)(ws + 64 * MB + 1536 * KB);
  unsigned short* W2m = (unsigned short*)(ws + 64 * MB + 2048 * KB);
  unsigned short* W2l = (unsigned short*)(ws + 64 * MB + 2560 * KB);
  float* partial = (float*)(ws + 80 * MB);                 // 2MB
  float* scale = (float*)(ws + 82 * MB);
  float* shiftv = scale + 512;
  float* sq = shiftv + 512;
  int* pos = (int*)(sq + 8192);
  int* idx3 = pos + 8192;
  // overlays in dead Y1 region (used only after gemm2):
  unsigned short* Xh = (unsigned short*)ws;                // 8MB
  float* p8v = (float*)(ws + 8 * MB);                      // 4MB
  int*   p8j = (int*)(ws + 12 * MB);                       // 4MB
  int*   cand = (int*)(ws + 16 * MB);                      // 256KB

  dim3 wgrid(8, 8);
  split_w_t3<<<wgrid, 256, 0, stream>>>(W1, W1h, W1m, W1l);
  split_w_t3<<<wgrid, 256, 0, stream>>>(W2, W2h, W2m, W2l);

  dim3 ggrid(bs / 128, 4);
  int nslot = (bs / 128) * 2;

  gemm_split3<<<ggrid, 256, 0, stream>>>(fea, W1h, W1m, W1l, b1, Y1, partial);
  bn_finalize<<<2, 256, 0, stream>>>(partial, g1, beta1, scale, shiftv, nslot, bs);
  bn_swish<<<(bs * 512 / 4 + 255) / 256, 256, 0, stream>>>(Y1, scale, shiftv, Y1, bs * 512 / 4);

  gemm_split3<<<ggrid, 256, 0, stream>>>(Y1, W2h, W2m, W2l, b2, Hout, partial);
  bn_finalize<<<2, 256, 0, stream>>>(partial, g2, beta2, scale, shiftv, nslot, bs);
  bn_swish<<<(bs * 512 / 4 + 255) / 256, 256, 0, stream>>>(Hout, scale, shiftv, Hout, bs * 512 / 4);

  compact_pos<<<1, 1024, 0, stream>>>(lbl, bs, pos, P);
  gather_sq<<<P, 128, 0, stream>>>(Hout, pos, X, Xh, sq);

  dim3 gram_grid(P / 128, NSPLIT);
  gram8<<<gram_grid, 256, 0, stream>>>(Xh, sq, P, p8v, p8j);
  merge8<<<(P + 255) / 256, 256, 0, stream>>>(p8v, p8j, cand, P);
  rescore<<<P, 64, 0, stream>>>(X, sq, cand, idx3);

  make_newfea<<<3 * P, 128, 0, stream>>>(X, idx3, lerp_w, newfea);
  write_lbl<<<(n_total + 255) / 256, 256, 0, stream>>>(lbl, lbl_out, bs, n_total);
}

// Round 5
// 541.215 us; speedup vs baseline: 4.2151x; 1.4057x over previous
//
#include <hip/hip_runtime.h>
#include <math.h>

#define NEG_INF -3.402823466e38f
#define NSPLIT 8

typedef __attribute__((ext_vector_type(8))) short bf16x8;
typedef __attribute__((ext_vector_type(4))) float f32x4;

__device__ __forceinline__ void gload_lds16(const unsigned short* g, unsigned short* l) {
  __builtin_amdgcn_global_load_lds(
      (const __attribute__((address_space(1))) unsigned int*)g,
      (__attribute__((address_space(3))) unsigned int*)l, 16, 0, 0);
}
__device__ __forceinline__ void gload_lds16f(const float* g, float* l) {
  __builtin_amdgcn_global_load_lds(
      (const __attribute__((address_space(1))) unsigned int*)g,
      (__attribute__((address_space(3))) unsigned int*)l, 16, 0, 0);
}

__device__ __forceinline__ unsigned short f2bf(float f) {
  union { float f; unsigned int u; } a; a.f = f;
  unsigned int u = a.u;
  return (unsigned short)((u + 0x7fffu + ((u >> 16) & 1u)) >> 16);
}

// pairwise 3-term truncation split: 8 f32 -> hi/mid/lo bf16x8.
__device__ __forceinline__ void split3_8(f32x4 a, f32x4 b,
                                         bf16x8& hi, bf16x8& md, bf16x8& lo) {
  union { bf16x8 v; unsigned int u[4]; } H, M, L;
  float f[8];
  f[0]=a[0]; f[1]=a[1]; f[2]=a[2]; f[3]=a[3];
  f[4]=b[0]; f[5]=b[1]; f[6]=b[2]; f[7]=b[3];
#pragma unroll
  for (int p = 0; p < 4; ++p) {
    union { float f; unsigned int u; } x0, x1, h0, h1, r0, r1, m0, m1, s0, s1;
    x0.f = f[2*p]; x1.f = f[2*p+1];
    H.u[p] = (x0.u >> 16) | (x1.u & 0xffff0000u);
    h0.u = x0.u & 0xffff0000u; h1.u = x1.u & 0xffff0000u;
    r0.f = x0.f - h0.f;        r1.f = x1.f - h1.f;
    M.u[p] = (r0.u >> 16) | (r1.u & 0xffff0000u);
    m0.u = r0.u & 0xffff0000u; m1.u = r1.u & 0xffff0000u;
    s0.f = r0.f - m0.f;        s1.f = r1.f - m1.f;
    L.u[p] = (s0.u >> 16) | (s1.u & 0xffff0000u);
  }
  hi = H.v; md = M.v; lo = L.v;
}

// ------ split+transpose weights: W[512][512] -> Wt_{h,m,l}[n][k] --------------
__global__ __launch_bounds__(256) void split_w_t3(const float* __restrict__ W,
    unsigned short* __restrict__ Th, unsigned short* __restrict__ Tm,
    unsigned short* __restrict__ Tl)
{
  __shared__ float T[64][65];
  int k0 = blockIdx.x * 64, n0 = blockIdx.y * 64;
  int tid = threadIdx.x;
  int r = tid >> 4, c4 = (tid & 15) << 2;
#pragma unroll
  for (int p = 0; p < 4; ++p) {
    int row = r + p * 16;
    float4 v = *(const float4*)&W[(size_t)(k0 + row) * 512 + n0 + c4];
    T[c4 + 0][row] = v.x; T[c4 + 1][row] = v.y;
    T[c4 + 2][row] = v.z; T[c4 + 3][row] = v.w;
  }
  __syncthreads();
  int nr = tid >> 2, kc = (tid & 3) << 4;
#pragma unroll
  for (int u = 0; u < 16; ++u) {
    union { float f; unsigned int u; } x, h, rr, m, ss;
    x.f = T[nr][kc + u];
    unsigned short hb = (unsigned short)(x.u >> 16);
    h.u = x.u & 0xffff0000u;
    rr.f = x.f - h.f;
    unsigned short mb = (unsigned short)(rr.u >> 16);
    m.u = rr.u & 0xffff0000u;
    ss.f = rr.f - m.f;
    unsigned short lb = (unsigned short)(ss.u >> 16);
    size_t o = (size_t)(n0 + nr) * 512 + k0 + kc + u;
    Th[o] = hb; Tm[o] = mb; Tl[o] = lb;
  }
}

// ------ GEMM: C = A(Mx512 fp32) @ (Bh+Bm+Bl)^T + bias, 6-MFMA fp32-emulation ---
__global__ __launch_bounds__(256, 2) void gemm_split3(
    const float* __restrict__ A, const unsigned short* __restrict__ Bth,
    const unsigned short* __restrict__ Btm, const unsigned short* __restrict__ Btl,
    const float* __restrict__ bias, float* __restrict__ C, float* __restrict__ partial)
{
  __shared__ float sA[128 * 64];
  __shared__ unsigned short sBh[128 * 64];
  __shared__ unsigned short sBm[128 * 64];
  __shared__ unsigned short sBl[128 * 64];
  const int tid = threadIdx.x;
  const int w = tid >> 6, lane = tid & 63;
  const int wr = w >> 1, wc = w & 1;
  const int bm = blockIdx.x * 128, bn = blockIdx.y * 128;
  const int fr = lane & 15, fg = lane >> 4;
  const int arow = tid >> 4, acb = (tid & 15) << 4;
  const int brow = tid >> 3, bcb = (tid & 7) << 4;

  f32x4 acc[4][4];
#pragma unroll
  for (int mi = 0; mi < 4; ++mi)
#pragma unroll
    for (int ni = 0; ni < 4; ++ni) acc[mi][ni] = (f32x4){0.f, 0.f, 0.f, 0.f};

  for (int kt = 0; kt < 512; kt += 64) {
#pragma unroll
    for (int p = 0; p < 8; ++p) {
      int row = arow + p * 16;
      int swz = ((row & 3) << 5) | ((row & 4) << 2);
      int cb = acb ^ swz;
      gload_lds16f(&A[(size_t)(bm + row) * 512 + kt + (cb >> 2)],
                   &sA[row * 64 + (acb >> 2)]);
    }
#pragma unroll
    for (int p = 0; p < 4; ++p) {
      int row = brow + p * 32;
      int cb = bcb ^ ((row & 7) << 4);
      int so = (bcb >> 1);
      gload_lds16(&Bth[(size_t)(bn + row) * 512 + kt + (cb >> 1)], &sBh[row * 64 + so]);
      gload_lds16(&Btm[(size_t)(bn + row) * 512 + kt + (cb >> 1)], &sBm[row * 64 + so]);
      gload_lds16(&Btl[(size_t)(bn + row) * 512 + kt + (cb >> 1)], &sBl[row * 64 + so]);
    }
    __syncthreads();
#pragma unroll
    for (int ks = 0; ks < 2; ++ks) {
      int kbb = ks * 64 + fg * 16;
      bf16x8 bfh[4], bfm[4], bfl[4];
#pragma unroll
      for (int ni = 0; ni < 4; ++ni) {
        int row = wc * 64 + ni * 16 + fr;
        int off = row * 64 + ((kbb ^ ((row & 7) << 4)) >> 1);
        bfh[ni] = *(const bf16x8*)&sBh[off];
        bfm[ni] = *(const bf16x8*)&sBm[off];
        bfl[ni] = *(const bf16x8*)&sBl[off];
      }
      bf16x8 afh[4], afm[4], afl[4];
      int kba = ks * 128 + fg * 32;
#pragma unroll
      for (int mi = 0; mi < 4; ++mi) {
        int row = wr * 64 + mi * 16 + fr;
        int swz = ((row & 3) << 5) | ((row & 4) << 2);
        f32x4 f0 = *(const f32x4*)((const char*)sA + row * 256 + (kba ^ swz));
        f32x4 f1 = *(const f32x4*)((const char*)sA + row * 256 + ((kba + 16) ^ swz));
        split3_8(f0, f1, afh[mi], afm[mi], afl[mi]);
      }
#pragma unroll
      for (int mi = 0; mi < 4; ++mi)
#pragma unroll
        for (int ni = 0; ni < 4; ++ni) {
          acc[mi][ni] = __builtin_amdgcn_mfma_f32_16x16x32_bf16(afl[mi], bfh[ni], acc[mi][ni], 0, 0, 0);
          acc[mi][ni] = __builtin_amdgcn_mfma_f32_16x16x32_bf16(afm[mi], bfm[ni], acc[mi][ni], 0, 0, 0);
          acc[mi][ni] = __builtin_amdgcn_mfma_f32_16x16x32_bf16(afh[mi], bfl[ni], acc[mi][ni], 0, 0, 0);
          acc[mi][ni] = __builtin_amdgcn_mfma_f32_16x16x32_bf16(afm[mi], bfh[ni], acc[mi][ni], 0, 0, 0);
          acc[mi][ni] = __builtin_amdgcn_mfma_f32_16x16x32_bf16(afh[mi], bfm[ni], acc[mi][ni], 0, 0, 0);
          acc[mi][ni] = __builtin_amdgcn_mfma_f32_16x16x32_bf16(afh[mi], bfh[ni], acc[mi][ni], 0, 0, 0);
        }
    }
    __syncthreads();
  }
  float bno[4], s[4] = {0, 0, 0, 0}, q[4] = {0, 0, 0, 0};
#pragma unroll
  for (int ni = 0; ni < 4; ++ni) bno[ni] = bias[bn + wc * 64 + ni * 16 + fr];
#pragma unroll
  for (int mi = 0; mi < 4; ++mi) {
    int row = bm + wr * 64 + mi * 16 + fg * 4;
#pragma unroll
    for (int ni = 0; ni < 4; ++ni) {
      int col = bn + wc * 64 + ni * 16 + fr;
#pragma unroll
      for (int r = 0; r < 4; ++r) {
        float v = acc[mi][ni][r] + bno[ni];
        C[(size_t)(row + r) * 512 + col] = v;
        s[ni] += v; q[ni] += v * v;
      }
    }
  }
#pragma unroll
  for (int ni = 0; ni < 4; ++ni) {
    float ss = s[ni], qq = q[ni];
    ss += __shfl_xor(ss, 16); ss += __shfl_xor(ss, 32);
    qq += __shfl_xor(qq, 16); qq += __shfl_xor(qq, 32);
    if (fg == 0) {
      int slot = blockIdx.x * 2 + wr;
      int col = bn + wc * 64 + ni * 16 + fr;
      partial[(size_t)(slot * 2 + 0) * 512 + col] = ss;
      partial[(size_t)(slot * 2 + 1) * 512 + col] = qq;
    }
  }
}

// ------ BN reduce stage 1: fold nslot slots into 16 groups (coalesced) --------
__global__ __launch_bounds__(256) void bn_reduce1(
    const float* __restrict__ partial, float* __restrict__ partial2, int nslot)
{
  int g = blockIdx.x, p = blockIdx.y;   // 16 groups x 2 parts
  int per = nslot >> 4;
  int t = threadIdx.x;
#pragma unroll
  for (int cc = 0; cc < 2; ++cc) {
    int c = t + cc * 256;
    float s = 0.f;
    for (int s0 = 0; s0 < per; ++s0) {
      int slot = g * per + s0;
      s += partial[(size_t)(slot * 2 + p) * 512 + c];
    }
    partial2[(size_t)(g * 2 + p) * 512 + c] = s;
  }
}

__global__ void bn_finalize(
    const float* __restrict__ partial2, const float* __restrict__ g,
    const float* __restrict__ beta, float* __restrict__ scale,
    float* __restrict__ shift, int rows)
{
  int c = blockIdx.x * blockDim.x + threadIdx.x;
  if (c >= 512) return;
  float s = 0, s2 = 0;
  for (int b = 0; b < 16; ++b) {
    s  += partial2[(size_t)(b * 2 + 0) * 512 + c];
    s2 += partial2[(size_t)(b * 2 + 1) * 512 + c];
  }
  float m = s / rows;
  float v = s2 / rows - m * m;
  if (v < 0) v = 0;
  float sc = g[c] / sqrtf(v + 1e-5f);
  scale[c] = sc;
  shift[c] = beta[c] - m * sc;
}

__global__ void bn_swish(
    const float* __restrict__ Y, const float* __restrict__ scale,
    const float* __restrict__ shift, float* __restrict__ H, int total4)
{
  int i = blockIdx.x * blockDim.x + threadIdx.x;
  if (i >= total4) return;
  float4 y = ((const float4*)Y)[i];
  int c = (i * 4) & 511;
  float z;
  float4 o;
  z = y.x * scale[c + 0] + shift[c + 0]; o.x = z / (1.f + expf(-z));
  z = y.y * scale[c + 1] + shift[c + 1]; o.y = z / (1.f + expf(-z));
  z = y.z * scale[c + 2] + shift[c + 2]; o.z = z / (1.f + expf(-z));
  z = y.w * scale[c + 3] + shift[c + 3]; o.w = z / (1.f + expf(-z));
  ((float4*)H)[i] = o;
}

// ---------------- ordered compaction of positive labels ----------------
__global__ void compact_pos(const int* __restrict__ lbl, int n,
                            int* __restrict__ pos, int P)
{
  __shared__ int base;
  __shared__ int wsum[16];
  int tid = threadIdx.x;
  int nthr = blockDim.x;
  for (int t = tid; t < P; t += nthr) pos[t] = 0;
  if (tid == 0) base = 0;
  __syncthreads();
  int nw = nthr >> 6;
  for (int start = 0; start < n; start += nthr) {
    int i = start + tid;
    int pred = (i < n) && (lbl[i] > 0);
    unsigned long long m = __ballot(pred);
    int wid = tid >> 6, lane = tid & 63;
    if (lane == 0) wsum[wid] = __popcll(m);
    __syncthreads();
    int wbase = 0;
    for (int w2 = 0; w2 < wid; ++w2) wbase += wsum[w2];
    int rank = base + wbase + __popcll(m & ((1ull << lane) - 1ull));
    if (pred && rank < P) pos[rank] = i;
    __syncthreads();
    if (tid == 0) { int t2 = 0; for (int w2 = 0; w2 < nw; ++w2) t2 += wsum[w2]; base += t2; }
    __syncthreads();
  }
}

// ---------------- gather positives + sq norms + bf16 copy ----------------
__global__ void gather_sq(const float* __restrict__ H, const int* __restrict__ pos,
                          float* __restrict__ X, unsigned short* __restrict__ Xh,
                          float* __restrict__ sq)
{
  int r = blockIdx.x, t = threadIdx.x;  // 128 threads
  int src = pos[r];
  float4 v = *(const float4*)&H[src * 512 + t * 4];
  *(float4*)&X[r * 512 + t * 4] = v;
  ushort4 hv;
  hv.x = f2bf(v.x); hv.y = f2bf(v.y); hv.z = f2bf(v.z); hv.w = f2bf(v.w);
  *(ushort4*)&Xh[r * 512 + t * 4] = hv;
  float s = v.x * v.x + v.y * v.y + v.z * v.z + v.w * v.w;
#pragma unroll
  for (int off = 32; off > 0; off >>= 1) s += __shfl_down(s, off);
  __shared__ float red[2];
  if ((t & 63) == 0) red[t >> 6] = s;
  __syncthreads();
  if (t == 0) sq[r] = red[0] + red[1];
}

// ---------------- approx Gram (bf16 MFMA) + running top-8 ----------------
__global__ __launch_bounds__(256, 2) void gram8(
    const unsigned short* __restrict__ Xh, const float* __restrict__ sq, int P,
    float* __restrict__ p8v, int* __restrict__ p8j)
{
  __shared__ unsigned short Ah[128 * 64];
  __shared__ unsigned short Bh[128 * 64];
  __shared__ float dl[4][64][17];
  __shared__ float sqj_l[128];

  const int tid = threadIdx.x;
  const int w = tid >> 6, lane = tid & 63;
  const int wr = w >> 1, wc = w & 1;
  const int bi = blockIdx.x * 128;
  const int jchunk = P / NSPLIT;
  const int jlo = blockIdx.y * jchunk;

  const int srow = tid >> 3;
  const int scb  = (tid & 7) << 4;
  const int fr = lane & 15, fg = lane >> 4;

  float t[8]; int ji[8];
#pragma unroll
  for (int q = 0; q < 8; ++q) { t[q] = NEG_INF; ji[q] = 0x7fffffff; }

  for (int jt = 0; jt < jchunk; jt += 128) {
    const int j0 = jlo + jt;
    if (tid < 128) sqj_l[tid] = sq[j0 + tid];
    f32x4 acc[4][4];
#pragma unroll
    for (int mi = 0; mi < 4; ++mi)
#pragma unroll
      for (int ni = 0; ni < 4; ++ni) acc[mi][ni] = (f32x4){0.f, 0.f, 0.f, 0.f};

    for (int kt = 0; kt < 512; kt += 64) {
#pragma unroll
      for (int it = 0; it < 4; ++it) {
        int row = srow + it * 32;
        int cb = scb ^ ((row & 7) << 4);
        gload_lds16(&Xh[(size_t)(bi + row) * 512 + kt + (cb >> 1)],
                    &Ah[row * 64 + (scb >> 1)]);
        gload_lds16(&Xh[(size_t)(j0 + row) * 512 + kt + (cb >> 1)],
                    &Bh[row * 64 + (scb >> 1)]);
      }
      __syncthreads();
#pragma unroll
      for (int ks = 0; ks < 2; ++ks) {
        bf16x8 af[4], bfr[4];
        int kb = ks * 64 + fg * 16;
#pragma unroll
        for (int mi = 0; mi < 4; ++mi) {
          int row = wr * 64 + mi * 16 + fr;
          af[mi] = *(const bf16x8*)&Ah[row * 64 + ((kb ^ ((row & 7) << 4)) >> 1)];
        }
#pragma unroll
        for (int ni = 0; ni < 4; ++ni) {
          int row = wc * 64 + ni * 16 + fr;
          bfr[ni] = *(const bf16x8*)&Bh[row * 64 + ((kb ^ ((row & 7) << 4)) >> 1)];
        }
#pragma unroll
        for (int mi = 0; mi < 4; ++mi)
#pragma unroll
          for (int ni = 0; ni < 4; ++ni)
            acc[mi][ni] = __builtin_amdgcn_mfma_f32_16x16x32_bf16(
                af[mi], bfr[ni], acc[mi][ni], 0, 0, 0);
      }
      __syncthreads();
    }

#pragma unroll
    for (int qn = 0; qn < 4; ++qn) {
      float sqv = sqj_l[wc * 64 + qn * 16 + fr];
#pragma unroll
      for (int mi = 0; mi < 4; ++mi)
#pragma unroll
        for (int r = 0; r < 4; ++r)
          dl[w][mi * 16 + fg * 4 + r][fr] = 2.0f * acc[mi][qn][r] - sqv;
      __syncthreads();
      int jbase = j0 + wc * 64 + qn * 16;
      for (int c = 0; c < 16; ++c) {
        float v = dl[w][lane][c];
        if (v > t[7]) {
          t[7] = v; ji[7] = jbase + c;
#pragma unroll
          for (int q = 7; q > 0; --q) {
            if (t[q] > t[q - 1]) {
              float tv = t[q]; t[q] = t[q - 1]; t[q - 1] = tv;
              int tj = ji[q]; ji[q] = ji[q - 1]; ji[q - 1] = tj;
            }
          }
        }
      }
      __syncthreads();
    }
  }

  int row = bi + wr * 64 + lane;
  int set = blockIdx.y * 2 + wc;
  size_t base = ((size_t)row * (NSPLIT * 2) + set) * 8;
#pragma unroll
  for (int q = 0; q < 8; ++q) { p8v[base + q] = t[q]; p8j[base + q] = ji[q]; }
}

// ---------------- merge 16 sorted top-8 lists -> top-8 candidates ----------
__global__ void merge8(const float* __restrict__ p8v, const int* __restrict__ p8j,
                       int* __restrict__ cand, int P)
{
  int i = blockIdx.x * blockDim.x + threadIdx.x;
  if (i >= P) return;
  const int S = NSPLIT * 2;
  int head[S];
#pragma unroll
  for (int s = 0; s < S; ++s) head[s] = 0;
  const float* v = p8v + (size_t)i * S * 8;
  const int* j = p8j + (size_t)i * S * 8;
  for (int k = 0; k < 8; ++k) {
    float bv = NEG_INF; int bj = 0x7fffffff; int bs = 0;
#pragma unroll
    for (int s = 0; s < S; ++s) {
      if (head[s] < 8) {
        float vv = v[s * 8 + head[s]];
        int jj = j[s * 8 + head[s]];
        if (vv > bv || (vv == bv && jj < bj)) { bv = vv; bj = jj; bs = s; }
      }
    }
    head[bs]++;
    cand[i * 8 + k] = bj;
  }
}

// ---------------- exact fp32 rescore of 8 candidates -> top-3 --------------
__global__ __launch_bounds__(64) void rescore(
    const float* __restrict__ X, const float* __restrict__ sq,
    const int* __restrict__ cand, int* __restrict__ idx3)
{
  int i = blockIdx.x;
  int lane = threadIdx.x;
  f32x4 x0 = *(const f32x4*)&X[(size_t)i * 512 + lane * 8];
  f32x4 x1 = *(const f32x4*)&X[(size_t)i * 512 + lane * 8 + 4];
  float d[8]; int cj[8];
#pragma unroll
  for (int c = 0; c < 8; ++c) {
    int j = cand[i * 8 + c];
    cj[c] = j;
    f32x4 y0 = *(const f32x4*)&X[(size_t)j * 512 + lane * 8];
    f32x4 y1 = *(const f32x4*)&X[(size_t)j * 512 + lane * 8 + 4];
    float p = x0.x * y0.x + x0.y * y0.y + x0.z * y0.z + x0.w * y0.w
            + x1.x * y1.x + x1.y * y1.y + x1.z * y1.z + x1.w * y1.w;
#pragma unroll
    for (int off = 32; off > 0; off >>= 1) p += __shfl_xor(p, off);
    d[c] = 2.0f * p - sq[i] - sq[j];
  }
  if (lane == 0) {
    for (int k = 0; k < 3; ++k) {
      int b = 0;
#pragma unroll
      for (int c = 1; c < 8; ++c)
        if (d[c] > d[b] || (d[c] == d[b] && cj[c] < cj[b])) b = c;
      idx3[i * 3 + k] = cj[b];
      d[b] = NEG_INF; cj[b] = 0x7fffffff;
    }
  }
}

// ---------------- SMOTE lerp rows ----------------
__global__ void make_newfea(const float* __restrict__ X, const int* __restrict__ idx3,
                            const float* __restrict__ lw, float* __restrict__ out)
{
  int r = blockIdx.x;
  int i = r / 3, k = r - i * 3;
  int ai = idx3[i * 3 + 0];
  int bi = idx3[i * 3 + k];
  float w = lw[r];
  int t = threadIdx.x;
  float4 av = *(const float4*)&X[ai * 512 + t * 4];
  float4 bv = *(const float4*)&X[bi * 512 + t * 4];
  float4 o;
  o.x = av.x + w * (bv.x - av.x);
  o.y = av.y + w * (bv.y - av.y);
  o.z = av.z + w * (bv.z - av.z);
  o.w = av.w + w * (bv.w - av.w);
  *(float4*)&out[(size_t)r * 512 + t * 4] = o;
}

__global__ void write_lbl(const int* __restrict__ lbl, float* __restrict__ out,
                          int n_in, int n_total)
{
  int i = blockIdx.x * blockDim.x + threadIdx.x;
  if (i < n_total) out[i] = (i < n_in) ? (float)lbl[i] : 1.0f;
}

// ---------------- launch ----------------
extern "C" void kernel_launch(void* const* d_in, const int* in_sizes, int n_in,
                              void* d_out, int out_size, void* d_ws, size_t ws_size,
                              hipStream_t stream)
{
  const float* fea   = (const float*)d_in[0];
  const int*   lbl   = (const int*)d_in[1];
  const float* W1    = (const float*)d_in[2];
  const float* b1    = (const float*)d_in[3];
  const float* g1    = (const float*)d_in[4];
  const float* beta1 = (const float*)d_in[5];
  const float* W2    = (const float*)d_in[6];
  const float* b2    = (const float*)d_in[7];
  const float* g2    = (const float*)d_in[8];
  const float* beta2 = (const float*)d_in[9];
  const float* lerp_w = (const float*)d_in[10];

  int bs = in_sizes[0] / 512;       // 32768
  int P  = in_sizes[10] / 3;        // 8192
  int n_total = bs + 3 * P;         // 57344

  float* out_f = (float*)d_out;
  float* Hout = out_f;
  float* newfea = out_f + (size_t)bs * 512;
  float* lbl_out = out_f + (size_t)n_total * 512;

  const size_t MB = 1024 * 1024;
  const size_t KB = 1024;
  char* ws = (char*)d_ws;
  float* Y1 = (float*)ws;                                  // 64MB fp32 y1 -> h1
  float* X  = (float*)(ws + 64 * MB);                      // 16MB (after weights dead)
  unsigned short* W1h = (unsigned short*)(ws + 64 * MB);
  unsigned short* W1m = (unsigned short*)(ws + 64 * MB + 512 * KB);
  unsigned short* W1l = (unsigned short*)(ws + 64 * MB + 1024 * KB);
  unsigned short* W2h = (unsigned short*)(ws + 64 * MB + 1536 * KB);
  unsigned short* W2m = (unsigned short*)(ws + 64 * MB + 2048 * KB);
  unsigned short* W2l = (unsigned short*)(ws + 64 * MB + 2560 * KB);
  float* partial = (float*)(ws + 80 * MB);                 // 2MB
  float* scale = (float*)(ws + 82 * MB);
  float* shiftv = scale + 512;
  float* sq = shiftv + 512;
  int* pos = (int*)(sq + 8192);
  int* idx3 = pos + 8192;
  float* partial2 = (float*)(ws + 83 * MB);                // 64KB
  // overlays in dead Y1 region (used only after gemm2):
  unsigned short* Xh = (unsigned short*)ws;                // 8MB
  float* p8v = (float*)(ws + 8 * MB);                      // 4MB
  int*   p8j = (int*)(ws + 12 * MB);                       // 4MB
  int*   cand = (int*)(ws + 16 * MB);                      // 256KB

  dim3 wgrid(8, 8);
  split_w_t3<<<wgrid, 256, 0, stream>>>(W1, W1h, W1m, W1l);
  split_w_t3<<<wgrid, 256, 0, stream>>>(W2, W2h, W2m, W2l);

  dim3 ggrid(bs / 128, 4);
  int nslot = (bs / 128) * 2;          // 512
  dim3 rgrid(16, 2);

  gemm_split3<<<ggrid, 256, 0, stream>>>(fea, W1h, W1m, W1l, b1, Y1, partial);
  bn_reduce1<<<rgrid, 256, 0, stream>>>(partial, partial2, nslot);
  bn_finalize<<<2, 256, 0, stream>>>(partial2, g1, beta1, scale, shiftv, bs);
  bn_swish<<<(bs * 512 / 4 + 255) / 256, 256, 0, stream>>>(Y1, scale, shiftv, Y1, bs * 512 / 4);

  gemm_split3<<<ggrid, 256, 0, stream>>>(Y1, W2h, W2m, W2l, b2, Hout, partial);
  bn_reduce1<<<rgrid, 256, 0, stream>>>(partial, partial2, nslot);
  bn_finalize<<<2, 256, 0, stream>>>(partial2, g2, beta2, scale, shiftv, bs);
  bn_swish<<<(bs * 512 / 4 + 255) / 256, 256, 0, stream>>>(Hout, scale, shiftv, Hout, bs * 512 / 4);

  compact_pos<<<1, 1024, 0, stream>>>(lbl, bs, pos, P);
  gather_sq<<<P, 128, 0, stream>>>(Hout, pos, X, Xh, sq);

  dim3 gram_grid(P / 128, NSPLIT);
  gram8<<<gram_grid, 256, 0, stream>>>(Xh, sq, P, p8v, p8j);
  merge8<<<(P + 255) / 256, 256, 0, stream>>>(p8v, p8j, cand, P);
  rescore<<<P, 64, 0, stream>>>(X, sq, cand, idx3);

  make_newfea<<<3 * P, 128, 0, stream>>>(X, idx3, lerp_w, newfea);
  write_lbl<<<(n_total + 255) / 256, 256, 0, stream>>>(lbl, lbl_out, bs, n_total);
}

// Round 6
// 536.517 us; speedup vs baseline: 4.2520x; 1.0088x over previous
//
#include <hip/hip_runtime.h>
#include <math.h>

#define NEG_INF -3.402823466e38f
#define NSPLIT 8

typedef __attribute__((ext_vector_type(8))) short bf16x8;
typedef __attribute__((ext_vector_type(4))) float f32x4;

__device__ __forceinline__ void gload_lds16(const unsigned short* g, unsigned short* l) {
  __builtin_amdgcn_global_load_lds(
      (const __attribute__((address_space(1))) unsigned int*)g,
      (__attribute__((address_space(3))) unsigned int*)l, 16, 0, 0);
}
__device__ __forceinline__ void gload_lds16f(const float* g, float* l) {
  __builtin_amdgcn_global_load_lds(
      (const __attribute__((address_space(1))) unsigned int*)g,
      (__attribute__((address_space(3))) unsigned int*)l, 16, 0, 0);
}

__device__ __forceinline__ unsigned short f2bf(float f) {
  union { float f; unsigned int u; } a; a.f = f;
  unsigned int u = a.u;
  return (unsigned short)((u + 0x7fffu + ((u >> 16) & 1u)) >> 16);
}

// pairwise 3-term truncation split: 8 f32 -> hi/mid/lo bf16x8.
__device__ __forceinline__ void split3_8(f32x4 a, f32x4 b,
                                         bf16x8& hi, bf16x8& md, bf16x8& lo) {
  union { bf16x8 v; unsigned int u[4]; } H, M, L;
  float f[8];
  f[0]=a[0]; f[1]=a[1]; f[2]=a[2]; f[3]=a[3];
  f[4]=b[0]; f[5]=b[1]; f[6]=b[2]; f[7]=b[3];
#pragma unroll
  for (int p = 0; p < 4; ++p) {
    union { float f; unsigned int u; } x0, x1, h0, h1, r0, r1, m0, m1, s0, s1;
    x0.f = f[2*p]; x1.f = f[2*p+1];
    H.u[p] = (x0.u >> 16) | (x1.u & 0xffff0000u);
    h0.u = x0.u & 0xffff0000u; h1.u = x1.u & 0xffff0000u;
    r0.f = x0.f - h0.f;        r1.f = x1.f - h1.f;
    M.u[p] = (r0.u >> 16) | (r1.u & 0xffff0000u);
    m0.u = r0.u & 0xffff0000u; m1.u = r1.u & 0xffff0000u;
    s0.f = r0.f - m0.f;        s1.f = r1.f - m1.f;
    L.u[p] = (s0.u >> 16) | (s1.u & 0xffff0000u);
  }
  hi = H.v; md = M.v; lo = L.v;
}

// ------ split+transpose weights: W[512][512] -> Wt_{h,m,l}[n][k] --------------
__global__ __launch_bounds__(256) void split_w_t3(const float* __restrict__ W,
    unsigned short* __restrict__ Th, unsigned short* __restrict__ Tm,
    unsigned short* __restrict__ Tl)
{
  __shared__ float T[64][65];
  int k0 = blockIdx.x * 64, n0 = blockIdx.y * 64;
  int tid = threadIdx.x;
  int r = tid >> 4, c4 = (tid & 15) << 2;
#pragma unroll
  for (int p = 0; p < 4; ++p) {
    int row = r + p * 16;
    float4 v = *(const float4*)&W[(size_t)(k0 + row) * 512 + n0 + c4];
    T[c4 + 0][row] = v.x; T[c4 + 1][row] = v.y;
    T[c4 + 2][row] = v.z; T[c4 + 3][row] = v.w;
  }
  __syncthreads();
  int nr = tid >> 2, kc = (tid & 3) << 4;
#pragma unroll
  for (int u = 0; u < 16; ++u) {
    union { float f; unsigned int u; } x, h, rr, m, ss;
    x.f = T[nr][kc + u];
    unsigned short hb = (unsigned short)(x.u >> 16);
    h.u = x.u & 0xffff0000u;
    rr.f = x.f - h.f;
    unsigned short mb = (unsigned short)(rr.u >> 16);
    m.u = rr.u & 0xffff0000u;
    ss.f = rr.f - m.f;
    unsigned short lb = (unsigned short)(ss.u >> 16);
    size_t o = (size_t)(n0 + nr) * 512 + k0 + kc + u;
    Th[o] = hb; Tm[o] = mb; Tl[o] = lb;
  }
}

// ------ GEMM: double-buffered BK=32, 6-MFMA fp32-emulation + BN partials ------
__global__ __launch_bounds__(256, 2) void gemm_split3(
    const float* __restrict__ A, const unsigned short* __restrict__ Bth,
    const unsigned short* __restrict__ Btm, const unsigned short* __restrict__ Btl,
    const float* __restrict__ bias, float* __restrict__ C, float* __restrict__ partial)
{
  __shared__ char smem[81920];   // 2 x (sA 16K + 3x8K B)
  const int tid = threadIdx.x;
  const int w = tid >> 6, lane = tid & 63;
  const int wr = w >> 1, wc = w & 1;
  const int bm = blockIdx.x * 128, bn = blockIdx.y * 128;
  const int fr = lane & 15, fg = lane >> 4;
  const int arow = tid >> 3, acb = (tid & 7) << 4;   // A: 8 lanes x 16B per 128B row
  const int brow = tid >> 2, bcb = (tid & 3) << 4;   // B: 4 lanes x 16B per 64B row

  f32x4 acc[4][4];
#pragma unroll
  for (int mi = 0; mi < 4; ++mi)
#pragma unroll
    for (int ni = 0; ni < 4; ++ni) acc[mi][ni] = (f32x4){0.f, 0.f, 0.f, 0.f};

  auto STAGE = [&](int buf, int ktf) {
    float* sA = (float*)(smem + buf * 40960);
    unsigned short* sBh = (unsigned short*)(smem + buf * 40960 + 16384);
    unsigned short* sBm = sBh + 4096;
    unsigned short* sBl = sBm + 4096;
#pragma unroll
    for (int p = 0; p < 4; ++p) {
      int row = arow + p * 32;
      int cb = acb ^ ((row & 7) << 4);
      gload_lds16f(&A[(size_t)(bm + row) * 512 + ktf + (cb >> 2)],
                   &sA[row * 32 + (acb >> 2)]);
    }
#pragma unroll
    for (int p = 0; p < 2; ++p) {
      int row = brow + p * 64;
      int cb = bcb ^ (((row >> 1) & 3) << 4);
      int so = row * 32 + (bcb >> 1);
      gload_lds16(&Bth[(size_t)(bn + row) * 512 + ktf + (cb >> 1)], &sBh[so]);
      gload_lds16(&Btm[(size_t)(bn + row) * 512 + ktf + (cb >> 1)], &sBm[so]);
      gload_lds16(&Btl[(size_t)(bn + row) * 512 + ktf + (cb >> 1)], &sBl[so]);
    }
  };

  STAGE(0, 0);
  __syncthreads();
  for (int it = 0; it < 16; ++it) {
    int cur = it & 1;
    if (it + 1 < 16) STAGE(cur ^ 1, (it + 1) * 32);
    float* sA = (float*)(smem + cur * 40960);
    unsigned short* sBh = (unsigned short*)(smem + cur * 40960 + 16384);
    unsigned short* sBm = sBh + 4096;
    unsigned short* sBl = sBm + 4096;
    bf16x8 bh[4], bmf[4], blf[4];
#pragma unroll
    for (int ni = 0; ni < 4; ++ni) {
      int row = wc * 64 + ni * 16 + fr;
      int off = row * 32 + (((fg * 16) ^ (((row >> 1) & 3) << 4)) >> 1);
      bh[ni]  = *(const bf16x8*)&sBh[off];
      bmf[ni] = *(const bf16x8*)&sBm[off];
      blf[ni] = *(const bf16x8*)&sBl[off];
    }
    bf16x8 ah[4], am[4], al[4];
#pragma unroll
    for (int mi = 0; mi < 4; ++mi) {
      int row = wr * 64 + mi * 16 + fr;
      int swz = (row & 7) << 4;
      const char* rb = (const char*)(sA + row * 32);
      f32x4 f0 = *(const f32x4*)(rb + ((fg * 32) ^ swz));
      f32x4 f1 = *(const f32x4*)(rb + ((fg * 32 + 16) ^ swz));
      split3_8(f0, f1, ah[mi], am[mi], al[mi]);
    }
#pragma unroll
    for (int mi = 0; mi < 4; ++mi)
#pragma unroll
      for (int ni = 0; ni < 4; ++ni) {
        acc[mi][ni] = __builtin_amdgcn_mfma_f32_16x16x32_bf16(al[mi], bh[ni],  acc[mi][ni], 0, 0, 0);
        acc[mi][ni] = __builtin_amdgcn_mfma_f32_16x16x32_bf16(am[mi], bmf[ni], acc[mi][ni], 0, 0, 0);
        acc[mi][ni] = __builtin_amdgcn_mfma_f32_16x16x32_bf16(ah[mi], blf[ni], acc[mi][ni], 0, 0, 0);
        acc[mi][ni] = __builtin_amdgcn_mfma_f32_16x16x32_bf16(am[mi], bh[ni],  acc[mi][ni], 0, 0, 0);
        acc[mi][ni] = __builtin_amdgcn_mfma_f32_16x16x32_bf16(ah[mi], bmf[ni], acc[mi][ni], 0, 0, 0);
        acc[mi][ni] = __builtin_amdgcn_mfma_f32_16x16x32_bf16(ah[mi], bh[ni],  acc[mi][ni], 0, 0, 0);
      }
    __syncthreads();
  }
  float bno[4], s[4] = {0, 0, 0, 0}, q[4] = {0, 0, 0, 0};
#pragma unroll
  for (int ni = 0; ni < 4; ++ni) bno[ni] = bias[bn + wc * 64 + ni * 16 + fr];
#pragma unroll
  for (int mi = 0; mi < 4; ++mi) {
    int row = bm + wr * 64 + mi * 16 + fg * 4;
#pragma unroll
    for (int ni = 0; ni < 4; ++ni) {
      int col = bn + wc * 64 + ni * 16 + fr;
#pragma unroll
      for (int r = 0; r < 4; ++r) {
        float v = acc[mi][ni][r] + bno[ni];
        C[(size_t)(row + r) * 512 + col] = v;
        s[ni] += v; q[ni] += v * v;
      }
    }
  }
#pragma unroll
  for (int ni = 0; ni < 4; ++ni) {
    float ss = s[ni], qq = q[ni];
    ss += __shfl_xor(ss, 16); ss += __shfl_xor(ss, 32);
    qq += __shfl_xor(qq, 16); qq += __shfl_xor(qq, 32);
    if (fg == 0) {
      int slot = blockIdx.x * 2 + wr;
      int col = bn + wc * 64 + ni * 16 + fr;
      partial[(size_t)(slot * 2 + 0) * 512 + col] = ss;
      partial[(size_t)(slot * 2 + 1) * 512 + col] = qq;
    }
  }
}

// ------ BN reduce stage 1: fold nslot slots into 16 groups (coalesced) --------
__global__ __launch_bounds__(256) void bn_reduce1(
    const float* __restrict__ partial, float* __restrict__ partial2, int nslot)
{
  int g = blockIdx.x, p = blockIdx.y;
  int per = nslot >> 4;
  int t = threadIdx.x;
#pragma unroll
  for (int cc = 0; cc < 2; ++cc) {
    int c = t + cc * 256;
    float s = 0.f;
    for (int s0 = 0; s0 < per; ++s0) {
      int slot = g * per + s0;
      s += partial[(size_t)(slot * 2 + p) * 512 + c];
    }
    partial2[(size_t)(g * 2 + p) * 512 + c] = s;
  }
}

__global__ void bn_finalize(
    const float* __restrict__ partial2, const float* __restrict__ g,
    const float* __restrict__ beta, float* __restrict__ scale,
    float* __restrict__ shift, int rows)
{
  int c = blockIdx.x * blockDim.x + threadIdx.x;
  if (c >= 512) return;
  float s = 0, s2 = 0;
  for (int b = 0; b < 16; ++b) {
    s  += partial2[(size_t)(b * 2 + 0) * 512 + c];
    s2 += partial2[(size_t)(b * 2 + 1) * 512 + c];
  }
  float m = s / rows;
  float v = s2 / rows - m * m;
  if (v < 0) v = 0;
  float sc = g[c] / sqrtf(v + 1e-5f);
  scale[c] = sc;
  shift[c] = beta[c] - m * sc;
}

__global__ void bn_swish(
    const float* __restrict__ Y, const float* __restrict__ scale,
    const float* __restrict__ shift, float* __restrict__ H, int total4)
{
  int i = blockIdx.x * blockDim.x + threadIdx.x;
  if (i >= total4) return;
  float4 y = ((const float4*)Y)[i];
  int c = (i * 4) & 511;
  float z;
  float4 o;
  z = y.x * scale[c + 0] + shift[c + 0]; o.x = z / (1.f + expf(-z));
  z = y.y * scale[c + 1] + shift[c + 1]; o.y = z / (1.f + expf(-z));
  z = y.z * scale[c + 2] + shift[c + 2]; o.z = z / (1.f + expf(-z));
  z = y.w * scale[c + 3] + shift[c + 3]; o.w = z / (1.f + expf(-z));
  ((float4*)H)[i] = o;
}

// ---------------- positive-label compaction: 3-kernel scan ----------------
__global__ __launch_bounds__(1024) void pos_count(const int* __restrict__ lbl, int n,
                                                  int* __restrict__ cnt,
                                                  int* __restrict__ pos, int P)
{
  int b = blockIdx.x, tid = threadIdx.x;
  int i = b * 1024 + tid;
  if (i < P) pos[i] = 0;          // jnp.nonzero pads with 0
  int pred = (i < n) && (lbl[i] > 0);
  unsigned long long m = __ballot(pred);
  __shared__ int ws[16];
  if ((tid & 63) == 0) ws[tid >> 6] = __popcll(m);
  __syncthreads();
  if (tid == 0) { int s = 0; for (int k = 0; k < 16; ++k) s += ws[k]; cnt[b] = s; }
}

__global__ void pos_prefix(int* __restrict__ cnt, int nb)
{
  if (threadIdx.x == 0) {
    int s = 0;
    for (int b = 0; b < nb; ++b) { int c = cnt[b]; cnt[b] = s; s += c; }
  }
}

__global__ __launch_bounds__(1024) void pos_scatter(const int* __restrict__ lbl, int n,
                                                    const int* __restrict__ cntp,
                                                    int* __restrict__ pos, int P)
{
  int b = blockIdx.x, tid = threadIdx.x;
  int i = b * 1024 + tid;
  int pred = (i < n) && (lbl[i] > 0);
  unsigned long long m = __ballot(pred);
  __shared__ int ws[16];
  int wid = tid >> 6, lane = tid & 63;
  if (lane == 0) ws[wid] = __popcll(m);
  __syncthreads();
  int wbase = 0;
  for (int w2 = 0; w2 < wid; ++w2) wbase += ws[w2];
  int rank = cntp[b] + wbase + __popcll(m & ((1ull << lane) - 1ull));
  if (pred && rank < P) pos[rank] = i;
}

// ---------------- gather positives + sq norms + bf16 copy ----------------
__global__ void gather_sq(const float* __restrict__ H, const int* __restrict__ pos,
                          float* __restrict__ X, unsigned short* __restrict__ Xh,
                          float* __restrict__ sq)
{
  int r = blockIdx.x, t = threadIdx.x;  // 128 threads
  int src = pos[r];
  float4 v = *(const float4*)&H[src * 512 + t * 4];
  *(float4*)&X[r * 512 + t * 4] = v;
  ushort4 hv;
  hv.x = f2bf(v.x); hv.y = f2bf(v.y); hv.z = f2bf(v.z); hv.w = f2bf(v.w);
  *(ushort4*)&Xh[r * 512 + t * 4] = hv;
  float s = v.x * v.x + v.y * v.y + v.z * v.z + v.w * v.w;
#pragma unroll
  for (int off = 32; off > 0; off >>= 1) s += __shfl_down(s, off);
  __shared__ float red[2];
  if ((t & 63) == 0) red[t >> 6] = s;
  __syncthreads();
  if (t == 0) sq[r] = red[0] + red[1];
}

// ------ approx Gram (bf16 MFMA, swapped operands) + in-register top-8 --------
__global__ __launch_bounds__(256, 2) void gram8(
    const unsigned short* __restrict__ Xh, const float* __restrict__ sq, int P,
    float* __restrict__ p8v, int* __restrict__ p8j)
{
  __shared__ char smem[65536];       // 2 x (Ah 16K + Bh 16K); merge overlay at end
  __shared__ float sqj_l[2][128];

  const int tid = threadIdx.x;
  const int w = tid >> 6, lane = tid & 63;
  const int ih = w >> 1, jh = w & 1;
  const int bi = blockIdx.x * 128;
  const int jchunk = P / NSPLIT;        // 1024
  const int jlo = blockIdx.y * jchunk;
  const int ntile = jchunk >> 7;        // 8
  const int total = ntile * 8;

  const int srow = tid >> 3;
  const int scb = (tid & 7) << 4;
  const int fr = lane & 15, fg = lane >> 4;

  float t8[4][8]; int j8[4][8];
#pragma unroll
  for (int mi = 0; mi < 4; ++mi)
#pragma unroll
    for (int q = 0; q < 8; ++q) { t8[mi][q] = NEG_INF; j8[mi][q] = 0x7fffffff; }

  auto STAGE = [&](int s) {
    int kt = (s & 7) << 6;
    int j0 = jlo + ((s >> 3) << 7);
    unsigned short* bA = (unsigned short*)(smem + ((s & 1) << 15));
    unsigned short* bB = bA + 8192;
#pragma unroll
    for (int it = 0; it < 4; ++it) {
      int row = srow + it * 32;
      int cb = scb ^ ((row & 7) << 4);
      gload_lds16(&Xh[(size_t)(bi + row) * 512 + kt + (cb >> 1)], &bA[row * 64 + (scb >> 1)]);
      gload_lds16(&Xh[(size_t)(j0 + row) * 512 + kt + (cb >> 1)], &bB[row * 64 + (scb >> 1)]);
    }
  };

  STAGE(0);
  if (tid < 128) sqj_l[0][tid] = sq[jlo + tid];
  __syncthreads();

  f32x4 acc[4][4];
  for (int s = 0; s < total; ++s) {
    if ((s & 7) == 0) {
#pragma unroll
      for (int a = 0; a < 4; ++a)
#pragma unroll
        for (int b = 0; b < 4; ++b) acc[a][b] = (f32x4){0.f, 0.f, 0.f, 0.f};
    }
    if (s + 1 < total) {
      STAGE(s + 1);
      if (((s + 1) & 7) == 0) {
        int jt1 = (s + 1) >> 3;
        if (tid < 128) sqj_l[jt1 & 1][tid] = sq[jlo + (jt1 << 7) + tid];
      }
    }
    unsigned short* bA = (unsigned short*)(smem + ((s & 1) << 15));
    unsigned short* bB = bA + 8192;
#pragma unroll
    for (int ks = 0; ks < 2; ++ks) {
      bf16x8 af[4], bfr[4];
      int kb = ks * 64 + fg * 16;
#pragma unroll
      for (int mi = 0; mi < 4; ++mi) {
        int row = ih * 64 + mi * 16 + fr;
        af[mi] = *(const bf16x8*)&bA[row * 64 + ((kb ^ ((row & 7) << 4)) >> 1)];
      }
#pragma unroll
      for (int nj = 0; nj < 4; ++nj) {
        int row = jh * 64 + nj * 16 + fr;
        bfr[nj] = *(const bf16x8*)&bB[row * 64 + ((kb ^ ((row & 7) << 4)) >> 1)];
      }
#pragma unroll
      for (int nj = 0; nj < 4; ++nj)
#pragma unroll
        for (int mi = 0; mi < 4; ++mi)
          acc[nj][mi] = __builtin_amdgcn_mfma_f32_16x16x32_bf16(
              bfr[nj], af[mi], acc[nj][mi], 0, 0, 0);
    }
    if ((s & 7) == 7) {          // in-register scan, no barrier needed
      int jt = s >> 3;
      int j0 = jlo + (jt << 7);
      int par = jt & 1;
#pragma unroll
      for (int nj = 0; nj < 4; ++nj) {
        f32x4 sv = *(const f32x4*)&sqj_l[par][jh * 64 + nj * 16 + fg * 4];
        int jb = j0 + jh * 64 + nj * 16 + fg * 4;
#pragma unroll
        for (int mi = 0; mi < 4; ++mi) {
#pragma unroll
          for (int r = 0; r < 4; ++r) {
            float v = 2.0f * acc[nj][mi][r] - sv[r];
            if (v > t8[mi][7]) {
              t8[mi][7] = v; j8[mi][7] = jb + r;
#pragma unroll
              for (int q = 7; q > 0; --q)
                if (t8[mi][q] > t8[mi][q - 1]) {
                  float tv = t8[mi][q]; t8[mi][q] = t8[mi][q - 1]; t8[mi][q - 1] = tv;
                  int tj = j8[mi][q]; j8[mi][q] = j8[mi][q - 1]; j8[mi][q - 1] = tj;
                }
            }
          }
        }
      }
    }
    __syncthreads();
  }

  // cross-lane merge: 4 g-class lists per (i, jh) -> top-8 (overlay on staging)
  float* mv = (float*)smem;
  int* mj = (int*)(smem + 32768);
#pragma unroll
  for (int mi = 0; mi < 4; ++mi)
#pragma unroll
    for (int q = 0; q < 8; ++q) {
      int idx = ((w * 4 + mi) * 16 + fr) * 32 + fg * 8 + q;
      mv[idx] = t8[mi][q]; mj[idx] = j8[mi][q];
    }
  __syncthreads();
  {
    int mi = lane >> 4, cc = lane & 15;
    int base = ((w * 4 + mi) * 16 + cc) * 32;
    int h0 = 0, h1 = 0, h2 = 0, h3 = 0;
    int i = bi + ih * 64 + mi * 16 + cc;
    int set = blockIdx.y * 2 + jh;
    size_t ob = ((size_t)i * (NSPLIT * 2) + set) * 8;
    for (int k = 0; k < 8; ++k) {
      float bv = NEG_INF; int bj = 0x7fffffff; int bg = 0;
      { float v = mv[base + h0];      int jj = mj[base + h0];      if (h0 < 8 && (v > bv || (v == bv && jj < bj))) { bv = v; bj = jj; bg = 0; } }
      { float v = mv[base + 8 + h1];  int jj = mj[base + 8 + h1];  if (h1 < 8 && (v > bv || (v == bv && jj < bj))) { bv = v; bj = jj; bg = 1; } }
      { float v = mv[base + 16 + h2]; int jj = mj[base + 16 + h2]; if (h2 < 8 && (v > bv || (v == bv && jj < bj))) { bv = v; bj = jj; bg = 2; } }
      { float v = mv[base + 24 + h3]; int jj = mj[base + 24 + h3]; if (h3 < 8 && (v > bv || (v == bv && jj < bj))) { bv = v; bj = jj; bg = 3; } }
      h0 += (bg == 0); h1 += (bg == 1); h2 += (bg == 2); h3 += (bg == 3);
      p8v[ob + k] = bv; p8j[ob + k] = bj;
    }
  }
}

// ---------------- merge 16 sorted top-8 lists -> top-8 candidates ----------
__global__ void merge8(const float* __restrict__ p8v, const int* __restrict__ p8j,
                       int* __restrict__ cand, int P)
{
  int i = blockIdx.x * blockDim.x + threadIdx.x;
  if (i >= P) return;
  const int S = NSPLIT * 2;
  int head[S];
#pragma unroll
  for (int s = 0; s < S; ++s) head[s] = 0;
  const float* v = p8v + (size_t)i * S * 8;
  const int* j = p8j + (size_t)i * S * 8;
  for (int k = 0; k < 8; ++k) {
    float bv = NEG_INF; int bj = 0x7fffffff; int bs = 0;
#pragma unroll
    for (int s = 0; s < S; ++s) {
      if (head[s] < 8) {
        float vv = v[s * 8 + head[s]];
        int jj = j[s * 8 + head[s]];
        if (vv > bv || (vv == bv && jj < bj)) { bv = vv; bj = jj; bs = s; }
      }
    }
    head[bs]++;
    cand[i * 8 + k] = bj;
  }
}

// ---------------- exact fp32 rescore of 8 candidates -> top-3 --------------
__global__ __launch_bounds__(64) void rescore(
    const float* __restrict__ X, const float* __restrict__ sq,
    const int* __restrict__ cand, int* __restrict__ idx3)
{
  int i = blockIdx.x;
  int lane = threadIdx.x;
  f32x4 x0 = *(const f32x4*)&X[(size_t)i * 512 + lane * 8];
  f32x4 x1 = *(const f32x4*)&X[(size_t)i * 512 + lane * 8 + 4];
  float d[8]; int cj[8];
#pragma unroll
  for (int c = 0; c < 8; ++c) {
    int j = cand[i * 8 + c];
    cj[c] = j;
    f32x4 y0 = *(const f32x4*)&X[(size_t)j * 512 + lane * 8];
    f32x4 y1 = *(const f32x4*)&X[(size_t)j * 512 + lane * 8 + 4];
    float p = x0.x * y0.x + x0.y * y0.y + x0.z * y0.z + x0.w * y0.w
            + x1.x * y1.x + x1.y * y1.y + x1.z * y1.z + x1.w * y1.w;
#pragma unroll
    for (int off = 32; off > 0; off >>= 1) p += __shfl_xor(p, off);
    d[c] = 2.0f * p - sq[i] - sq[j];
  }
  if (lane == 0) {
    for (int k = 0; k < 3; ++k) {
      int b = 0;
#pragma unroll
      for (int c = 1; c < 8; ++c)
        if (d[c] > d[b] || (d[c] == d[b] && cj[c] < cj[b])) b = c;
      idx3[i * 3 + k] = cj[b];
      d[b] = NEG_INF; cj[b] = 0x7fffffff;
    }
  }
}

// ---------------- SMOTE lerp rows ----------------
__global__ void make_newfea(const float* __restrict__ X, const int* __restrict__ idx3,
                            const float* __restrict__ lw, float* __restrict__ out)
{
  int r = blockIdx.x;
  int i = r / 3, k = r - i * 3;
  int ai = idx3[i * 3 + 0];
  int bi = idx3[i * 3 + k];
  float w = lw[r];
  int t = threadIdx.x;
  float4 av = *(const float4*)&X[ai * 512 + t * 4];
  float4 bv = *(const float4*)&X[bi * 512 + t * 4];
  float4 o;
  o.x = av.x + w * (bv.x - av.x);
  o.y = av.y + w * (bv.y - av.y);
  o.z = av.z + w * (bv.z - av.z);
  o.w = av.w + w * (bv.w - av.w);
  *(float4*)&out[(size_t)r * 512 + t * 4] = o;
}

__global__ void write_lbl(const int* __restrict__ lbl, float* __restrict__ out,
                          int n_in, int n_total)
{
  int i = blockIdx.x * blockDim.x + threadIdx.x;
  if (i < n_total) out[i] = (i < n_in) ? (float)lbl[i] : 1.0f;
}

// ---------------- launch ----------------
extern "C" void kernel_launch(void* const* d_in, const int* in_sizes, int n_in,
                              void* d_out, int out_size, void* d_ws, size_t ws_size,
                              hipStream_t stream)
{
  const float* fea   = (const float*)d_in[0];
  const int*   lbl   = (const int*)d_in[1];
  const float* W1    = (const float*)d_in[2];
  const float* b1    = (const float*)d_in[3];
  const float* g1    = (const float*)d_in[4];
  const float* beta1 = (const float*)d_in[5];
  const float* W2    = (const float*)d_in[6];
  const float* b2    = (const float*)d_in[7];
  const float* g2    = (const float*)d_in[8];
  const float* beta2 = (const float*)d_in[9];
  const float* lerp_w = (const float*)d_in[10];

  int bs = in_sizes[0] / 512;       // 32768
  int P  = in_sizes[10] / 3;        // 8192
  int n_total = bs + 3 * P;         // 57344

  float* out_f = (float*)d_out;
  float* Hout = out_f;
  float* newfea = out_f + (size_t)bs * 512;
  float* lbl_out = out_f + (size_t)n_total * 512;

  const size_t MB = 1024 * 1024;
  const size_t KB = 1024;
  char* ws = (char*)d_ws;
  float* Y1 = (float*)ws;                                  // 64MB fp32 y1 -> h1
  float* X  = (float*)(ws + 64 * MB);                      // 16MB (after weights dead)
  unsigned short* W1h = (unsigned short*)(ws + 64 * MB);
  unsigned short* W1m = (unsigned short*)(ws + 64 * MB + 512 * KB);
  unsigned short* W1l = (unsigned short*)(ws + 64 * MB + 1024 * KB);
  unsigned short* W2h = (unsigned short*)(ws + 64 * MB + 1536 * KB);
  unsigned short* W2m = (unsigned short*)(ws + 64 * MB + 2048 * KB);
  unsigned short* W2l = (unsigned short*)(ws + 64 * MB + 2560 * KB);
  float* partial = (float*)(ws + 80 * MB);                 // 2MB
  float* scale = (float*)(ws + 82 * MB);
  float* shiftv = scale + 512;
  float* sq = shiftv + 512;
  int* pos = (int*)(sq + 8192);
  int* idx3 = pos + 8192;
  int* cnt = idx3 + 3 * 8192;                              // 32 ints
  float* partial2 = (float*)(ws + 83 * MB);                // 64KB
  // overlays in dead Y1 region (used only after gemm2):
  unsigned short* Xh = (unsigned short*)ws;                // 8MB
  float* p8v = (float*)(ws + 8 * MB);                      // 4MB
  int*   p8j = (int*)(ws + 12 * MB);                       // 4MB
  int*   cand = (int*)(ws + 16 * MB);                      // 256KB

  dim3 wgrid(8, 8);
  split_w_t3<<<wgrid, 256, 0, stream>>>(W1, W1h, W1m, W1l);
  split_w_t3<<<wgrid, 256, 0, stream>>>(W2, W2h, W2m, W2l);

  dim3 ggrid(bs / 128, 4);
  int nslot = (bs / 128) * 2;          // 512
  dim3 rgrid(16, 2);

  gemm_split3<<<ggrid, 256, 0, stream>>>(fea, W1h, W1m, W1l, b1, Y1, partial);
  bn_reduce1<<<rgrid, 256, 0, stream>>>(partial, partial2, nslot);
  bn_finalize<<<2, 256, 0, stream>>>(partial2, g1, beta1, scale, shiftv, bs);
  bn_swish<<<(bs * 512 / 4 + 255) / 256, 256, 0, stream>>>(Y1, scale, shiftv, Y1, bs * 512 / 4);

  gemm_split3<<<ggrid, 256, 0, stream>>>(Y1, W2h, W2m, W2l, b2, Hout, partial);
  bn_reduce1<<<rgrid, 256, 0, stream>>>(partial, partial2, nslot);
  bn_finalize<<<2, 256, 0, stream>>>(partial2, g2, beta2, scale, shiftv, bs);
  bn_swish<<<(bs * 512 / 4 + 255) / 256, 256, 0, stream>>>(Hout, scale, shiftv, Hout, bs * 512 / 4);

  int nb = (bs + 1023) / 1024;         // 32
  pos_count<<<nb, 1024, 0, stream>>>(lbl, bs, cnt, pos, P);
  pos_prefix<<<1, 64, 0, stream>>>(cnt, nb);
  pos_scatter<<<nb, 1024, 0, stream>>>(lbl, bs, cnt, pos, P);
  gather_sq<<<P, 128, 0, stream>>>(Hout, pos, X, Xh, sq);

  dim3 gram_grid(P / 128, NSPLIT);
  gram8<<<gram_grid, 256, 0, stream>>>(Xh, sq, P, p8v, p8j);
  merge8<<<(P + 255) / 256, 256, 0, stream>>>(p8v, p8j, cand, P);
  rescore<<<P, 64, 0, stream>>>(X, sq, cand, idx3);

  make_newfea<<<3 * P, 128, 0, stream>>>(X, idx3, lerp_w, newfea);
  write_lbl<<<(n_total + 255) / 256, 256, 0, stream>>>(lbl, lbl_out, bs, n_total);
}

// Round 7
// 529.742 us; speedup vs baseline: 4.3064x; 1.0128x over previous
//
#include <hip/hip_runtime.h>
#include <math.h>

#define NEG_INF -3.402823466e38f
#define NSPLIT 16

typedef __attribute__((ext_vector_type(8))) short bf16x8;
typedef __attribute__((ext_vector_type(4))) float f32x4;

__device__ __forceinline__ void gload_lds16(const unsigned short* g, unsigned short* l) {
  __builtin_amdgcn_global_load_lds(
      (const __attribute__((address_space(1))) unsigned int*)g,
      (__attribute__((address_space(3))) unsigned int*)l, 16, 0, 0);
}
__device__ __forceinline__ void gload_lds16f(const float* g, float* l) {
  __builtin_amdgcn_global_load_lds(
      (const __attribute__((address_space(1))) unsigned int*)g,
      (__attribute__((address_space(3))) unsigned int*)l, 16, 0, 0);
}

__device__ __forceinline__ unsigned short f2bf(float f) {
  union { float f; unsigned int u; } a; a.f = f;
  unsigned int u = a.u;
  return (unsigned short)((u + 0x7fffu + ((u >> 16) & 1u)) >> 16);
}

// pairwise 3-term truncation split: 8 f32 -> hi/mid/lo bf16x8.
__device__ __forceinline__ void split3_8(f32x4 a, f32x4 b,
                                         bf16x8& hi, bf16x8& md, bf16x8& lo) {
  union { bf16x8 v; unsigned int u[4]; } H, M, L;
  float f[8];
  f[0]=a[0]; f[1]=a[1]; f[2]=a[2]; f[3]=a[3];
  f[4]=b[0]; f[5]=b[1]; f[6]=b[2]; f[7]=b[3];
#pragma unroll
  for (int p = 0; p < 4; ++p) {
    union { float f; unsigned int u; } x0, x1, h0, h1, r0, r1, m0, m1, s0, s1;
    x0.f = f[2*p]; x1.f = f[2*p+1];
    H.u[p] = (x0.u >> 16) | (x1.u & 0xffff0000u);
    h0.u = x0.u & 0xffff0000u; h1.u = x1.u & 0xffff0000u;
    r0.f = x0.f - h0.f;        r1.f = x1.f - h1.f;
    M.u[p] = (r0.u >> 16) | (r1.u & 0xffff0000u);
    m0.u = r0.u & 0xffff0000u; m1.u = r1.u & 0xffff0000u;
    s0.f = r0.f - m0.f;        s1.f = r1.f - m1.f;
    L.u[p] = (s0.u >> 16) | (s1.u & 0xffff0000u);
  }
  hi = H.v; md = M.v; lo = L.v;
}

// ------ split+transpose weights: W[512][512] -> Wt_{h,m,l}[n][k] --------------
__global__ __launch_bounds__(256) void split_w_t3(const float* __restrict__ W,
    unsigned short* __restrict__ Th, unsigned short* __restrict__ Tm,
    unsigned short* __restrict__ Tl)
{
  __shared__ float T[64][65];
  int k0 = blockIdx.x * 64, n0 = blockIdx.y * 64;
  int tid = threadIdx.x;
  int r = tid >> 4, c4 = (tid & 15) << 2;
#pragma unroll
  for (int p = 0; p < 4; ++p) {
    int row = r + p * 16;
    float4 v = *(const float4*)&W[(size_t)(k0 + row) * 512 + n0 + c4];
    T[c4 + 0][row] = v.x; T[c4 + 1][row] = v.y;
    T[c4 + 2][row] = v.z; T[c4 + 3][row] = v.w;
  }
  __syncthreads();
  int nr = tid >> 2, kc = (tid & 3) << 4;
#pragma unroll
  for (int u = 0; u < 16; ++u) {
    union { float f; unsigned int u; } x, h, rr, m, ss;
    x.f = T[nr][kc + u];
    unsigned short hb = (unsigned short)(x.u >> 16);
    h.u = x.u & 0xffff0000u;
    rr.f = x.f - h.f;
    unsigned short mb = (unsigned short)(rr.u >> 16);
    m.u = rr.u & 0xffff0000u;
    ss.f = rr.f - m.f;
    unsigned short lb = (unsigned short)(ss.u >> 16);
    size_t o = (size_t)(n0 + nr) * 512 + k0 + kc + u;
    Th[o] = hb; Tm[o] = mb; Tl[o] = lb;
  }
}

// ------ GEMM: double-buffered BK=32, 6-MFMA fp32-emulation + BN partials ------
__global__ __launch_bounds__(256, 2) void gemm_split3(
    const float* __restrict__ A, const unsigned short* __restrict__ Bth,
    const unsigned short* __restrict__ Btm, const unsigned short* __restrict__ Btl,
    const float* __restrict__ bias, float* __restrict__ C, float* __restrict__ partial)
{
  __shared__ char smem[81920];   // 2 x (sA 16K + 3x8K B)
  const int tid = threadIdx.x;
  const int w = tid >> 6, lane = tid & 63;
  const int wr = w >> 1, wc = w & 1;
  const int bm = blockIdx.x * 128, bn = blockIdx.y * 128;
  const int fr = lane & 15, fg = lane >> 4;
  const int arow = tid >> 3, acb = (tid & 7) << 4;   // A: 8 lanes x 16B per 128B row
  const int brow = tid >> 2, bcb = (tid & 3) << 4;   // B: 4 lanes x 16B per 64B row

  f32x4 acc[4][4];
#pragma unroll
  for (int mi = 0; mi < 4; ++mi)
#pragma unroll
    for (int ni = 0; ni < 4; ++ni) acc[mi][ni] = (f32x4){0.f, 0.f, 0.f, 0.f};

  auto STAGE = [&](int buf, int ktf) {
    float* sA = (float*)(smem + buf * 40960);
    unsigned short* sBh = (unsigned short*)(smem + buf * 40960 + 16384);
    unsigned short* sBm = sBh + 4096;
    unsigned short* sBl = sBm + 4096;
#pragma unroll
    for (int p = 0; p < 4; ++p) {
      int row = arow + p * 32;
      int cb = acb ^ ((row & 7) << 4);
      gload_lds16f(&A[(size_t)(bm + row) * 512 + ktf + (cb >> 2)],
                   &sA[row * 32 + (acb >> 2)]);
    }
#pragma unroll
    for (int p = 0; p < 2; ++p) {
      int row = brow + p * 64;
      int cb = bcb ^ (((row >> 1) & 3) << 4);
      int so = row * 32 + (bcb >> 1);
      gload_lds16(&Bth[(size_t)(bn + row) * 512 + ktf + (cb >> 1)], &sBh[so]);
      gload_lds16(&Btm[(size_t)(bn + row) * 512 + ktf + (cb >> 1)], &sBm[so]);
      gload_lds16(&Btl[(size_t)(bn + row) * 512 + ktf + (cb >> 1)], &sBl[so]);
    }
  };

  STAGE(0, 0);
  __syncthreads();
  for (int it = 0; it < 16; ++it) {
    int cur = it & 1;
    if (it + 1 < 16) STAGE(cur ^ 1, (it + 1) * 32);
    float* sA = (float*)(smem + cur * 40960);
    unsigned short* sBh = (unsigned short*)(smem + cur * 40960 + 16384);
    unsigned short* sBm = sBh + 4096;
    unsigned short* sBl = sBm + 4096;
    bf16x8 bh[4], bmf[4], blf[4];
#pragma unroll
    for (int ni = 0; ni < 4; ++ni) {
      int row = wc * 64 + ni * 16 + fr;
      int off = row * 32 + (((fg * 16) ^ (((row >> 1) & 3) << 4)) >> 1);
      bh[ni]  = *(const bf16x8*)&sBh[off];
      bmf[ni] = *(const bf16x8*)&sBm[off];
      blf[ni] = *(const bf16x8*)&sBl[off];
    }
    bf16x8 ah[4], am[4], al[4];
#pragma unroll
    for (int mi = 0; mi < 4; ++mi) {
      int row = wr * 64 + mi * 16 + fr;
      int swz = (row & 7) << 4;
      const char* rb = (const char*)(sA + row * 32);
      f32x4 f0 = *(const f32x4*)(rb + ((fg * 32) ^ swz));
      f32x4 f1 = *(const f32x4*)(rb + ((fg * 32 + 16) ^ swz));
      split3_8(f0, f1, ah[mi], am[mi], al[mi]);
    }
#pragma unroll
    for (int mi = 0; mi < 4; ++mi)
#pragma unroll
      for (int ni = 0; ni < 4; ++ni) {
        acc[mi][ni] = __builtin_amdgcn_mfma_f32_16x16x32_bf16(al[mi], bh[ni],  acc[mi][ni], 0, 0, 0);
        acc[mi][ni] = __builtin_amdgcn_mfma_f32_16x16x32_bf16(am[mi], bmf[ni], acc[mi][ni], 0, 0, 0);
        acc[mi][ni] = __builtin_amdgcn_mfma_f32_16x16x32_bf16(ah[mi], blf[ni], acc[mi][ni], 0, 0, 0);
        acc[mi][ni] = __builtin_amdgcn_mfma_f32_16x16x32_bf16(am[mi], bh[ni],  acc[mi][ni], 0, 0, 0);
        acc[mi][ni] = __builtin_amdgcn_mfma_f32_16x16x32_bf16(ah[mi], bmf[ni], acc[mi][ni], 0, 0, 0);
        acc[mi][ni] = __builtin_amdgcn_mfma_f32_16x16x32_bf16(ah[mi], bh[ni],  acc[mi][ni], 0, 0, 0);
      }
    __syncthreads();
  }
  float bno[4], s[4] = {0, 0, 0, 0}, q[4] = {0, 0, 0, 0};
#pragma unroll
  for (int ni = 0; ni < 4; ++ni) bno[ni] = bias[bn + wc * 64 + ni * 16 + fr];
#pragma unroll
  for (int mi = 0; mi < 4; ++mi) {
    int row = bm + wr * 64 + mi * 16 + fg * 4;
#pragma unroll
    for (int ni = 0; ni < 4; ++ni) {
      int col = bn + wc * 64 + ni * 16 + fr;
#pragma unroll
      for (int r = 0; r < 4; ++r) {
        float v = acc[mi][ni][r] + bno[ni];
        C[(size_t)(row + r) * 512 + col] = v;
        s[ni] += v; q[ni] += v * v;
      }
    }
  }
#pragma unroll
  for (int ni = 0; ni < 4; ++ni) {
    float ss = s[ni], qq = q[ni];
    ss += __shfl_xor(ss, 16); ss += __shfl_xor(ss, 32);
    qq += __shfl_xor(qq, 16); qq += __shfl_xor(qq, 32);
    if (fg == 0) {
      int slot = blockIdx.x * 2 + wr;
      int col = bn + wc * 64 + ni * 16 + fr;
      partial[(size_t)(slot * 2 + 0) * 512 + col] = ss;
      partial[(size_t)(slot * 2 + 1) * 512 + col] = qq;
    }
  }
}

// ------ BN reduce stage 1: fold nslot slots into 16 groups (coalesced) --------
__global__ __launch_bounds__(256) void bn_reduce1(
    const float* __restrict__ partial, float* __restrict__ partial2, int nslot)
{
  int g = blockIdx.x, p = blockIdx.y;
  int per = nslot >> 4;
  int t = threadIdx.x;
#pragma unroll
  for (int cc = 0; cc < 2; ++cc) {
    int c = t + cc * 256;
    float s = 0.f;
    for (int s0 = 0; s0 < per; ++s0) {
      int slot = g * per + s0;
      s += partial[(size_t)(slot * 2 + p) * 512 + c];
    }
    partial2[(size_t)(g * 2 + p) * 512 + c] = s;
  }
}

__global__ void bn_finalize(
    const float* __restrict__ partial2, const float* __restrict__ g,
    const float* __restrict__ beta, float* __restrict__ scale,
    float* __restrict__ shift, int rows)
{
  int c = blockIdx.x * blockDim.x + threadIdx.x;
  if (c >= 512) return;
  float s = 0, s2 = 0;
  for (int b = 0; b < 16; ++b) {
    s  += partial2[(size_t)(b * 2 + 0) * 512 + c];
    s2 += partial2[(size_t)(b * 2 + 1) * 512 + c];
  }
  float m = s / rows;
  float v = s2 / rows - m * m;
  if (v < 0) v = 0;
  float sc = g[c] / sqrtf(v + 1e-5f);
  scale[c] = sc;
  shift[c] = beta[c] - m * sc;
}

__global__ void bn_swish(
    const float* __restrict__ Y, const float* __restrict__ scale,
    const float* __restrict__ shift, float* __restrict__ H, int total4)
{
  int i = blockIdx.x * blockDim.x + threadIdx.x;
  if (i >= total4) return;
  float4 y = ((const float4*)Y)[i];
  int c = (i * 4) & 511;
  float z;
  float4 o;
  z = y.x * scale[c + 0] + shift[c + 0]; o.x = z / (1.f + expf(-z));
  z = y.y * scale[c + 1] + shift[c + 1]; o.y = z / (1.f + expf(-z));
  z = y.z * scale[c + 2] + shift[c + 2]; o.z = z / (1.f + expf(-z));
  z = y.w * scale[c + 3] + shift[c + 3]; o.w = z / (1.f + expf(-z));
  ((float4*)H)[i] = o;
}

// ---------------- positive-label compaction: 3-kernel scan ----------------
__global__ __launch_bounds__(1024) void pos_count(const int* __restrict__ lbl, int n,
                                                  int* __restrict__ cnt,
                                                  int* __restrict__ pos, int P)
{
  int b = blockIdx.x, tid = threadIdx.x;
  int i = b * 1024 + tid;
  if (i < P) pos[i] = 0;          // jnp.nonzero pads with 0
  int pred = (i < n) && (lbl[i] > 0);
  unsigned long long m = __ballot(pred);
  __shared__ int ws[16];
  if ((tid & 63) == 0) ws[tid >> 6] = __popcll(m);
  __syncthreads();
  if (tid == 0) { int s = 0; for (int k = 0; k < 16; ++k) s += ws[k]; cnt[b] = s; }
}

__global__ void pos_prefix(int* __restrict__ cnt, int nb)
{
  if (threadIdx.x == 0) {
    int s = 0;
    for (int b = 0; b < nb; ++b) { int c = cnt[b]; cnt[b] = s; s += c; }
  }
}

__global__ __launch_bounds__(1024) void pos_scatter(const int* __restrict__ lbl, int n,
                                                    const int* __restrict__ cntp,
                                                    int* __restrict__ pos, int P)
{
  int b = blockIdx.x, tid = threadIdx.x;
  int i = b * 1024 + tid;
  int pred = (i < n) && (lbl[i] > 0);
  unsigned long long m = __ballot(pred);
  __shared__ int ws[16];
  int wid = tid >> 6, lane = tid & 63;
  if (lane == 0) ws[wid] = __popcll(m);
  __syncthreads();
  int wbase = 0;
  for (int w2 = 0; w2 < wid; ++w2) wbase += ws[w2];
  int rank = cntp[b] + wbase + __popcll(m & ((1ull << lane) - 1ull));
  if (pred && rank < P) pos[rank] = i;
}

// ---------------- gather positives + sq norms + bf16 copy ----------------
__global__ void gather_sq(const float* __restrict__ H, const int* __restrict__ pos,
                          float* __restrict__ X, unsigned short* __restrict__ Xh,
                          float* __restrict__ sq)
{
  int r = blockIdx.x, t = threadIdx.x;  // 128 threads
  int src = pos[r];
  float4 v = *(const float4*)&H[src * 512 + t * 4];
  *(float4*)&X[r * 512 + t * 4] = v;
  ushort4 hv;
  hv.x = f2bf(v.x); hv.y = f2bf(v.y); hv.z = f2bf(v.z); hv.w = f2bf(v.w);
  *(ushort4*)&Xh[r * 512 + t * 4] = hv;
  float s = v.x * v.x + v.y * v.y + v.z * v.z + v.w * v.w;
#pragma unroll
  for (int off = 32; off > 0; off >>= 1) s += __shfl_down(s, off);
  __shared__ float red[2];
  if ((t & 63) == 0) red[t >> 6] = s;
  __syncthreads();
  if (t == 0) sq[r] = red[0] + red[1];
}

// ---------------- approx Gram (bf16 MFMA) + running top-8 ----------------
__global__ __launch_bounds__(256, 2) void gram8(
    const unsigned short* __restrict__ Xh, const float* __restrict__ sq, int P,
    float* __restrict__ p8v, int* __restrict__ p8j)
{
  __shared__ unsigned short Ah[128 * 64];
  __shared__ unsigned short Bh[128 * 64];
  __shared__ float dl[4][64][17];
  __shared__ float sqj_l[128];

  const int tid = threadIdx.x;
  const int w = tid >> 6, lane = tid & 63;
  const int wr = w >> 1, wc = w & 1;
  const int bi = blockIdx.x * 128;
  const int jchunk = P / NSPLIT;         // 512
  const int jlo = blockIdx.y * jchunk;

  const int srow = tid >> 3;
  const int scb  = (tid & 7) << 4;
  const int fr = lane & 15, fg = lane >> 4;

  float t[8]; int ji[8];
#pragma unroll
  for (int q = 0; q < 8; ++q) { t[q] = NEG_INF; ji[q] = 0x7fffffff; }

  for (int jt = 0; jt < jchunk; jt += 128) {
    const int j0 = jlo + jt;
    if (tid < 128) sqj_l[tid] = sq[j0 + tid];
    f32x4 acc[4][4];
#pragma unroll
    for (int mi = 0; mi < 4; ++mi)
#pragma unroll
      for (int ni = 0; ni < 4; ++ni) acc[mi][ni] = (f32x4){0.f, 0.f, 0.f, 0.f};

    for (int kt = 0; kt < 512; kt += 64) {
#pragma unroll
      for (int it = 0; it < 4; ++it) {
        int row = srow + it * 32;
        int cb = scb ^ ((row & 7) << 4);
        gload_lds16(&Xh[(size_t)(bi + row) * 512 + kt + (cb >> 1)],
                    &Ah[row * 64 + (scb >> 1)]);
        gload_lds16(&Xh[(size_t)(j0 + row) * 512 + kt + (cb >> 1)],
                    &Bh[row * 64 + (scb >> 1)]);
      }
      __syncthreads();
#pragma unroll
      for (int ks = 0; ks < 2; ++ks) {
        bf16x8 af[4], bfr[4];
        int kb = ks * 64 + fg * 16;
#pragma unroll
        for (int mi = 0; mi < 4; ++mi) {
          int row = wr * 64 + mi * 16 + fr;
          af[mi] = *(const bf16x8*)&Ah[row * 64 + ((kb ^ ((row & 7) << 4)) >> 1)];
        }
#pragma unroll
        for (int ni = 0; ni < 4; ++ni) {
          int row = wc * 64 + ni * 16 + fr;
          bfr[ni] = *(const bf16x8*)&Bh[row * 64 + ((kb ^ ((row & 7) << 4)) >> 1)];
        }
#pragma unroll
        for (int mi = 0; mi < 4; ++mi)
#pragma unroll
          for (int ni = 0; ni < 4; ++ni)
            acc[mi][ni] = __builtin_amdgcn_mfma_f32_16x16x32_bf16(
                af[mi], bfr[ni], acc[mi][ni], 0, 0, 0);
      }
      __syncthreads();
    }

#pragma unroll
    for (int qn = 0; qn < 4; ++qn) {
      float sqv = sqj_l[wc * 64 + qn * 16 + fr];
#pragma unroll
      for (int mi = 0; mi < 4; ++mi)
#pragma unroll
        for (int r = 0; r < 4; ++r)
          dl[w][mi * 16 + fg * 4 + r][fr] = 2.0f * acc[mi][qn][r] - sqv;
      __syncthreads();
      int jbase = j0 + wc * 64 + qn * 16;
      for (int c = 0; c < 16; ++c) {
        float v = dl[w][lane][c];
        if (v > t[7]) {
          t[7] = v; ji[7] = jbase + c;
#pragma unroll
          for (int q = 7; q > 0; --q) {
            if (t[q] > t[q - 1]) {
              float tv = t[q]; t[q] = t[q - 1]; t[q - 1] = tv;
              int tj = ji[q]; ji[q] = ji[q - 1]; ji[q - 1] = tj;
            }
          }
        }
      }
      __syncthreads();
    }
  }

  int row = bi + wr * 64 + lane;
  int set = blockIdx.y * 2 + wc;
  size_t base = ((size_t)row * (NSPLIT * 2) + set) * 8;
#pragma unroll
  for (int q = 0; q < 8; ++q) { p8v[base + q] = t[q]; p8j[base + q] = ji[q]; }
}

// ---------------- merge 32 sorted top-8 lists -> top-8 candidates ----------
__global__ void merge8(const float* __restrict__ p8v, const int* __restrict__ p8j,
                       int* __restrict__ cand, int P)
{
  int i = blockIdx.x * blockDim.x + threadIdx.x;
  if (i >= P) return;
  const int S = NSPLIT * 2;
  int head[S];
#pragma unroll
  for (int s = 0; s < S; ++s) head[s] = 0;
  const float* v = p8v + (size_t)i * S * 8;
  const int* j = p8j + (size_t)i * S * 8;
  for (int k = 0; k < 8; ++k) {
    float bv = NEG_INF; int bj = 0x7fffffff; int bs = 0;
#pragma unroll
    for (int s = 0; s < S; ++s) {
      if (head[s] < 8) {
        float vv = v[s * 8 + head[s]];
        int jj = j[s * 8 + head[s]];
        if (vv > bv || (vv == bv && jj < bj)) { bv = vv; bj = jj; bs = s; }
      }
    }
    head[bs]++;
    cand[i * 8 + k] = bj;
  }
}

// ---------------- exact fp32 rescore of 8 candidates -> top-3 --------------
__global__ __launch_bounds__(64) void rescore(
    const float* __restrict__ X, const float* __restrict__ sq,
    const int* __restrict__ cand, int* __restrict__ idx3)
{
  int i = blockIdx.x;
  int lane = threadIdx.x;
  f32x4 x0 = *(const f32x4*)&X[(size_t)i * 512 + lane * 8];
  f32x4 x1 = *(const f32x4*)&X[(size_t)i * 512 + lane * 8 + 4];
  float d[8]; int cj[8];
#pragma unroll
  for (int c = 0; c < 8; ++c) {
    int j = cand[i * 8 + c];
    cj[c] = j;
    f32x4 y0 = *(const f32x4*)&X[(size_t)j * 512 + lane * 8];
    f32x4 y1 = *(const f32x4*)&X[(size_t)j * 512 + lane * 8 + 4];
    float p = x0.x * y0.x + x0.y * y0.y + x0.z * y0.z + x0.w * y0.w
            + x1.x * y1.x + x1.y * y1.y + x1.z * y1.z + x1.w * y1.w;
#pragma unroll
    for (int off = 32; off > 0; off >>= 1) p += __shfl_xor(p, off);
    d[c] = 2.0f * p - sq[i] - sq[j];
  }
  if (lane == 0) {
    for (int k = 0; k < 3; ++k) {
      int b = 0;
#pragma unroll
      for (int c = 1; c < 8; ++c)
        if (d[c] > d[b] || (d[c] == d[b] && cj[c] < cj[b])) b = c;
      idx3[i * 3 + k] = cj[b];
      d[b] = NEG_INF; cj[b] = 0x7fffffff;
    }
  }
}

// ---------------- SMOTE lerp rows ----------------
__global__ void make_newfea(const float* __restrict__ X, const int* __restrict__ idx3,
                            const float* __restrict__ lw, float* __restrict__ out)
{
  int r = blockIdx.x;
  int i = r / 3, k = r - i * 3;
  int ai = idx3[i * 3 + 0];
  int bi = idx3[i * 3 + k];
  float w = lw[r];
  int t = threadIdx.x;
  float4 av = *(const float4*)&X[ai * 512 + t * 4];
  float4 bv = *(const float4*)&X[bi * 512 + t * 4];
  float4 o;
  o.x = av.x + w * (bv.x - av.x);
  o.y = av.y + w * (bv.y - av.y);
  o.z = av.z + w * (bv.z - av.z);
  o.w = av.w + w * (bv.w - av.w);
  *(float4*)&out[(size_t)r * 512 + t * 4] = o;
}

__global__ void write_lbl(const int* __restrict__ lbl, float* __restrict__ out,
                          int n_in, int n_total)
{
  int i = blockIdx.x * blockDim.x + threadIdx.x;
  if (i < n_total) out[i] = (i < n_in) ? (float)lbl[i] : 1.0f;
}

// ---------------- launch ----------------
extern "C" void kernel_launch(void* const* d_in, const int* in_sizes, int n_in,
                              void* d_out, int out_size, void* d_ws, size_t ws_size,
                              hipStream_t stream)
{
  const float* fea   = (const float*)d_in[0];
  const int*   lbl   = (const int*)d_in[1];
  const float* W1    = (const float*)d_in[2];
  const float* b1    = (const float*)d_in[3];
  const float* g1    = (const float*)d_in[4];
  const float* beta1 = (const float*)d_in[5];
  const float* W2    = (const float*)d_in[6];
  const float* b2    = (const float*)d_in[7];
  const float* g2    = (const float*)d_in[8];
  const float* beta2 = (const float*)d_in[9];
  const float* lerp_w = (const float*)d_in[10];

  int bs = in_sizes[0] / 512;       // 32768
  int P  = in_sizes[10] / 3;        // 8192
  int n_total = bs + 3 * P;         // 57344

  float* out_f = (float*)d_out;
  float* Hout = out_f;
  float* newfea = out_f + (size_t)bs * 512;
  float* lbl_out = out_f + (size_t)n_total * 512;

  const size_t MB = 1024 * 1024;
  const size_t KB = 1024;
  char* ws = (char*)d_ws;
  float* Y1 = (float*)ws;                                  // 64MB fp32 y1 -> h1
  float* X  = (float*)(ws + 64 * MB);                      // 16MB (after weights dead)
  unsigned short* W1h = (unsigned short*)(ws + 64 * MB);
  unsigned short* W1m = (unsigned short*)(ws + 64 * MB + 512 * KB);
  unsigned short* W1l = (unsigned short*)(ws + 64 * MB + 1024 * KB);
  unsigned short* W2h = (unsigned short*)(ws + 64 * MB + 1536 * KB);
  unsigned short* W2m = (unsigned short*)(ws + 64 * MB + 2048 * KB);
  unsigned short* W2l = (unsigned short*)(ws + 64 * MB + 2560 * KB);
  float* partial = (float*)(ws + 80 * MB);                 // 2MB
  float* scale = (float*)(ws + 82 * MB);
  float* shiftv = scale + 512;
  float* sq = shiftv + 512;
  int* pos = (int*)(sq + 8192);
  int* idx3 = pos + 8192;
  int* cnt = idx3 + 3 * 8192;                              // 32 ints
  float* partial2 = (float*)(ws + 83 * MB);                // 64KB
  // overlays in dead Y1 region (used only after gemm2):
  unsigned short* Xh = (unsigned short*)ws;                // 8MB
  float* p8v = (float*)(ws + 8 * MB);                      // 8MB (8192 x 32 x 8)
  int*   p8j = (int*)(ws + 16 * MB);                       // 8MB
  int*   cand = (int*)(ws + 24 * MB);                      // 256KB

  dim3 wgrid(8, 8);
  split_w_t3<<<wgrid, 256, 0, stream>>>(W1, W1h, W1m, W1l);
  split_w_t3<<<wgrid, 256, 0, stream>>>(W2, W2h, W2m, W2l);

  dim3 ggrid(bs / 128, 4);
  int nslot = (bs / 128) * 2;          // 512
  dim3 rgrid(16, 2);

  gemm_split3<<<ggrid, 256, 0, stream>>>(fea, W1h, W1m, W1l, b1, Y1, partial);
  bn_reduce1<<<rgrid, 256, 0, stream>>>(partial, partial2, nslot);
  bn_finalize<<<2, 256, 0, stream>>>(partial2, g1, beta1, scale, shiftv, bs);
  bn_swish<<<(bs * 512 / 4 + 255) / 256, 256, 0, stream>>>(Y1, scale, shiftv, Y1, bs * 512 / 4);

  gemm_split3<<<ggrid, 256, 0, stream>>>(Y1, W2h, W2m, W2l, b2, Hout, partial);
  bn_reduce1<<<rgrid, 256, 0, stream>>>(partial, partial2, nslot);
  bn_finalize<<<2, 256, 0, stream>>>(partial2, g2, beta2, scale, shiftv, bs);
  bn_swish<<<(bs * 512 / 4 + 255) / 256, 256, 0, stream>>>(Hout, scale, shiftv, Hout, bs * 512 / 4);

  int nb = (bs + 1023) / 1024;         // 32
  pos_count<<<nb, 1024, 0, stream>>>(lbl, bs, cnt, pos, P);
  pos_prefix<<<1, 64, 0, stream>>>(cnt, nb);
  pos_scatter<<<nb, 1024, 0, stream>>>(lbl, bs, cnt, pos, P);
  gather_sq<<<P, 128, 0, stream>>>(Hout, pos, X, Xh, sq);

  dim3 gram_grid(P / 128, NSPLIT);
  gram8<<<gram_grid, 256, 0, stream>>>(Xh, sq, P, p8v, p8j);
  merge8<<<(P + 255) / 256, 256, 0, stream>>>(p8v, p8j, cand, P);
  rescore<<<P, 64, 0, stream>>>(X, sq, cand, idx3);

  make_newfea<<<3 * P, 128, 0, stream>>>(X, idx3, lerp_w, newfea);
  write_lbl<<<(n_total + 255) / 256, 256, 0, stream>>>(lbl, lbl_out, bs, n_total);
}

// Round 8
// 465.189 us; speedup vs baseline: 4.9040x; 1.1388x over previous
//
#include <hip/hip_runtime.h>
#include <math.h>

#define NEG_INF -3.402823466e38f
#define NSPLIT 8

typedef __attribute__((ext_vector_type(8))) short bf16x8;
typedef __attribute__((ext_vector_type(4))) float f32x4;

__device__ __forceinline__ void gload_lds16(const unsigned short* g, unsigned short* l) {
  __builtin_amdgcn_global_load_lds(
      (const __attribute__((address_space(1))) unsigned int*)g,
      (__attribute__((address_space(3))) unsigned int*)l, 16, 0, 0);
}
__device__ __forceinline__ void gload_lds16f(const float* g, float* l) {
  __builtin_amdgcn_global_load_lds(
      (const __attribute__((address_space(1))) unsigned int*)g,
      (__attribute__((address_space(3))) unsigned int*)l, 16, 0, 0);
}

__device__ __forceinline__ unsigned short f2bf(float f) {
  union { float f; unsigned int u; } a; a.f = f;
  unsigned int u = a.u;
  return (unsigned short)((u + 0x7fffu + ((u >> 16) & 1u)) >> 16);
}

// pairwise 3-term truncation split: 8 f32 -> hi/mid/lo bf16x8.
__device__ __forceinline__ void split3_8(f32x4 a, f32x4 b,
                                         bf16x8& hi, bf16x8& md, bf16x8& lo) {
  union { bf16x8 v; unsigned int u[4]; } H, M, L;
  float f[8];
  f[0]=a[0]; f[1]=a[1]; f[2]=a[2]; f[3]=a[3];
  f[4]=b[0]; f[5]=b[1]; f[6]=b[2]; f[7]=b[3];
#pragma unroll
  for (int p = 0; p < 4; ++p) {
    union { float f; unsigned int u; } x0, x1, h0, h1, r0, r1, m0, m1, s0, s1;
    x0.f = f[2*p]; x1.f = f[2*p+1];
    H.u[p] = (x0.u >> 16) | (x1.u & 0xffff0000u);
    h0.u = x0.u & 0xffff0000u; h1.u = x1.u & 0xffff0000u;
    r0.f = x0.f - h0.f;        r1.f = x1.f - h1.f;
    M.u[p] = (r0.u >> 16) | (r1.u & 0xffff0000u);
    m0.u = r0.u & 0xffff0000u; m1.u = r1.u & 0xffff0000u;
    s0.f = r0.f - m0.f;        s1.f = r1.f - m1.f;
    L.u[p] = (s0.u >> 16) | (s1.u & 0xffff0000u);
  }
  hi = H.v; md = M.v; lo = L.v;
}

// ------ split+transpose weights: W[512][512] -> Wt_{h,m,l}[n][k] --------------
__global__ __launch_bounds__(256) void split_w_t3(const float* __restrict__ W,
    unsigned short* __restrict__ Th, unsigned short* __restrict__ Tm,
    unsigned short* __restrict__ Tl)
{
  __shared__ float T[64][65];
  int k0 = blockIdx.x * 64, n0 = blockIdx.y * 64;
  int tid = threadIdx.x;
  int r = tid >> 4, c4 = (tid & 15) << 2;
#pragma unroll
  for (int p = 0; p < 4; ++p) {
    int row = r + p * 16;
    float4 v = *(const float4*)&W[(size_t)(k0 + row) * 512 + n0 + c4];
    T[c4 + 0][row] = v.x; T[c4 + 1][row] = v.y;
    T[c4 + 2][row] = v.z; T[c4 + 3][row] = v.w;
  }
  __syncthreads();
  int nr = tid >> 2, kc = (tid & 3) << 4;
#pragma unroll
  for (int u = 0; u < 16; ++u) {
    union { float f; unsigned int u; } x, h, rr, m, ss;
    x.f = T[nr][kc + u];
    unsigned short hb = (unsigned short)(x.u >> 16);
    h.u = x.u & 0xffff0000u;
    rr.f = x.f - h.f;
    unsigned short mb = (unsigned short)(rr.u >> 16);
    m.u = rr.u & 0xffff0000u;
    ss.f = rr.f - m.f;
    unsigned short lb = (unsigned short)(ss.u >> 16);
    size_t o = (size_t)(n0 + nr) * 512 + k0 + kc + u;
    Th[o] = hb; Tm[o] = mb; Tl[o] = lb;
  }
}

// ------ GEMM: dbuf BK=32, wave = 32 rows x 128 cols (2 splits/iter) -----------
__global__ __launch_bounds__(256, 2) void gemm_split3(
    const float* __restrict__ A, const unsigned short* __restrict__ Bth,
    const unsigned short* __restrict__ Btm, const unsigned short* __restrict__ Btl,
    const float* __restrict__ bias, float* __restrict__ C, float* __restrict__ partial)
{
  __shared__ char smem[81920];   // 2 x (sA 16K + 3x8K B)
  const int tid = threadIdx.x;
  const int w = tid >> 6, lane = tid & 63;
  const int bm = blockIdx.x * 128, bn = blockIdx.y * 128;
  const int fr = lane & 15, fg = lane >> 4;
  const int arow = tid >> 3, acb = (tid & 7) << 4;   // A: 8 lanes x 16B per 128B row
  const int brow = tid >> 2, bcb = (tid & 3) << 4;   // B: 4 lanes x 16B per 64B row

  f32x4 acc[2][8];
#pragma unroll
  for (int mi = 0; mi < 2; ++mi)
#pragma unroll
    for (int ni = 0; ni < 8; ++ni) acc[mi][ni] = (f32x4){0.f, 0.f, 0.f, 0.f};

  auto STAGE = [&](int buf, int ktf) {
    float* sA = (float*)(smem + buf * 40960);
    unsigned short* sBh = (unsigned short*)(smem + buf * 40960 + 16384);
    unsigned short* sBm = sBh + 4096;
    unsigned short* sBl = sBm + 4096;
#pragma unroll
    for (int p = 0; p < 4; ++p) {
      int row = arow + p * 32;
      int cb = acb ^ ((row & 7) << 4);
      gload_lds16f(&A[(size_t)(bm + row) * 512 + ktf + (cb >> 2)],
                   &sA[row * 32 + (acb >> 2)]);
    }
#pragma unroll
    for (int p = 0; p < 2; ++p) {
      int row = brow + p * 64;
      int cb = bcb ^ (((row >> 1) & 3) << 4);
      int so = row * 32 + (bcb >> 1);
      gload_lds16(&Bth[(size_t)(bn + row) * 512 + ktf + (cb >> 1)], &sBh[so]);
      gload_lds16(&Btm[(size_t)(bn + row) * 512 + ktf + (cb >> 1)], &sBm[so]);
      gload_lds16(&Btl[(size_t)(bn + row) * 512 + ktf + (cb >> 1)], &sBl[so]);
    }
  };

  STAGE(0, 0);
  __syncthreads();
  for (int it = 0; it < 16; ++it) {
    int cur = it & 1;
    if (it + 1 < 16) STAGE(cur ^ 1, (it + 1) * 32);
    float* sA = (float*)(smem + cur * 40960);
    unsigned short* sBh = (unsigned short*)(smem + cur * 40960 + 16384);
    unsigned short* sBm = sBh + 4096;
    unsigned short* sBl = sBm + 4096;
    bf16x8 ah[2], am[2], al[2];
#pragma unroll
    for (int mi = 0; mi < 2; ++mi) {
      int row = w * 32 + mi * 16 + fr;
      int swz = (row & 7) << 4;
      const char* rb = (const char*)(sA + row * 32);
      f32x4 f0 = *(const f32x4*)(rb + ((fg * 32) ^ swz));
      f32x4 f1 = *(const f32x4*)(rb + ((fg * 32 + 16) ^ swz));
      split3_8(f0, f1, ah[mi], am[mi], al[mi]);
    }
#pragma unroll
    for (int ni = 0; ni < 8; ++ni) {
      int row = ni * 16 + fr;
      int off = row * 32 + (((fg * 16) ^ (((row >> 1) & 3) << 4)) >> 1);
      bf16x8 bh  = *(const bf16x8*)&sBh[off];
      bf16x8 bmf = *(const bf16x8*)&sBm[off];
      bf16x8 blf = *(const bf16x8*)&sBl[off];
#pragma unroll
      for (int mi = 0; mi < 2; ++mi) {
        acc[mi][ni] = __builtin_amdgcn_mfma_f32_16x16x32_bf16(al[mi], bh,  acc[mi][ni], 0, 0, 0);
        acc[mi][ni] = __builtin_amdgcn_mfma_f32_16x16x32_bf16(am[mi], bmf, acc[mi][ni], 0, 0, 0);
        acc[mi][ni] = __builtin_amdgcn_mfma_f32_16x16x32_bf16(ah[mi], blf, acc[mi][ni], 0, 0, 0);
        acc[mi][ni] = __builtin_amdgcn_mfma_f32_16x16x32_bf16(am[mi], bh,  acc[mi][ni], 0, 0, 0);
        acc[mi][ni] = __builtin_amdgcn_mfma_f32_16x16x32_bf16(ah[mi], bmf, acc[mi][ni], 0, 0, 0);
        acc[mi][ni] = __builtin_amdgcn_mfma_f32_16x16x32_bf16(ah[mi], bh,  acc[mi][ni], 0, 0, 0);
      }
    }
    __syncthreads();
  }

  // epilogue: C write + BN column partials (wave = 32 rows x 128 cols)
  float ssv[8], qqv[8];
#pragma unroll
  for (int ni = 0; ni < 8; ++ni) {
    float bno = bias[bn + ni * 16 + fr];
    float s = 0.f, q = 0.f;
#pragma unroll
    for (int mi = 0; mi < 2; ++mi) {
      int row = bm + w * 32 + mi * 16 + fg * 4;
      int col = bn + ni * 16 + fr;
#pragma unroll
      for (int r = 0; r < 4; ++r) {
        float v = acc[mi][ni][r] + bno;
        C[(size_t)(row + r) * 512 + col] = v;
        s += v; q += v * v;
      }
    }
    s += __shfl_xor(s, 16); s += __shfl_xor(s, 32);
    q += __shfl_xor(q, 16); q += __shfl_xor(q, 32);
    ssv[ni] = s; qqv[ni] = q;
  }
  // pair-combine waves (0+1)->slot even, (2+3)->slot odd via LDS (deterministic)
  float* ps = (float*)smem;   // [4][2][8][16] = 4KB, smem is free now
  if (fg == 0) {
#pragma unroll
    for (int ni = 0; ni < 8; ++ni) {
      ps[((w * 2 + 0) * 8 + ni) * 16 + fr] = ssv[ni];
      ps[((w * 2 + 1) * 8 + ni) * 16 + fr] = qqv[ni];
    }
  }
  __syncthreads();
  if ((w & 1) == 0) {
    int p = w >> 1;
#pragma unroll
    for (int k = 0; k < 4; ++k) {
      int idx = k * 64 + lane;          // 0..255
      int part = idx >> 7;              // 0 = sum, 1 = sumsq
      int rem = idx & 127;
      int ni = rem >> 4, fr2 = rem & 15;
      float v = ps[(((2 * p) * 2 + part) * 8 + ni) * 16 + fr2]
              + ps[(((2 * p + 1) * 2 + part) * 8 + ni) * 16 + fr2];
      int slot = blockIdx.x * 2 + p;
      partial[(size_t)(slot * 2 + part) * 512 + bn + ni * 16 + fr2] = v;
    }
  }
}

// ------ BN reduce stage 1: fold nslot slots into 16 groups (coalesced) --------
__global__ __launch_bounds__(256) void bn_reduce1(
    const float* __restrict__ partial, float* __restrict__ partial2, int nslot)
{
  int g = blockIdx.x, p = blockIdx.y;
  int per = nslot >> 4;
  int t = threadIdx.x;
#pragma unroll
  for (int cc = 0; cc < 2; ++cc) {
    int c = t + cc * 256;
    float s = 0.f;
    for (int s0 = 0; s0 < per; ++s0) {
      int slot = g * per + s0;
      s += partial[(size_t)(slot * 2 + p) * 512 + c];
    }
    partial2[(size_t)(g * 2 + p) * 512 + c] = s;
  }
}

__global__ void bn_finalize(
    const float* __restrict__ partial2, const float* __restrict__ g,
    const float* __restrict__ beta, float* __restrict__ scale,
    float* __restrict__ shift, int rows)
{
  int c = blockIdx.x * blockDim.x + threadIdx.x;
  if (c >= 512) return;
  float s = 0, s2 = 0;
  for (int b = 0; b < 16; ++b) {
    s  += partial2[(size_t)(b * 2 + 0) * 512 + c];
    s2 += partial2[(size_t)(b * 2 + 1) * 512 + c];
  }
  float m = s / rows;
  float v = s2 / rows - m * m;
  if (v < 0) v = 0;
  float sc = g[c] / sqrtf(v + 1e-5f);
  scale[c] = sc;
  shift[c] = beta[c] - m * sc;
}

__global__ void bn_swish(
    const float* __restrict__ Y, const float* __restrict__ scale,
    const float* __restrict__ shift, float* __restrict__ H, int total4)
{
  int i = blockIdx.x * blockDim.x + threadIdx.x;
  if (i >= total4) return;
  float4 y = ((const float4*)Y)[i];
  int c = (i * 4) & 511;
  float z;
  float4 o;
  z = y.x * scale[c + 0] + shift[c + 0]; o.x = z / (1.f + expf(-z));
  z = y.y * scale[c + 1] + shift[c + 1]; o.y = z / (1.f + expf(-z));
  z = y.z * scale[c + 2] + shift[c + 2]; o.z = z / (1.f + expf(-z));
  z = y.w * scale[c + 3] + shift[c + 3]; o.w = z / (1.f + expf(-z));
  ((float4*)H)[i] = o;
}

// ---------------- positive-label compaction: 3-kernel scan ----------------
__global__ __launch_bounds__(1024) void pos_count(const int* __restrict__ lbl, int n,
                                                  int* __restrict__ cnt,
                                                  int* __restrict__ pos, int P)
{
  int b = blockIdx.x, tid = threadIdx.x;
  int i = b * 1024 + tid;
  if (i < P) pos[i] = 0;          // jnp.nonzero pads with 0
  int pred = (i < n) && (lbl[i] > 0);
  unsigned long long m = __ballot(pred);
  __shared__ int ws[16];
  if ((tid & 63) == 0) ws[tid >> 6] = __popcll(m);
  __syncthreads();
  if (tid == 0) { int s = 0; for (int k = 0; k < 16; ++k) s += ws[k]; cnt[b] = s; }
}

__global__ void pos_prefix(int* __restrict__ cnt, int nb)
{
  if (threadIdx.x == 0) {
    int s = 0;
    for (int b = 0; b < nb; ++b) { int c = cnt[b]; cnt[b] = s; s += c; }
  }
}

__global__ __launch_bounds__(1024) void pos_scatter(const int* __restrict__ lbl, int n,
                                                    const int* __restrict__ cntp,
                                                    int* __restrict__ pos, int P)
{
  int b = blockIdx.x, tid = threadIdx.x;
  int i = b * 1024 + tid;
  int pred = (i < n) && (lbl[i] > 0);
  unsigned long long m = __ballot(pred);
  __shared__ int ws[16];
  int wid = tid >> 6, lane = tid & 63;
  if (lane == 0) ws[wid] = __popcll(m);
  __syncthreads();
  int wbase = 0;
  for (int w2 = 0; w2 < wid; ++w2) wbase += ws[w2];
  int rank = cntp[b] + wbase + __popcll(m & ((1ull << lane) - 1ull));
  if (pred && rank < P) pos[rank] = i;
}

// ---------------- gather positives + sq norms + bf16 copy ----------------
__global__ void gather_sq(const float* __restrict__ H, const int* __restrict__ pos,
                          float* __restrict__ X, unsigned short* __restrict__ Xh,
                          float* __restrict__ sq)
{
  int r = blockIdx.x, t = threadIdx.x;  // 128 threads
  int src = pos[r];
  float4 v = *(const float4*)&H[src * 512 + t * 4];
  *(float4*)&X[r * 512 + t * 4] = v;
  ushort4 hv;
  hv.x = f2bf(v.x); hv.y = f2bf(v.y); hv.z = f2bf(v.z); hv.w = f2bf(v.w);
  *(ushort4*)&Xh[r * 512 + t * 4] = hv;
  float s = v.x * v.x + v.y * v.y + v.z * v.z + v.w * v.w;
#pragma unroll
  for (int off = 32; off > 0; off >>= 1) s += __shfl_down(s, off);
  __shared__ float red[2];
  if ((t & 63) == 0) red[t >> 6] = s;
  __syncthreads();
  if (t == 0) sq[r] = red[0] + red[1];
}

// ---------------- approx Gram (bf16 MFMA) + running top-8 ----------------
__global__ __launch_bounds__(256, 2) void gram8(
    const unsigned short* __restrict__ Xh, const float* __restrict__ sq, int P,
    float* __restrict__ p8v, int* __restrict__ p8j)
{
  __shared__ unsigned short Ah[128 * 64];
  __shared__ unsigned short Bh[128 * 64];
  __shared__ float dl[4][64][17];
  __shared__ float sqj_l[128];

  const int tid = threadIdx.x;
  const int w = tid >> 6, lane = tid & 63;
  const int wr = w >> 1, wc = w & 1;
  const int bi = blockIdx.x * 128;
  const int jchunk = P / NSPLIT;         // 1024
  const int jlo = blockIdx.y * jchunk;

  const int srow = tid >> 3;
  const int scb  = (tid & 7) << 4;
  const int fr = lane & 15, fg = lane >> 4;

  float t[8]; int ji[8];
#pragma unroll
  for (int q = 0; q < 8; ++q) { t[q] = NEG_INF; ji[q] = 0x7fffffff; }

  for (int jt = 0; jt < jchunk; jt += 128) {
    const int j0 = jlo + jt;
    if (tid < 128) sqj_l[tid] = sq[j0 + tid];
    f32x4 acc[4][4];
#pragma unroll
    for (int mi = 0; mi < 4; ++mi)
#pragma unroll
      for (int ni = 0; ni < 4; ++ni) acc[mi][ni] = (f32x4){0.f, 0.f, 0.f, 0.f};

    for (int kt = 0; kt < 512; kt += 64) {
#pragma unroll
      for (int it = 0; it < 4; ++it) {
        int row = srow + it * 32;
        int cb = scb ^ ((row & 7) << 4);
        gload_lds16(&Xh[(size_t)(bi + row) * 512 + kt + (cb >> 1)],
                    &Ah[row * 64 + (scb >> 1)]);
        gload_lds16(&Xh[(size_t)(j0 + row) * 512 + kt + (cb >> 1)],
                    &Bh[row * 64 + (scb >> 1)]);
      }
      __syncthreads();
#pragma unroll
      for (int ks = 0; ks < 2; ++ks) {
        bf16x8 af[4], bfr[4];
        int kb = ks * 64 + fg * 16;
#pragma unroll
        for (int mi = 0; mi < 4; ++mi) {
          int row = wr * 64 + mi * 16 + fr;
          af[mi] = *(const bf16x8*)&Ah[row * 64 + ((kb ^ ((row & 7) << 4)) >> 1)];
        }
#pragma unroll
        for (int ni = 0; ni < 4; ++ni) {
          int row = wc * 64 + ni * 16 + fr;
          bfr[ni] = *(const bf16x8*)&Bh[row * 64 + ((kb ^ ((row & 7) << 4)) >> 1)];
        }
#pragma unroll
        for (int mi = 0; mi < 4; ++mi)
#pragma unroll
          for (int ni = 0; ni < 4; ++ni)
            acc[mi][ni] = __builtin_amdgcn_mfma_f32_16x16x32_bf16(
                af[mi], bfr[ni], acc[mi][ni], 0, 0, 0);
      }
      __syncthreads();
    }

#pragma unroll
    for (int qn = 0; qn < 4; ++qn) {
      float sqv = sqj_l[wc * 64 + qn * 16 + fr];
#pragma unroll
      for (int mi = 0; mi < 4; ++mi)
#pragma unroll
        for (int r = 0; r < 4; ++r)
          dl[w][mi * 16 + fg * 4 + r][fr] = 2.0f * acc[mi][qn][r] - sqv;
      __syncthreads();
      int jbase = j0 + wc * 64 + qn * 16;
      for (int c = 0; c < 16; ++c) {
        float v = dl[w][lane][c];
        if (v > t[7]) {
          t[7] = v; ji[7] = jbase + c;
#pragma unroll
          for (int q = 7; q > 0; --q) {
            if (t[q] > t[q - 1]) {
              float tv = t[q]; t[q] = t[q - 1]; t[q - 1] = tv;
              int tj = ji[q]; ji[q] = ji[q - 1]; ji[q - 1] = tj;
            }
          }
        }
      }
      __syncthreads();
    }
  }

  int row = bi + wr * 64 + lane;
  int set = blockIdx.y * 2 + wc;
  size_t base = ((size_t)row * (NSPLIT * 2) + set) * 8;
#pragma unroll
  for (int q = 0; q < 8; ++q) { p8v[base + q] = t[q]; p8j[base + q] = ji[q]; }
}

// ------- wave-parallel merge: 16 lists x 8 = 128 cands -> top-8 per row -------
__global__ __launch_bounds__(256) void merge8w(const float* __restrict__ p8v,
                                               const int* __restrict__ p8j,
                                               int* __restrict__ cand, int P)
{
  int row = blockIdx.x * 4 + (threadIdx.x >> 6);
  int lane = threadIdx.x & 63;
  if (row >= P) return;
  const float* v = p8v + (size_t)row * 128;
  const int* j = p8j + (size_t)row * 128;
  float v0 = v[lane * 2], v1 = v[lane * 2 + 1];
  int j0 = j[lane * 2], j1 = j[lane * 2 + 1];
  for (int k = 0; k < 8; ++k) {
    float bv; int bj;
    if (v0 > v1 || (v0 == v1 && j0 < j1)) { bv = v0; bj = j0; }
    else { bv = v1; bj = j1; }
#pragma unroll
    for (int off = 1; off < 64; off <<= 1) {
      float ov = __shfl_xor(bv, off);
      int oj = __shfl_xor(bj, off);
      if (ov > bv || (ov == bv && oj < bj)) { bv = ov; bj = oj; }
    }
    if (lane == 0) cand[row * 8 + k] = bj;
    if (j0 == bj) { v0 = NEG_INF; j0 = 0x7fffffff; }
    if (j1 == bj) { v1 = NEG_INF; j1 = 0x7fffffff; }
  }
}

// ---------------- exact fp32 rescore of 8 candidates -> top-3 --------------
__global__ __launch_bounds__(64) void rescore(
    const float* __restrict__ X, const float* __restrict__ sq,
    const int* __restrict__ cand, int* __restrict__ idx3)
{
  int i = blockIdx.x;
  int lane = threadIdx.x;
  f32x4 x0 = *(const f32x4*)&X[(size_t)i * 512 + lane * 8];
  f32x4 x1 = *(const f32x4*)&X[(size_t)i * 512 + lane * 8 + 4];
  float d[8]; int cj[8];
#pragma unroll
  for (int c = 0; c < 8; ++c) {
    int j = cand[i * 8 + c];
    cj[c] = j;
    f32x4 y0 = *(const f32x4*)&X[(size_t)j * 512 + lane * 8];
    f32x4 y1 = *(const f32x4*)&X[(size_t)j * 512 + lane * 8 + 4];
    float p = x0.x * y0.x + x0.y * y0.y + x0.z * y0.z + x0.w * y0.w
            + x1.x * y1.x + x1.y * y1.y + x1.z * y1.z + x1.w * y1.w;
#pragma unroll
    for (int off = 32; off > 0; off >>= 1) p += __shfl_xor(p, off);
    d[c] = 2.0f * p - sq[i] - sq[j];
  }
  if (lane == 0) {
    for (int k = 0; k < 3; ++k) {
      int b = 0;
#pragma unroll
      for (int c = 1; c < 8; ++c)
        if (d[c] > d[b] || (d[c] == d[b] && cj[c] < cj[b])) b = c;
      idx3[i * 3 + k] = cj[b];
      d[b] = NEG_INF; cj[b] = 0x7fffffff;
    }
  }
}

// ---------------- SMOTE lerp rows ----------------
__global__ void make_newfea(const float* __restrict__ X, const int* __restrict__ idx3,
                            const float* __restrict__ lw, float* __restrict__ out)
{
  int r = blockIdx.x;
  int i = r / 3, k = r - i * 3;
  int ai = idx3[i * 3 + 0];
  int bi = idx3[i * 3 + k];
  float w = lw[r];
  int t = threadIdx.x;
  float4 av = *(const float4*)&X[ai * 512 + t * 4];
  float4 bv = *(const float4*)&X[bi * 512 + t * 4];
  float4 o;
  o.x = av.x + w * (bv.x - av.x);
  o.y = av.y + w * (bv.y - av.y);
  o.z = av.z + w * (bv.z - av.z);
  o.w = av.w + w * (bv.w - av.w);
  *(float4*)&out[(size_t)r * 512 + t * 4] = o;
}

__global__ void write_lbl(const int* __restrict__ lbl, float* __restrict__ out,
                          int n_in, int n_total)
{
  int i = blockIdx.x * blockDim.x + threadIdx.x;
  if (i < n_total) out[i] = (i < n_in) ? (float)lbl[i] : 1.0f;
}

// ---------------- launch ----------------
extern "C" void kernel_launch(void* const* d_in, const int* in_sizes, int n_in,
                              void* d_out, int out_size, void* d_ws, size_t ws_size,
                              hipStream_t stream)
{
  const float* fea   = (const float*)d_in[0];
  const int*   lbl   = (const int*)d_in[1];
  const float* W1    = (const float*)d_in[2];
  const float* b1    = (const float*)d_in[3];
  const float* g1    = (const float*)d_in[4];
  const float* beta1 = (const float*)d_in[5];
  const float* W2    = (const float*)d_in[6];
  const float* b2    = (const float*)d_in[7];
  const float* g2    = (const float*)d_in[8];
  const float* beta2 = (const float*)d_in[9];
  const float* lerp_w = (const float*)d_in[10];

  int bs = in_sizes[0] / 512;       // 32768
  int P  = in_sizes[10] / 3;        // 8192
  int n_total = bs + 3 * P;         // 57344

  float* out_f = (float*)d_out;
  float* Hout = out_f;
  float* newfea = out_f + (size_t)bs * 512;
  float* lbl_out = out_f + (size_t)n_total * 512;

  const size_t MB = 1024 * 1024;
  const size_t KB = 1024;
  char* ws = (char*)d_ws;
  float* Y1 = (float*)ws;                                  // 64MB fp32 y1 -> h1
  float* X  = (float*)(ws + 64 * MB);                      // 16MB (after weights dead)
  unsigned short* W1h = (unsigned short*)(ws + 64 * MB);
  unsigned short* W1m = (unsigned short*)(ws + 64 * MB + 512 * KB);
  unsigned short* W1l = (unsigned short*)(ws + 64 * MB + 1024 * KB);
  unsigned short* W2h = (unsigned short*)(ws + 64 * MB + 1536 * KB);
  unsigned short* W2m = (unsigned short*)(ws + 64 * MB + 2048 * KB);
  unsigned short* W2l = (unsigned short*)(ws + 64 * MB + 2560 * KB);
  float* partial = (float*)(ws + 80 * MB);                 // 2MB
  float* scale = (float*)(ws + 82 * MB);
  float* shiftv = scale + 512;
  float* sq = shiftv + 512;
  int* pos = (int*)(sq + 8192);
  int* idx3 = pos + 8192;
  int* cnt = idx3 + 3 * 8192;                              // 32 ints
  float* partial2 = (float*)(ws + 83 * MB);                // 64KB
  // overlays in dead Y1 region (used only after gemm2):
  unsigned short* Xh = (unsigned short*)ws;                // 8MB
  float* p8v = (float*)(ws + 8 * MB);                      // 4MB (8192 x 16 x 8)
  int*   p8j = (int*)(ws + 12 * MB);                       // 4MB
  int*   cand = (int*)(ws + 16 * MB);                      // 256KB

  dim3 wgrid(8, 8);
  split_w_t3<<<wgrid, 256, 0, stream>>>(W1, W1h, W1m, W1l);
  split_w_t3<<<wgrid, 256, 0, stream>>>(W2, W2h, W2m, W2l);

  dim3 ggrid(bs / 128, 4);
  int nslot = (bs / 128) * 2;          // 512
  dim3 rgrid(16, 2);

  gemm_split3<<<ggrid, 256, 0, stream>>>(fea, W1h, W1m, W1l, b1, Y1, partial);
  bn_reduce1<<<rgrid, 256, 0, stream>>>(partial, partial2, nslot);
  bn_finalize<<<2, 256, 0, stream>>>(partial2, g1, beta1, scale, shiftv, bs);
  bn_swish<<<(bs * 512 / 4 + 255) / 256, 256, 0, stream>>>(Y1, scale, shiftv, Y1, bs * 512 / 4);

  gemm_split3<<<ggrid, 256, 0, stream>>>(Y1, W2h, W2m, W2l, b2, Hout, partial);
  bn_reduce1<<<rgrid, 256, 0, stream>>>(partial, partial2, nslot);
  bn_finalize<<<2, 256, 0, stream>>>(partial2, g2, beta2, scale, shiftv, bs);
  bn_swish<<<(bs * 512 / 4 + 255) / 256, 256, 0, stream>>>(Hout, scale, shiftv, Hout, bs * 512 / 4);

  int nb = (bs + 1023) / 1024;         // 32
  pos_count<<<nb, 1024, 0, stream>>>(lbl, bs, cnt, pos, P);
  pos_prefix<<<1, 64, 0, stream>>>(cnt, nb);
  pos_scatter<<<nb, 1024, 0, stream>>>(lbl, bs, cnt, pos, P);
  gather_sq<<<P, 128, 0, stream>>>(Hout, pos, X, Xh, sq);

  dim3 gram_grid(P / 128, NSPLIT);
  gram8<<<gram_grid, 256, 0, stream>>>(Xh, sq, P, p8v, p8j);
  merge8w<<<(P + 3) / 4, 256, 0, stream>>>(p8v, p8j, cand, P);
  rescore<<<P, 64, 0, stream>>>(X, sq, cand, idx3);

  make_newfea<<<3 * P, 128, 0, stream>>>(X, idx3, lerp_w, newfea);
  write_lbl<<<(n_total + 255) / 256, 256, 0, stream>>>(lbl, lbl_out, bs, n_total);
}

// Round 9
// 459.480 us; speedup vs baseline: 4.9649x; 1.0124x over previous
//
#include <hip/hip_runtime.h>
#include <math.h>

#define NEG_INF -3.402823466e38f

typedef __attribute__((ext_vector_type(8))) short bf16x8;
typedef __attribute__((ext_vector_type(4))) float f32x4;

__device__ __forceinline__ void gload_lds16(const unsigned short* g, unsigned short* l) {
  __builtin_amdgcn_global_load_lds(
      (const __attribute__((address_space(1))) unsigned int*)g,
      (__attribute__((address_space(3))) unsigned int*)l, 16, 0, 0);
}
__device__ __forceinline__ void gload_lds16f(const float* g, float* l) {
  __builtin_amdgcn_global_load_lds(
      (const __attribute__((address_space(1))) unsigned int*)g,
      (__attribute__((address_space(3))) unsigned int*)l, 16, 0, 0);
}

__device__ __forceinline__ unsigned short f2bf(float f) {
  union { float f; unsigned int u; } a; a.f = f;
  unsigned int u = a.u;
  return (unsigned short)((u + 0x7fffu + ((u >> 16) & 1u)) >> 16);
}

// pairwise 3-term truncation split: 8 f32 -> hi/mid/lo bf16x8.
__device__ __forceinline__ void split3_8(f32x4 a, f32x4 b,
                                         bf16x8& hi, bf16x8& md, bf16x8& lo) {
  union { bf16x8 v; unsigned int u[4]; } H, M, L;
  float f[8];
  f[0]=a[0]; f[1]=a[1]; f[2]=a[2]; f[3]=a[3];
  f[4]=b[0]; f[5]=b[1]; f[6]=b[2]; f[7]=b[3];
#pragma unroll
  for (int p = 0; p < 4; ++p) {
    union { float f; unsigned int u; } x0, x1, h0, h1, r0, r1, m0, m1, s0, s1;
    x0.f = f[2*p]; x1.f = f[2*p+1];
    H.u[p] = (x0.u >> 16) | (x1.u & 0xffff0000u);
    h0.u = x0.u & 0xffff0000u; h1.u = x1.u & 0xffff0000u;
    r0.f = x0.f - h0.f;        r1.f = x1.f - h1.f;
    M.u[p] = (r0.u >> 16) | (r1.u & 0xffff0000u);
    m0.u = r0.u & 0xffff0000u; m1.u = r1.u & 0xffff0000u;
    s0.f = r0.f - m0.f;        s1.f = r1.f - m1.f;
    L.u[p] = (s0.u >> 16) | (s1.u & 0xffff0000u);
  }
  hi = H.v; md = M.v; lo = L.v;
}

// ------ split+transpose weights: W[512][512] -> Wt_{h,m,l}[n][k] --------------
__global__ __launch_bounds__(256) void split_w_t3(const float* __restrict__ W,
    unsigned short* __restrict__ Th, unsigned short* __restrict__ Tm,
    unsigned short* __restrict__ Tl)
{
  __shared__ float T[64][65];
  int k0 = blockIdx.x * 64, n0 = blockIdx.y * 64;
  int tid = threadIdx.x;
  int r = tid >> 4, c4 = (tid & 15) << 2;
#pragma unroll
  for (int p = 0; p < 4; ++p) {
    int row = r + p * 16;
    float4 v = *(const float4*)&W[(size_t)(k0 + row) * 512 + n0 + c4];
    T[c4 + 0][row] = v.x; T[c4 + 1][row] = v.y;
    T[c4 + 2][row] = v.z; T[c4 + 3][row] = v.w;
  }
  __syncthreads();
  int nr = tid >> 2, kc = (tid & 3) << 4;
#pragma unroll
  for (int u = 0; u < 16; ++u) {
    union { float f; unsigned int u; } x, h, rr, m, ss;
    x.f = T[nr][kc + u];
    unsigned short hb = (unsigned short)(x.u >> 16);
    h.u = x.u & 0xffff0000u;
    rr.f = x.f - h.f;
    unsigned short mb = (unsigned short)(rr.u >> 16);
    m.u = rr.u & 0xffff0000u;
    ss.f = rr.f - m.f;
    unsigned short lb = (unsigned short)(ss.u >> 16);
    size_t o = (size_t)(n0 + nr) * 512 + k0 + kc + u;
    Th[o] = hb; Tm[o] = mb; Tl[o] = lb;
  }
}

// ------ GEMM: dbuf BK=32, wave = 32 rows x 128 cols (2 splits/iter) -----------
__global__ __launch_bounds__(256, 2) void gemm_split3(
    const float* __restrict__ A, const unsigned short* __restrict__ Bth,
    const unsigned short* __restrict__ Btm, const unsigned short* __restrict__ Btl,
    const float* __restrict__ bias, float* __restrict__ C, float* __restrict__ partial)
{
  __shared__ char smem[81920];   // 2 x (sA 16K + 3x8K B)
  const int tid = threadIdx.x;
  const int w = tid >> 6, lane = tid & 63;
  const int bm = blockIdx.x * 128, bn = blockIdx.y * 128;
  const int fr = lane & 15, fg = lane >> 4;
  const int arow = tid >> 3, acb = (tid & 7) << 4;
  const int brow = tid >> 2, bcb = (tid & 3) << 4;

  f32x4 acc[2][8];
#pragma unroll
  for (int mi = 0; mi < 2; ++mi)
#pragma unroll
    for (int ni = 0; ni < 8; ++ni) acc[mi][ni] = (f32x4){0.f, 0.f, 0.f, 0.f};

  auto STAGE = [&](int buf, int ktf) {
    float* sA = (float*)(smem + buf * 40960);
    unsigned short* sBh = (unsigned short*)(smem + buf * 40960 + 16384);
    unsigned short* sBm = sBh + 4096;
    unsigned short* sBl = sBm + 4096;
#pragma unroll
    for (int p = 0; p < 4; ++p) {
      int row = arow + p * 32;
      int cb = acb ^ ((row & 7) << 4);
      gload_lds16f(&A[(size_t)(bm + row) * 512 + ktf + (cb >> 2)],
                   &sA[row * 32 + (acb >> 2)]);
    }
#pragma unroll
    for (int p = 0; p < 2; ++p) {
      int row = brow + p * 64;
      int cb = bcb ^ (((row >> 1) & 3) << 4);
      int so = row * 32 + (bcb >> 1);
      gload_lds16(&Bth[(size_t)(bn + row) * 512 + ktf + (cb >> 1)], &sBh[so]);
      gload_lds16(&Btm[(size_t)(bn + row) * 512 + ktf + (cb >> 1)], &sBm[so]);
      gload_lds16(&Btl[(size_t)(bn + row) * 512 + ktf + (cb >> 1)], &sBl[so]);
    }
  };

  STAGE(0, 0);
  __syncthreads();
  for (int it = 0; it < 16; ++it) {
    int cur = it & 1;
    if (it + 1 < 16) STAGE(cur ^ 1, (it + 1) * 32);
    float* sA = (float*)(smem + cur * 40960);
    unsigned short* sBh = (unsigned short*)(smem + cur * 40960 + 16384);
    unsigned short* sBm = sBh + 4096;
    unsigned short* sBl = sBm + 4096;
    bf16x8 ah[2], am[2], al[2];
#pragma unroll
    for (int mi = 0; mi < 2; ++mi) {
      int row = w * 32 + mi * 16 + fr;
      int swz = (row & 7) << 4;
      const char* rb = (const char*)(sA + row * 32);
      f32x4 f0 = *(const f32x4*)(rb + ((fg * 32) ^ swz));
      f32x4 f1 = *(const f32x4*)(rb + ((fg * 32 + 16) ^ swz));
      split3_8(f0, f1, ah[mi], am[mi], al[mi]);
    }
#pragma unroll
    for (int ni = 0; ni < 8; ++ni) {
      int row = ni * 16 + fr;
      int off = row * 32 + (((fg * 16) ^ (((row >> 1) & 3) << 4)) >> 1);
      bf16x8 bh  = *(const bf16x8*)&sBh[off];
      bf16x8 bmf = *(const bf16x8*)&sBm[off];
      bf16x8 blf = *(const bf16x8*)&sBl[off];
#pragma unroll
      for (int mi = 0; mi < 2; ++mi) {
        acc[mi][ni] = __builtin_amdgcn_mfma_f32_16x16x32_bf16(al[mi], bh,  acc[mi][ni], 0, 0, 0);
        acc[mi][ni] = __builtin_amdgcn_mfma_f32_16x16x32_bf16(am[mi], bmf, acc[mi][ni], 0, 0, 0);
        acc[mi][ni] = __builtin_amdgcn_mfma_f32_16x16x32_bf16(ah[mi], blf, acc[mi][ni], 0, 0, 0);
        acc[mi][ni] = __builtin_amdgcn_mfma_f32_16x16x32_bf16(am[mi], bh,  acc[mi][ni], 0, 0, 0);
        acc[mi][ni] = __builtin_amdgcn_mfma_f32_16x16x32_bf16(ah[mi], bmf, acc[mi][ni], 0, 0, 0);
        acc[mi][ni] = __builtin_amdgcn_mfma_f32_16x16x32_bf16(ah[mi], bh,  acc[mi][ni], 0, 0, 0);
      }
    }
    __syncthreads();
  }

  float ssv[8], qqv[8];
#pragma unroll
  for (int ni = 0; ni < 8; ++ni) {
    float bno = bias[bn + ni * 16 + fr];
    float s = 0.f, q = 0.f;
#pragma unroll
    for (int mi = 0; mi < 2; ++mi) {
      int row = bm + w * 32 + mi * 16 + fg * 4;
      int col = bn + ni * 16 + fr;
#pragma unroll
      for (int r = 0; r < 4; ++r) {
        float v = acc[mi][ni][r] + bno;
        C[(size_t)(row + r) * 512 + col] = v;
        s += v; q += v * v;
      }
    }
    s += __shfl_xor(s, 16); s += __shfl_xor(s, 32);
    q += __shfl_xor(q, 16); q += __shfl_xor(q, 32);
    ssv[ni] = s; qqv[ni] = q;
  }
  float* ps = (float*)smem;
  if (fg == 0) {
#pragma unroll
    for (int ni = 0; ni < 8; ++ni) {
      ps[((w * 2 + 0) * 8 + ni) * 16 + fr] = ssv[ni];
      ps[((w * 2 + 1) * 8 + ni) * 16 + fr] = qqv[ni];
    }
  }
  __syncthreads();
  if ((w & 1) == 0) {
    int p = w >> 1;
#pragma unroll
    for (int k = 0; k < 4; ++k) {
      int idx = k * 64 + lane;
      int part = idx >> 7;
      int rem = idx & 127;
      int ni = rem >> 4, fr2 = rem & 15;
      float v = ps[(((2 * p) * 2 + part) * 8 + ni) * 16 + fr2]
              + ps[(((2 * p + 1) * 2 + part) * 8 + ni) * 16 + fr2];
      int slot = blockIdx.x * 2 + p;
      partial[(size_t)(slot * 2 + part) * 512 + bn + ni * 16 + fr2] = v;
    }
  }
}

// ------ BN reduce stage 1 --------
__global__ __launch_bounds__(256) void bn_reduce1(
    const float* __restrict__ partial, float* __restrict__ partial2, int nslot)
{
  int g = blockIdx.x, p = blockIdx.y;
  int per = nslot >> 4;
  int t = threadIdx.x;
#pragma unroll
  for (int cc = 0; cc < 2; ++cc) {
    int c = t + cc * 256;
    float s = 0.f;
    for (int s0 = 0; s0 < per; ++s0) {
      int slot = g * per + s0;
      s += partial[(size_t)(slot * 2 + p) * 512 + c];
    }
    partial2[(size_t)(g * 2 + p) * 512 + c] = s;
  }
}

__global__ void bn_finalize(
    const float* __restrict__ partial2, const float* __restrict__ g,
    const float* __restrict__ beta, float* __restrict__ scale,
    float* __restrict__ shift, int rows)
{
  int c = blockIdx.x * blockDim.x + threadIdx.x;
  if (c >= 512) return;
  float s = 0, s2 = 0;
  for (int b = 0; b < 16; ++b) {
    s  += partial2[(size_t)(b * 2 + 0) * 512 + c];
    s2 += partial2[(size_t)(b * 2 + 1) * 512 + c];
  }
  float m = s / rows;
  float v = s2 / rows - m * m;
  if (v < 0) v = 0;
  float sc = g[c] / sqrtf(v + 1e-5f);
  scale[c] = sc;
  shift[c] = beta[c] - m * sc;
}

__global__ void bn_swish(
    const float* __restrict__ Y, const float* __restrict__ scale,
    const float* __restrict__ shift, float* __restrict__ H, int total4)
{
  int i = blockIdx.x * blockDim.x + threadIdx.x;
  if (i >= total4) return;
  float4 y = ((const float4*)Y)[i];
  int c = (i * 4) & 511;
  float z;
  float4 o;
  z = y.x * scale[c + 0] + shift[c + 0]; o.x = z / (1.f + expf(-z));
  z = y.y * scale[c + 1] + shift[c + 1]; o.y = z / (1.f + expf(-z));
  z = y.z * scale[c + 2] + shift[c + 2]; o.z = z / (1.f + expf(-z));
  z = y.w * scale[c + 3] + shift[c + 3]; o.w = z / (1.f + expf(-z));
  ((float4*)H)[i] = o;
}

// ---------------- positive-label compaction: 3-kernel scan ----------------
__global__ __launch_bounds__(1024) void pos_count(const int* __restrict__ lbl, int n,
                                                  int* __restrict__ cnt,
                                                  int* __restrict__ pos, int P)
{
  int b = blockIdx.x, tid = threadIdx.x;
  int i = b * 1024 + tid;
  if (i < P) pos[i] = 0;
  int pred = (i < n) && (lbl[i] > 0);
  unsigned long long m = __ballot(pred);
  __shared__ int ws[16];
  if ((tid & 63) == 0) ws[tid >> 6] = __popcll(m);
  __syncthreads();
  if (tid == 0) { int s = 0; for (int k = 0; k < 16; ++k) s += ws[k]; cnt[b] = s; }
}

__global__ void pos_prefix(int* __restrict__ cnt, int nb)
{
  if (threadIdx.x == 0) {
    int s = 0;
    for (int b = 0; b < nb; ++b) { int c = cnt[b]; cnt[b] = s; s += c; }
  }
}

__global__ __launch_bounds__(1024) void pos_scatter(const int* __restrict__ lbl, int n,
                                                    const int* __restrict__ cntp,
                                                    int* __restrict__ pos, int P)
{
  int b = blockIdx.x, tid = threadIdx.x;
  int i = b * 1024 + tid;
  int pred = (i < n) && (lbl[i] > 0);
  unsigned long long m = __ballot(pred);
  __shared__ int ws[16];
  int wid = tid >> 6, lane = tid & 63;
  if (lane == 0) ws[wid] = __popcll(m);
  __syncthreads();
  int wbase = 0;
  for (int w2 = 0; w2 < wid; ++w2) wbase += ws[w2];
  int rank = cntp[b] + wbase + __popcll(m & ((1ull << lane) - 1ull));
  if (pred && rank < P) pos[rank] = i;
}

// ---------------- gather positives + sq norms + bf16 copy ----------------
__global__ void gather_sq(const float* __restrict__ H, const int* __restrict__ pos,
                          float* __restrict__ X, unsigned short* __restrict__ Xh,
                          float* __restrict__ sq)
{
  int r = blockIdx.x, t = threadIdx.x;  // 128 threads
  int src = pos[r];
  float4 v = *(const float4*)&H[src * 512 + t * 4];
  *(float4*)&X[r * 512 + t * 4] = v;
  ushort4 hv;
  hv.x = f2bf(v.x); hv.y = f2bf(v.y); hv.z = f2bf(v.z); hv.w = f2bf(v.w);
  *(ushort4*)&Xh[r * 512 + t * 4] = hv;
  float s = v.x * v.x + v.y * v.y + v.z * v.z + v.w * v.w;
#pragma unroll
  for (int off = 32; off > 0; off >>= 1) s += __shfl_down(s, off);
  __shared__ float red[2];
  if ((t & 63) == 0) red[t >> 6] = s;
  __syncthreads();
  if (t == 0) sq[r] = red[0] + red[1];
}

// ------ symmetric Gram: one block per upper-tri 128x128 tile, dual scan -------
__global__ __launch_bounds__(256, 3) void gram_sym(
    const unsigned short* __restrict__ Xh, const float* __restrict__ sq,
    float* __restrict__ p8v, int* __restrict__ p8j)
{
  __shared__ char smem[32768];         // staging; dl / merge buffers time-share it
  __shared__ float sqi_l[128], sqj_l[128];
  unsigned short* Ah = (unsigned short*)smem;          // 16K
  unsigned short* Bh = (unsigned short*)(smem + 16384);// 16K
  float (*dl)[64][17] = (float (*)[64][17])(void*)smem; // 17.4K overlay (post k-loop)
  float* mv = (float*)smem;                             // 8K overlay (post scan)
  int*   mj = (int*)(smem + 8192);                      // 8K

  const int tid = threadIdx.x;
  const int w = tid >> 6, lane = tid & 63;
  const int wr = w >> 1, wc = w & 1;
  const int fr = lane & 15, fg = lane >> 4;
  const int srow = tid >> 3;
  const int scb  = (tid & 7) << 4;

  // decode upper-triangular (a,b), a<=b, from linear block id
  int t = blockIdx.x;
  int a = (int)(64.5f - sqrtf(64.5f * 64.5f - 2.0f * (float)t));
  if (a < 0) a = 0;
  while (a > 0 && (a * (129 - a)) / 2 > t) --a;
  while (((a + 1) * (128 - a)) / 2 <= t) ++a;
  int b = a + (t - (a * (129 - a)) / 2);
  const int ai0 = a * 128, bj0 = b * 128;

  if (tid < 128) { sqi_l[tid] = sq[ai0 + tid]; sqj_l[tid] = sq[bj0 + tid]; }

  f32x4 acc[4][4];
#pragma unroll
  for (int mi = 0; mi < 4; ++mi)
#pragma unroll
    for (int ni = 0; ni < 4; ++ni) acc[mi][ni] = (f32x4){0.f, 0.f, 0.f, 0.f};

  for (int kt = 0; kt < 512; kt += 64) {
#pragma unroll
    for (int it = 0; it < 4; ++it) {
      int row = srow + it * 32;
      int cb = scb ^ ((row & 7) << 4);
      gload_lds16(&Xh[(size_t)(ai0 + row) * 512 + kt + (cb >> 1)],
                  &Ah[row * 64 + (scb >> 1)]);
      gload_lds16(&Xh[(size_t)(bj0 + row) * 512 + kt + (cb >> 1)],
                  &Bh[row * 64 + (scb >> 1)]);
    }
    __syncthreads();
#pragma unroll
    for (int ks = 0; ks < 2; ++ks) {
      bf16x8 af[4], bfr[4];
      int kb = ks * 64 + fg * 16;
#pragma unroll
      for (int mi = 0; mi < 4; ++mi) {
        int row = wr * 64 + mi * 16 + fr;
        af[mi] = *(const bf16x8*)&Ah[row * 64 + ((kb ^ ((row & 7) << 4)) >> 1)];
      }
#pragma unroll
      for (int ni = 0; ni < 4; ++ni) {
        int row = wc * 64 + ni * 16 + fr;
        bfr[ni] = *(const bf16x8*)&Bh[row * 64 + ((kb ^ ((row & 7) << 4)) >> 1)];
      }
#pragma unroll
      for (int mi = 0; mi < 4; ++mi)
#pragma unroll
        for (int ni = 0; ni < 4; ++ni)
          acc[mi][ni] = __builtin_amdgcn_mfma_f32_16x16x32_bf16(
              af[mi], bfr[ni], acc[mi][ni], 0, 0, 0);
    }
    __syncthreads();
  }

  float t8[8]; int j8[8];
#pragma unroll
  for (int q = 0; q < 8; ++q) { t8[q] = NEG_INF; j8[q] = 0x7fffffff; }

  // ---- direction 1: rows of a, candidates = cols of b (v = 2*dot - sq_j) ----
#pragma unroll
  for (int qn = 0; qn < 4; ++qn) {
    float sqv = sqj_l[wc * 64 + qn * 16 + fr];
#pragma unroll
    for (int mi = 0; mi < 4; ++mi)
#pragma unroll
      for (int r = 0; r < 4; ++r)
        dl[w][mi * 16 + fg * 4 + r][fr] = 2.0f * acc[mi][qn][r] - sqv;
    __syncthreads();
    int jbase = bj0 + wc * 64 + qn * 16;
    for (int c = 0; c < 16; ++c) {
      float v = dl[w][lane][c];
      if (v > t8[7]) {
        t8[7] = v; j8[7] = jbase + c;
#pragma unroll
        for (int q = 7; q > 0; --q)
          if (t8[q] > t8[q - 1]) {
            float tv = t8[q]; t8[q] = t8[q - 1]; t8[q - 1] = tv;
            int tj = j8[q]; j8[q] = j8[q - 1]; j8[q - 1] = tj;
          }
      }
    }
    __syncthreads();
  }
  // pair-merge (wc halves) and store: row = ai0 + wr*64 + lane, set = b
#pragma unroll
  for (int q = 0; q < 8; ++q) {
    mv[(w * 64 + lane) * 8 + q] = t8[q];
    mj[(w * 64 + lane) * 8 + q] = j8[q];
  }
  __syncthreads();
  if ((w & 1) == 0) {
    int row = ai0 + (w >> 1) * 64 + lane;
    const float* v0 = &mv[(w * 64 + lane) * 8];
    const int*   c0 = &mj[(w * 64 + lane) * 8];
    const float* v1 = &mv[((w + 1) * 64 + lane) * 8];
    const int*   c1 = &mj[((w + 1) * 64 + lane) * 8];
    size_t ob = ((size_t)row * 64 + b) * 8;
    int h0 = 0, h1 = 0;
    for (int k = 0; k < 8; ++k) {
      float a0 = (h0 < 8) ? v0[h0] : NEG_INF;
      float a1 = (h1 < 8) ? v1[h1] : NEG_INF;
      int   b0 = (h0 < 8) ? c0[h0] : 0x7fffffff;
      int   b1 = (h1 < 8) ? c1[h1] : 0x7fffffff;
      bool take0 = (a0 > a1) || (a0 == a1 && b0 < b1);
      p8v[ob + k] = take0 ? a0 : a1;
      p8j[ob + k] = take0 ? b0 : b1;
      if (take0) ++h0; else ++h1;
    }
  }

  if (a != b) {
    __syncthreads();     // merge reads done before dl overwrite
#pragma unroll
    for (int q = 0; q < 8; ++q) { t8[q] = NEG_INF; j8[q] = 0x7fffffff; }
    // ---- direction 2: rows of b, candidates = rows of a (v = 2*dot - sq_i) ----
#pragma unroll
    for (int mi = 0; mi < 4; ++mi) {
      f32x4 sv = *(const f32x4*)&sqi_l[wr * 64 + mi * 16 + fg * 4];
#pragma unroll
      for (int ni = 0; ni < 4; ++ni)
#pragma unroll
        for (int r = 0; r < 4; ++r)
          dl[w][ni * 16 + fr][fg * 4 + r] = 2.0f * acc[mi][ni][r] - sv[r];
      __syncthreads();
      int ibase = ai0 + wr * 64 + mi * 16;
      for (int c = 0; c < 16; ++c) {
        float v = dl[w][lane][c];
        if (v > t8[7]) {
          t8[7] = v; j8[7] = ibase + c;
#pragma unroll
          for (int q = 7; q > 0; --q)
            if (t8[q] > t8[q - 1]) {
              float tv = t8[q]; t8[q] = t8[q - 1]; t8[q - 1] = tv;
              int tj = j8[q]; j8[q] = j8[q - 1]; j8[q - 1] = tj;
            }
        }
      }
      __syncthreads();
    }
    // pair-merge (wr halves) and store: row = bj0 + wc*64 + lane, set = a
#pragma unroll
    for (int q = 0; q < 8; ++q) {
      mv[(w * 64 + lane) * 8 + q] = t8[q];
      mj[(w * 64 + lane) * 8 + q] = j8[q];
    }
    __syncthreads();
    if (wr == 0) {
      int row = bj0 + wc * 64 + lane;
      const float* v0 = &mv[(w * 64 + lane) * 8];
      const int*   c0 = &mj[(w * 64 + lane) * 8];
      const float* v1 = &mv[((w + 2) * 64 + lane) * 8];
      const int*   c1 = &mj[((w + 2) * 64 + lane) * 8];
      size_t ob = ((size_t)row * 64 + a) * 8;
      int h0 = 0, h1 = 0;
      for (int k = 0; k < 8; ++k) {
        float a0 = (h0 < 8) ? v0[h0] : NEG_INF;
        float a1 = (h1 < 8) ? v1[h1] : NEG_INF;
        int   b0 = (h0 < 8) ? c0[h0] : 0x7fffffff;
        int   b1 = (h1 < 8) ? c1[h1] : 0x7fffffff;
        bool take0 = (a0 > a1) || (a0 == a1 && b0 < b1);
        p8v[ob + k] = take0 ? a0 : a1;
        p8j[ob + k] = take0 ? b0 : b1;
        if (take0) ++h0; else ++h1;
      }
    }
  }
}

// ------- wave-parallel merge: 64 sorted lists (one per lane) -> top-8 ---------
__global__ __launch_bounds__(256) void merge8w(const float* __restrict__ p8v,
                                               const int* __restrict__ p8j,
                                               int* __restrict__ cand, int P)
{
  int row = blockIdx.x * 4 + (threadIdx.x >> 6);
  int lane = threadIdx.x & 63;
  if (row >= P) return;
  const float* v = p8v + (size_t)row * 512 + lane * 8;
  const int* j = p8j + (size_t)row * 512 + lane * 8;
  float vv[8]; int jj[8];
#pragma unroll
  for (int q = 0; q < 8; ++q) { vv[q] = v[q]; jj[q] = j[q]; }
  for (int k = 0; k < 8; ++k) {
    float cv = vv[0]; int cj = jj[0];
#pragma unroll
    for (int off = 1; off < 64; off <<= 1) {
      float ov = __shfl_xor(cv, off);
      int oj = __shfl_xor(cj, off);
      if (ov > cv || (ov == cv && oj < cj)) { cv = ov; cj = oj; }
    }
    if (lane == 0) cand[row * 8 + k] = cj;
    if (jj[0] == cj) {
#pragma unroll
      for (int q = 0; q < 7; ++q) { vv[q] = vv[q + 1]; jj[q] = jj[q + 1]; }
      vv[7] = NEG_INF; jj[7] = 0x7fffffff;
    }
  }
}

// ---------------- exact fp32 rescore of 8 candidates -> top-3 --------------
__global__ __launch_bounds__(64) void rescore(
    const float* __restrict__ X, const float* __restrict__ sq,
    const int* __restrict__ cand, int* __restrict__ idx3)
{
  int i = blockIdx.x;
  int lane = threadIdx.x;
  f32x4 x0 = *(const f32x4*)&X[(size_t)i * 512 + lane * 8];
  f32x4 x1 = *(const f32x4*)&X[(size_t)i * 512 + lane * 8 + 4];
  float d[8]; int cj[8];
#pragma unroll
  for (int c = 0; c < 8; ++c) {
    int j = cand[i * 8 + c];
    cj[c] = j;
    f32x4 y0 = *(const f32x4*)&X[(size_t)j * 512 + lane * 8];
    f32x4 y1 = *(const f32x4*)&X[(size_t)j * 512 + lane * 8 + 4];
    float p = x0.x * y0.x + x0.y * y0.y + x0.z * y0.z + x0.w * y0.w
            + x1.x * y1.x + x1.y * y1.y + x1.z * y1.z + x1.w * y1.w;
#pragma unroll
    for (int off = 32; off > 0; off >>= 1) p += __shfl_xor(p, off);
    d[c] = 2.0f * p - sq[i] - sq[j];
  }
  if (lane == 0) {
    for (int k = 0; k < 3; ++k) {
      int b = 0;
#pragma unroll
      for (int c = 1; c < 8; ++c)
        if (d[c] > d[b] || (d[c] == d[b] && cj[c] < cj[b])) b = c;
      idx3[i * 3 + k] = cj[b];
      d[b] = NEG_INF; cj[b] = 0x7fffffff;
    }
  }
}

// ---------------- SMOTE lerp rows ----------------
__global__ void make_newfea(const float* __restrict__ X, const int* __restrict__ idx3,
                            const float* __restrict__ lw, float* __restrict__ out)
{
  int r = blockIdx.x;
  int i = r / 3, k = r - i * 3;
  int ai = idx3[i * 3 + 0];
  int bi = idx3[i * 3 + k];
  float w = lw[r];
  int t = threadIdx.x;
  float4 av = *(const float4*)&X[ai * 512 + t * 4];
  float4 bv = *(const float4*)&X[bi * 512 + t * 4];
  float4 o;
  o.x = av.x + w * (bv.x - av.x);
  o.y = av.y + w * (bv.y - av.y);
  o.z = av.z + w * (bv.z - av.z);
  o.w = av.w + w * (bv.w - av.w);
  *(float4*)&out[(size_t)r * 512 + t * 4] = o;
}

__global__ void write_lbl(const int* __restrict__ lbl, float* __restrict__ out,
                          int n_in, int n_total)
{
  int i = blockIdx.x * blockDim.x + threadIdx.x;
  if (i < n_total) out[i] = (i < n_in) ? (float)lbl[i] : 1.0f;
}

// ---------------- launch ----------------
extern "C" void kernel_launch(void* const* d_in, const int* in_sizes, int n_in,
                              void* d_out, int out_size, void* d_ws, size_t ws_size,
                              hipStream_t stream)
{
  const float* fea   = (const float*)d_in[0];
  const int*   lbl   = (const int*)d_in[1];
  const float* W1    = (const float*)d_in[2];
  const float* b1    = (const float*)d_in[3];
  const float* g1    = (const float*)d_in[4];
  const float* beta1 = (const float*)d_in[5];
  const float* W2    = (const float*)d_in[6];
  const float* b2    = (const float*)d_in[7];
  const float* g2    = (const float*)d_in[8];
  const float* beta2 = (const float*)d_in[9];
  const float* lerp_w = (const float*)d_in[10];

  int bs = in_sizes[0] / 512;       // 32768
  int P  = in_sizes[10] / 3;        // 8192
  int n_total = bs + 3 * P;         // 57344

  float* out_f = (float*)d_out;
  float* Hout = out_f;
  float* newfea = out_f + (size_t)bs * 512;
  float* lbl_out = out_f + (size_t)n_total * 512;

  const size_t MB = 1024 * 1024;
  const size_t KB = 1024;
  char* ws = (char*)d_ws;
  float* Y1 = (float*)ws;                                  // 64MB fp32 y1 -> h1
  float* X  = (float*)(ws + 64 * MB);                      // 16MB (after weights dead)
  unsigned short* W1h = (unsigned short*)(ws + 64 * MB);
  unsigned short* W1m = (unsigned short*)(ws + 64 * MB + 512 * KB);
  unsigned short* W1l = (unsigned short*)(ws + 64 * MB + 1024 * KB);
  unsigned short* W2h = (unsigned short*)(ws + 64 * MB + 1536 * KB);
  unsigned short* W2m = (unsigned short*)(ws + 64 * MB + 2048 * KB);
  unsigned short* W2l = (unsigned short*)(ws + 64 * MB + 2560 * KB);
  float* partial = (float*)(ws + 80 * MB);                 // 2MB
  float* scale = (float*)(ws + 82 * MB);
  float* shiftv = scale + 512;
  float* sq = shiftv + 512;
  int* pos = (int*)(sq + 8192);
  int* idx3 = pos + 8192;
  int* cnt = idx3 + 3 * 8192;                              // 32 ints
  float* partial2 = (float*)(ws + 83 * MB);                // 64KB
  // overlays in dead Y1 region (used only after gemm2):
  unsigned short* Xh = (unsigned short*)ws;                // 8MB
  float* p8v = (float*)(ws + 8 * MB);                      // 16MB (8192 x 64 x 8)
  int*   p8j = (int*)(ws + 24 * MB);                       // 16MB
  int*   cand = (int*)(ws + 40 * MB);                      // 256KB

  dim3 wgrid(8, 8);
  split_w_t3<<<wgrid, 256, 0, stream>>>(W1, W1h, W1m, W1l);
  split_w_t3<<<wgrid, 256, 0, stream>>>(W2, W2h, W2m, W2l);

  dim3 ggrid(bs / 128, 4);
  int nslot = (bs / 128) * 2;          // 512
  dim3 rgrid(16, 2);

  gemm_split3<<<ggrid, 256, 0, stream>>>(fea, W1h, W1m, W1l, b1, Y1, partial);
  bn_reduce1<<<rgrid, 256, 0, stream>>>(partial, partial2, nslot);
  bn_finalize<<<2, 256, 0, stream>>>(partial2, g1, beta1, scale, shiftv, bs);
  bn_swish<<<(bs * 512 / 4 + 255) / 256, 256, 0, stream>>>(Y1, scale, shiftv, Y1, bs * 512 / 4);

  gemm_split3<<<ggrid, 256, 0, stream>>>(Y1, W2h, W2m, W2l, b2, Hout, partial);
  bn_reduce1<<<rgrid, 256, 0, stream>>>(partial, partial2, nslot);
  bn_finalize<<<2, 256, 0, stream>>>(partial2, g2, beta2, scale, shiftv, bs);
  bn_swish<<<(bs * 512 / 4 + 255) / 256, 256, 0, stream>>>(Hout, scale, shiftv, Hout, bs * 512 / 4);

  int nb = (bs + 1023) / 1024;         // 32
  pos_count<<<nb, 1024, 0, stream>>>(lbl, bs, cnt, pos, P);
  pos_prefix<<<1, 64, 0, stream>>>(cnt, nb);
  pos_scatter<<<nb, 1024, 0, stream>>>(lbl, bs, cnt, pos, P);
  gather_sq<<<P, 128, 0, stream>>>(Hout, pos, X, Xh, sq);

  int nbk = P / 128;                    // 64
  int ntri = nbk * (nbk + 1) / 2;       // 2080
  gram_sym<<<ntri, 256, 0, stream>>>(Xh, sq, p8v, p8j);
  merge8w<<<(P + 3) / 4, 256, 0, stream>>>(p8v, p8j, cand, P);
  rescore<<<P, 64, 0, stream>>>(X, sq, cand, idx3);

  make_newfea<<<3 * P, 128, 0, stream>>>(X, idx3, lerp_w, newfea);
  write_lbl<<<(n_total + 255) / 256, 256, 0, stream>>>(lbl, lbl_out, bs, n_total);
}

// Round 10
// 459.014 us; speedup vs baseline: 4.9700x; 1.0010x over previous
//
#include <hip/hip_runtime.h>
#include <math.h>

#define NEG_INF -3.402823466e38f

typedef __attribute__((ext_vector_type(8))) short bf16x8;
typedef __attribute__((ext_vector_type(4))) float f32x4;

__device__ __forceinline__ void gload_lds16(const unsigned short* g, unsigned short* l) {
  __builtin_amdgcn_global_load_lds(
      (const __attribute__((address_space(1))) unsigned int*)g,
      (__attribute__((address_space(3))) unsigned int*)l, 16, 0, 0);
}
__device__ __forceinline__ void gload_lds16f(const float* g, float* l) {
  __builtin_amdgcn_global_load_lds(
      (const __attribute__((address_space(1))) unsigned int*)g,
      (__attribute__((address_space(3))) unsigned int*)l, 16, 0, 0);
}

__device__ __forceinline__ unsigned short f2bf(float f) {
  union { float f; unsigned int u; } a; a.f = f;
  unsigned int u = a.u;
  return (unsigned short)((u + 0x7fffu + ((u >> 16) & 1u)) >> 16);
}

// pairwise 3-term truncation split: 8 f32 -> hi/mid/lo bf16x8.
__device__ __forceinline__ void split3_8(f32x4 a, f32x4 b,
                                         bf16x8& hi, bf16x8& md, bf16x8& lo) {
  union { bf16x8 v; unsigned int u[4]; } H, M, L;
  float f[8];
  f[0]=a[0]; f[1]=a[1]; f[2]=a[2]; f[3]=a[3];
  f[4]=b[0]; f[5]=b[1]; f[6]=b[2]; f[7]=b[3];
#pragma unroll
  for (int p = 0; p < 4; ++p) {
    union { float f; unsigned int u; } x0, x1, h0, h1, r0, r1, m0, m1, s0, s1;
    x0.f = f[2*p]; x1.f = f[2*p+1];
    H.u[p] = (x0.u >> 16) | (x1.u & 0xffff0000u);
    h0.u = x0.u & 0xffff0000u; h1.u = x1.u & 0xffff0000u;
    r0.f = x0.f - h0.f;        r1.f = x1.f - h1.f;
    M.u[p] = (r0.u >> 16) | (r1.u & 0xffff0000u);
    m0.u = r0.u & 0xffff0000u; m1.u = r1.u & 0xffff0000u;
    s0.f = r0.f - m0.f;        s1.f = r1.f - m1.f;
    L.u[p] = (s0.u >> 16) | (s1.u & 0xffff0000u);
  }
  hi = H.v; md = M.v; lo = L.v;
}

// ------ split+transpose weights: W[512][512] -> Wt_{h,m,l}[n][k] --------------
__global__ __launch_bounds__(256) void split_w_t3(const float* __restrict__ W,
    unsigned short* __restrict__ Th, unsigned short* __restrict__ Tm,
    unsigned short* __restrict__ Tl)
{
  __shared__ float T[64][65];
  int k0 = blockIdx.x * 64, n0 = blockIdx.y * 64;
  int tid = threadIdx.x;
  int r = tid >> 4, c4 = (tid & 15) << 2;
#pragma unroll
  for (int p = 0; p < 4; ++p) {
    int row = r + p * 16;
    float4 v = *(const float4*)&W[(size_t)(k0 + row) * 512 + n0 + c4];
    T[c4 + 0][row] = v.x; T[c4 + 1][row] = v.y;
    T[c4 + 2][row] = v.z; T[c4 + 3][row] = v.w;
  }
  __syncthreads();
  int nr = tid >> 2, kc = (tid & 3) << 4;
#pragma unroll
  for (int u = 0; u < 16; ++u) {
    union { float f; unsigned int u; } x, h, rr, m, ss;
    x.f = T[nr][kc + u];
    unsigned short hb = (unsigned short)(x.u >> 16);
    h.u = x.u & 0xffff0000u;
    rr.f = x.f - h.f;
    unsigned short mb = (unsigned short)(rr.u >> 16);
    m.u = rr.u & 0xffff0000u;
    ss.f = rr.f - m.f;
    unsigned short lb = (unsigned short)(ss.u >> 16);
    size_t o = (size_t)(n0 + nr) * 512 + k0 + kc + u;
    Th[o] = hb; Tm[o] = mb; Tl[o] = lb;
  }
}

// ------ GEMM: dbuf BK=32, wave = 32 rows x 128 cols (2 splits/iter) -----------
__global__ __launch_bounds__(256, 2) void gemm_split3(
    const float* __restrict__ A, const unsigned short* __restrict__ Bth,
    const unsigned short* __restrict__ Btm, const unsigned short* __restrict__ Btl,
    const float* __restrict__ bias, float* __restrict__ C, float* __restrict__ partial)
{
  __shared__ char smem[81920];   // 2 x (sA 16K + 3x8K B)
  const int tid = threadIdx.x;
  const int w = tid >> 6, lane = tid & 63;
  const int bm = blockIdx.x * 128, bn = blockIdx.y * 128;
  const int fr = lane & 15, fg = lane >> 4;
  const int arow = tid >> 3, acb = (tid & 7) << 4;
  const int brow = tid >> 2, bcb = (tid & 3) << 4;

  f32x4 acc[2][8];
#pragma unroll
  for (int mi = 0; mi < 2; ++mi)
#pragma unroll
    for (int ni = 0; ni < 8; ++ni) acc[mi][ni] = (f32x4){0.f, 0.f, 0.f, 0.f};

  auto STAGE = [&](int buf, int ktf) {
    float* sA = (float*)(smem + buf * 40960);
    unsigned short* sBh = (unsigned short*)(smem + buf * 40960 + 16384);
    unsigned short* sBm = sBh + 4096;
    unsigned short* sBl = sBm + 4096;
#pragma unroll
    for (int p = 0; p < 4; ++p) {
      int row = arow + p * 32;
      int cb = acb ^ ((row & 7) << 4);
      gload_lds16f(&A[(size_t)(bm + row) * 512 + ktf + (cb >> 2)],
                   &sA[row * 32 + (acb >> 2)]);
    }
#pragma unroll
    for (int p = 0; p < 2; ++p) {
      int row = brow + p * 64;
      int cb = bcb ^ (((row >> 1) & 3) << 4);
      int so = row * 32 + (bcb >> 1);
      gload_lds16(&Bth[(size_t)(bn + row) * 512 + ktf + (cb >> 1)], &sBh[so]);
      gload_lds16(&Btm[(size_t)(bn + row) * 512 + ktf + (cb >> 1)], &sBm[so]);
      gload_lds16(&Btl[(size_t)(bn + row) * 512 + ktf + (cb >> 1)], &sBl[so]);
    }
  };

  STAGE(0, 0);
  __syncthreads();
  for (int it = 0; it < 16; ++it) {
    int cur = it & 1;
    if (it + 1 < 16) STAGE(cur ^ 1, (it + 1) * 32);
    float* sA = (float*)(smem + cur * 40960);
    unsigned short* sBh = (unsigned short*)(smem + cur * 40960 + 16384);
    unsigned short* sBm = sBh + 4096;
    unsigned short* sBl = sBm + 4096;
    bf16x8 ah[2], am[2], al[2];
#pragma unroll
    for (int mi = 0; mi < 2; ++mi) {
      int row = w * 32 + mi * 16 + fr;
      int swz = (row & 7) << 4;
      const char* rb = (const char*)(sA + row * 32);
      f32x4 f0 = *(const f32x4*)(rb + ((fg * 32) ^ swz));
      f32x4 f1 = *(const f32x4*)(rb + ((fg * 32 + 16) ^ swz));
      split3_8(f0, f1, ah[mi], am[mi], al[mi]);
    }
#pragma unroll
    for (int ni = 0; ni < 8; ++ni) {
      int row = ni * 16 + fr;
      int off = row * 32 + (((fg * 16) ^ (((row >> 1) & 3) << 4)) >> 1);
      bf16x8 bh  = *(const bf16x8*)&sBh[off];
      bf16x8 bmf = *(const bf16x8*)&sBm[off];
      bf16x8 blf = *(const bf16x8*)&sBl[off];
#pragma unroll
      for (int mi = 0; mi < 2; ++mi) {
        acc[mi][ni] = __builtin_amdgcn_mfma_f32_16x16x32_bf16(al[mi], bh,  acc[mi][ni], 0, 0, 0);
        acc[mi][ni] = __builtin_amdgcn_mfma_f32_16x16x32_bf16(am[mi], bmf, acc[mi][ni], 0, 0, 0);
        acc[mi][ni] = __builtin_amdgcn_mfma_f32_16x16x32_bf16(ah[mi], blf, acc[mi][ni], 0, 0, 0);
        acc[mi][ni] = __builtin_amdgcn_mfma_f32_16x16x32_bf16(am[mi], bh,  acc[mi][ni], 0, 0, 0);
        acc[mi][ni] = __builtin_amdgcn_mfma_f32_16x16x32_bf16(ah[mi], bmf, acc[mi][ni], 0, 0, 0);
        acc[mi][ni] = __builtin_amdgcn_mfma_f32_16x16x32_bf16(ah[mi], bh,  acc[mi][ni], 0, 0, 0);
      }
    }
    __syncthreads();
  }

  float ssv[8], qqv[8];
#pragma unroll
  for (int ni = 0; ni < 8; ++ni) {
    float bno = bias[bn + ni * 16 + fr];
    float s = 0.f, q = 0.f;
#pragma unroll
    for (int mi = 0; mi < 2; ++mi) {
      int row = bm + w * 32 + mi * 16 + fg * 4;
      int col = bn + ni * 16 + fr;
#pragma unroll
      for (int r = 0; r < 4; ++r) {
        float v = acc[mi][ni][r] + bno;
        C[(size_t)(row + r) * 512 + col] = v;
        s += v; q += v * v;
      }
    }
    s += __shfl_xor(s, 16); s += __shfl_xor(s, 32);
    q += __shfl_xor(q, 16); q += __shfl_xor(q, 32);
    ssv[ni] = s; qqv[ni] = q;
  }
  float* ps = (float*)smem;
  if (fg == 0) {
#pragma unroll
    for (int ni = 0; ni < 8; ++ni) {
      ps[((w * 2 + 0) * 8 + ni) * 16 + fr] = ssv[ni];
      ps[((w * 2 + 1) * 8 + ni) * 16 + fr] = qqv[ni];
    }
  }
  __syncthreads();
  if ((w & 1) == 0) {
    int p = w >> 1;
#pragma unroll
    for (int k = 0; k < 4; ++k) {
      int idx = k * 64 + lane;
      int part = idx >> 7;
      int rem = idx & 127;
      int ni = rem >> 4, fr2 = rem & 15;
      float v = ps[(((2 * p) * 2 + part) * 8 + ni) * 16 + fr2]
              + ps[(((2 * p + 1) * 2 + part) * 8 + ni) * 16 + fr2];
      int slot = blockIdx.x * 2 + p;
      partial[(size_t)(slot * 2 + part) * 512 + bn + ni * 16 + fr2] = v;
    }
  }
}

// ------ BN reduce stage 1 --------
__global__ __launch_bounds__(256) void bn_reduce1(
    const float* __restrict__ partial, float* __restrict__ partial2, int nslot)
{
  int g = blockIdx.x, p = blockIdx.y;
  int per = nslot >> 4;
  int t = threadIdx.x;
#pragma unroll
  for (int cc = 0; cc < 2; ++cc) {
    int c = t + cc * 256;
    float s = 0.f;
    for (int s0 = 0; s0 < per; ++s0) {
      int slot = g * per + s0;
      s += partial[(size_t)(slot * 2 + p) * 512 + c];
    }
    partial2[(size_t)(g * 2 + p) * 512 + c] = s;
  }
}

__global__ void bn_finalize(
    const float* __restrict__ partial2, const float* __restrict__ g,
    const float* __restrict__ beta, float* __restrict__ scale,
    float* __restrict__ shift, int rows)
{
  int c = blockIdx.x * blockDim.x + threadIdx.x;
  if (c >= 512) return;
  float s = 0, s2 = 0;
  for (int b = 0; b < 16; ++b) {
    s  += partial2[(size_t)(b * 2 + 0) * 512 + c];
    s2 += partial2[(size_t)(b * 2 + 1) * 512 + c];
  }
  float m = s / rows;
  float v = s2 / rows - m * m;
  if (v < 0) v = 0;
  float sc = g[c] / sqrtf(v + 1e-5f);
  scale[c] = sc;
  shift[c] = beta[c] - m * sc;
}

__global__ void bn_swish(
    const float* __restrict__ Y, const float* __restrict__ scale,
    const float* __restrict__ shift, float* __restrict__ H, int total4)
{
  int i = blockIdx.x * blockDim.x + threadIdx.x;
  if (i >= total4) return;
  float4 y = ((const float4*)Y)[i];
  int c = (i * 4) & 511;
  float z;
  float4 o;
  z = y.x * scale[c + 0] + shift[c + 0]; o.x = z / (1.f + expf(-z));
  z = y.y * scale[c + 1] + shift[c + 1]; o.y = z / (1.f + expf(-z));
  z = y.z * scale[c + 2] + shift[c + 2]; o.z = z / (1.f + expf(-z));
  z = y.w * scale[c + 3] + shift[c + 3]; o.w = z / (1.f + expf(-z));
  ((float4*)H)[i] = o;
}

// ---------------- positive-label compaction: 3-kernel scan ----------------
__global__ __launch_bounds__(1024) void pos_count(const int* __restrict__ lbl, int n,
                                                  int* __restrict__ cnt,
                                                  int* __restrict__ pos, int P)
{
  int b = blockIdx.x, tid = threadIdx.x;
  int i = b * 1024 + tid;
  if (i < P) pos[i] = 0;
  int pred = (i < n) && (lbl[i] > 0);
  unsigned long long m = __ballot(pred);
  __shared__ int ws[16];
  if ((tid & 63) == 0) ws[tid >> 6] = __popcll(m);
  __syncthreads();
  if (tid == 0) { int s = 0; for (int k = 0; k < 16; ++k) s += ws[k]; cnt[b] = s; }
}

__global__ void pos_prefix(int* __restrict__ cnt, int nb)
{
  if (threadIdx.x == 0) {
    int s = 0;
    for (int b = 0; b < nb; ++b) { int c = cnt[b]; cnt[b] = s; s += c; }
  }
}

__global__ __launch_bounds__(1024) void pos_scatter(const int* __restrict__ lbl, int n,
                                                    const int* __restrict__ cntp,
                                                    int* __restrict__ pos, int P)
{
  int b = blockIdx.x, tid = threadIdx.x;
  int i = b * 1024 + tid;
  int pred = (i < n) && (lbl[i] > 0);
  unsigned long long m = __ballot(pred);
  __shared__ int ws[16];
  int wid = tid >> 6, lane = tid & 63;
  if (lane == 0) ws[wid] = __popcll(m);
  __syncthreads();
  int wbase = 0;
  for (int w2 = 0; w2 < wid; ++w2) wbase += ws[w2];
  int rank = cntp[b] + wbase + __popcll(m & ((1ull << lane) - 1ull));
  if (pred && rank < P) pos[rank] = i;
}

// ---------------- gather positives + sq norms + bf16 copy ----------------
__global__ void gather_sq(const float* __restrict__ H, const int* __restrict__ pos,
                          float* __restrict__ X, unsigned short* __restrict__ Xh,
                          float* __restrict__ sq)
{
  int r = blockIdx.x, t = threadIdx.x;  // 128 threads
  int src = pos[r];
  float4 v = *(const float4*)&H[src * 512 + t * 4];
  *(float4*)&X[r * 512 + t * 4] = v;
  ushort4 hv;
  hv.x = f2bf(v.x); hv.y = f2bf(v.y); hv.z = f2bf(v.z); hv.w = f2bf(v.w);
  *(ushort4*)&Xh[r * 512 + t * 4] = hv;
  float s = v.x * v.x + v.y * v.y + v.z * v.z + v.w * v.w;
#pragma unroll
  for (int off = 32; off > 0; off >>= 1) s += __shfl_down(s, off);
  __shared__ float red[2];
  if ((t & 63) == 0) red[t >> 6] = s;
  __syncthreads();
  if (t == 0) sq[r] = red[0] + red[1];
}

// ------ symmetric Gram: one block per upper-tri 128x128 tile, dual scan -------
// dl widened to 32 cols -> half the scan barriers; 4 blocks/CU.
__global__ __launch_bounds__(256, 4) void gram_sym(
    const unsigned short* __restrict__ Xh, const float* __restrict__ sq,
    float* __restrict__ p8v, int* __restrict__ p8j)
{
  __shared__ char smem[33792];         // staging 32K; dl [4][64][33] overlay; merge overlay
  __shared__ float sqi_l[128], sqj_l[128];
  unsigned short* Ah = (unsigned short*)smem;          // 16K
  unsigned short* Bh = (unsigned short*)(smem + 16384);// 16K
  float (*dl)[64][33] = (float (*)[64][33])(void*)smem; // 33792B overlay (post k-loop)
  float* mv = (float*)smem;                             // 8K overlay (post scan)
  int*   mj = (int*)(smem + 8192);                      // 8K

  const int tid = threadIdx.x;
  const int w = tid >> 6, lane = tid & 63;
  const int wr = w >> 1, wc = w & 1;
  const int fr = lane & 15, fg = lane >> 4;
  const int srow = tid >> 3;
  const int scb  = (tid & 7) << 4;

  // decode upper-triangular (a,b), a<=b, from linear block id
  int t = blockIdx.x;
  int a = (int)(64.5f - sqrtf(64.5f * 64.5f - 2.0f * (float)t));
  if (a < 0) a = 0;
  while (a > 0 && (a * (129 - a)) / 2 > t) --a;
  while (((a + 1) * (128 - a)) / 2 <= t) ++a;
  int b = a + (t - (a * (129 - a)) / 2);
  const int ai0 = a * 128, bj0 = b * 128;

  if (tid < 128) { sqi_l[tid] = sq[ai0 + tid]; sqj_l[tid] = sq[bj0 + tid]; }

  f32x4 acc[4][4];
#pragma unroll
  for (int mi = 0; mi < 4; ++mi)
#pragma unroll
    for (int ni = 0; ni < 4; ++ni) acc[mi][ni] = (f32x4){0.f, 0.f, 0.f, 0.f};

  for (int kt = 0; kt < 512; kt += 64) {
#pragma unroll
    for (int it = 0; it < 4; ++it) {
      int row = srow + it * 32;
      int cb = scb ^ ((row & 7) << 4);
      gload_lds16(&Xh[(size_t)(ai0 + row) * 512 + kt + (cb >> 1)],
                  &Ah[row * 64 + (scb >> 1)]);
      gload_lds16(&Xh[(size_t)(bj0 + row) * 512 + kt + (cb >> 1)],
                  &Bh[row * 64 + (scb >> 1)]);
    }
    __syncthreads();
#pragma unroll
    for (int ks = 0; ks < 2; ++ks) {
      bf16x8 af[4], bfr[4];
      int kb = ks * 64 + fg * 16;
#pragma unroll
      for (int mi = 0; mi < 4; ++mi) {
        int row = wr * 64 + mi * 16 + fr;
        af[mi] = *(const bf16x8*)&Ah[row * 64 + ((kb ^ ((row & 7) << 4)) >> 1)];
      }
#pragma unroll
      for (int ni = 0; ni < 4; ++ni) {
        int row = wc * 64 + ni * 16 + fr;
        bfr[ni] = *(const bf16x8*)&Bh[row * 64 + ((kb ^ ((row & 7) << 4)) >> 1)];
      }
#pragma unroll
      for (int mi = 0; mi < 4; ++mi)
#pragma unroll
        for (int ni = 0; ni < 4; ++ni)
          acc[mi][ni] = __builtin_amdgcn_mfma_f32_16x16x32_bf16(
              af[mi], bfr[ni], acc[mi][ni], 0, 0, 0);
    }
    __syncthreads();
  }

  float t8[8]; int j8[8];
#pragma unroll
  for (int q = 0; q < 8; ++q) { t8[q] = NEG_INF; j8[q] = 0x7fffffff; }

  // ---- direction 1: rows of a, candidates = cols of b (v = 2*dot - sq_j) ----
#pragma unroll
  for (int qp = 0; qp < 2; ++qp) {
#pragma unroll
    for (int qh = 0; qh < 2; ++qh) {
      int qn = qp * 2 + qh;
      float sqv = sqj_l[wc * 64 + qn * 16 + fr];
#pragma unroll
      for (int mi = 0; mi < 4; ++mi)
#pragma unroll
        for (int r = 0; r < 4; ++r)
          dl[w][mi * 16 + fg * 4 + r][qh * 16 + fr] = 2.0f * acc[mi][qn][r] - sqv;
    }
    __syncthreads();
    int jbase = bj0 + wc * 64 + qp * 32;
    for (int c = 0; c < 32; ++c) {
      float v = dl[w][lane][c];
      if (v > t8[7]) {
        t8[7] = v; j8[7] = jbase + c;
#pragma unroll
        for (int q = 7; q > 0; --q)
          if (t8[q] > t8[q - 1]) {
            float tv = t8[q]; t8[q] = t8[q - 1]; t8[q - 1] = tv;
            int tj = j8[q]; j8[q] = j8[q - 1]; j8[q - 1] = tj;
          }
      }
    }
    __syncthreads();
  }
  // pair-merge (wc halves) and store: row = ai0 + wr*64 + lane, set = b
#pragma unroll
  for (int q = 0; q < 8; ++q) {
    mv[(w * 64 + lane) * 8 + q] = t8[q];
    mj[(w * 64 + lane) * 8 + q] = j8[q];
  }
  __syncthreads();
  if ((w & 1) == 0) {
    int row = ai0 + (w >> 1) * 64 + lane;
    const float* v0 = &mv[(w * 64 + lane) * 8];
    const int*   c0 = &mj[(w * 64 + lane) * 8];
    const float* v1 = &mv[((w + 1) * 64 + lane) * 8];
    const int*   c1 = &mj[((w + 1) * 64 + lane) * 8];
    size_t ob = ((size_t)row * 64 + b) * 8;
    int h0 = 0, h1 = 0;
    for (int k = 0; k < 8; ++k) {
      float a0 = (h0 < 8) ? v0[h0] : NEG_INF;
      float a1 = (h1 < 8) ? v1[h1] : NEG_INF;
      int   b0 = (h0 < 8) ? c0[h0] : 0x7fffffff;
      int   b1 = (h1 < 8) ? c1[h1] : 0x7fffffff;
      bool take0 = (a0 > a1) || (a0 == a1 && b0 < b1);
      p8v[ob + k] = take0 ? a0 : a1;
      p8j[ob + k] = take0 ? b0 : b1;
      if (take0) ++h0; else ++h1;
    }
  }

  if (a != b) {
    __syncthreads();     // merge reads done before dl overwrite
#pragma unroll
    for (int q = 0; q < 8; ++q) { t8[q] = NEG_INF; j8[q] = 0x7fffffff; }
    // ---- direction 2: rows of b, candidates = rows of a (v = 2*dot - sq_i) ----
#pragma unroll
    for (int mp = 0; mp < 2; ++mp) {
#pragma unroll
      for (int mh = 0; mh < 2; ++mh) {
        int mi = mp * 2 + mh;
        f32x4 sv = *(const f32x4*)&sqi_l[wr * 64 + mi * 16 + fg * 4];
#pragma unroll
        for (int ni = 0; ni < 4; ++ni)
#pragma unroll
          for (int r = 0; r < 4; ++r)
            dl[w][ni * 16 + fr][mh * 16 + fg * 4 + r] = 2.0f * acc[mi][ni][r] - sv[r];
      }
      __syncthreads();
      int ibase = ai0 + wr * 64 + mp * 32;
      for (int c = 0; c < 32; ++c) {
        float v = dl[w][lane][c];
        if (v > t8[7]) {
          t8[7] = v; j8[7] = ibase + c;
#pragma unroll
          for (int q = 7; q > 0; --q)
            if (t8[q] > t8[q - 1]) {
              float tv = t8[q]; t8[q] = t8[q - 1]; t8[q - 1] = tv;
              int tj = j8[q]; j8[q] = j8[q - 1]; j8[q - 1] = tj;
            }
        }
      }
      __syncthreads();
    }
    // pair-merge (wr halves) and store: row = bj0 + wc*64 + lane, set = a
#pragma unroll
    for (int q = 0; q < 8; ++q) {
      mv[(w * 64 + lane) * 8 + q] = t8[q];
      mj[(w * 64 + lane) * 8 + q] = j8[q];
    }
    __syncthreads();
    if (wr == 0) {
      int row = bj0 + wc * 64 + lane;
      const float* v0 = &mv[(w * 64 + lane) * 8];
      const int*   c0 = &mj[(w * 64 + lane) * 8];
      const float* v1 = &mv[((w + 2) * 64 + lane) * 8];
      const int*   c1 = &mj[((w + 2) * 64 + lane) * 8];
      size_t ob = ((size_t)row * 64 + a) * 8;
      int h0 = 0, h1 = 0;
      for (int k = 0; k < 8; ++k) {
        float a0 = (h0 < 8) ? v0[h0] : NEG_INF;
        float a1 = (h1 < 8) ? v1[h1] : NEG_INF;
        int   b0 = (h0 < 8) ? c0[h0] : 0x7fffffff;
        int   b1 = (h1 < 8) ? c1[h1] : 0x7fffffff;
        bool take0 = (a0 > a1) || (a0 == a1 && b0 < b1);
        p8v[ob + k] = take0 ? a0 : a1;
        p8j[ob + k] = take0 ? b0 : b1;
        if (take0) ++h0; else ++h1;
      }
    }
  }
}

// ------- wave-parallel merge: 64 sorted lists (one per lane) -> top-8 ---------
__global__ __launch_bounds__(256) void merge8w(const float* __restrict__ p8v,
                                               const int* __restrict__ p8j,
                                               int* __restrict__ cand, int P)
{
  int row = blockIdx.x * 4 + (threadIdx.x >> 6);
  int lane = threadIdx.x & 63;
  if (row >= P) return;
  const float* v = p8v + (size_t)row * 512 + lane * 8;
  const int* j = p8j + (size_t)row * 512 + lane * 8;
  float vv[8]; int jj[8];
#pragma unroll
  for (int q = 0; q < 8; ++q) { vv[q] = v[q]; jj[q] = j[q]; }
  for (int k = 0; k < 8; ++k) {
    float cv = vv[0]; int cj = jj[0];
#pragma unroll
    for (int off = 1; off < 64; off <<= 1) {
      float ov = __shfl_xor(cv, off);
      int oj = __shfl_xor(cj, off);
      if (ov > cv || (ov == cv && oj < cj)) { cv = ov; cj = oj; }
    }
    if (lane == 0) cand[row * 8 + k] = cj;
    if (jj[0] == cj) {
#pragma unroll
      for (int q = 0; q < 7; ++q) { vv[q] = vv[q + 1]; jj[q] = jj[q + 1]; }
      vv[7] = NEG_INF; jj[7] = 0x7fffffff;
    }
  }
}

// ---------------- exact fp32 rescore of 8 candidates -> top-3 --------------
__global__ __launch_bounds__(64) void rescore(
    const float* __restrict__ X, const float* __restrict__ sq,
    const int* __restrict__ cand, int* __restrict__ idx3)
{
  int i = blockIdx.x;
  int lane = threadIdx.x;
  f32x4 x0 = *(const f32x4*)&X[(size_t)i * 512 + lane * 8];
  f32x4 x1 = *(const f32x4*)&X[(size_t)i * 512 + lane * 8 + 4];
  float d[8]; int cj[8];
#pragma unroll
  for (int c = 0; c < 8; ++c) {
    int j = cand[i * 8 + c];
    cj[c] = j;
    f32x4 y0 = *(const f32x4*)&X[(size_t)j * 512 + lane * 8];
    f32x4 y1 = *(const f32x4*)&X[(size_t)j * 512 + lane * 8 + 4];
    float p = x0.x * y0.x + x0.y * y0.y + x0.z * y0.z + x0.w * y0.w
            + x1.x * y1.x + x1.y * y1.y + x1.z * y1.z + x1.w * y1.w;
#pragma unroll
    for (int off = 32; off > 0; off >>= 1) p += __shfl_xor(p, off);
    d[c] = 2.0f * p - sq[i] - sq[j];
  }
  if (lane == 0) {
    for (int k = 0; k < 3; ++k) {
      int b = 0;
#pragma unroll
      for (int c = 1; c < 8; ++c)
        if (d[c] > d[b] || (d[c] == d[b] && cj[c] < cj[b])) b = c;
      idx3[i * 3 + k] = cj[b];
      d[b] = NEG_INF; cj[b] = 0x7fffffff;
    }
  }
}

// ---------------- SMOTE lerp rows ----------------
__global__ void make_newfea(const float* __restrict__ X, const int* __restrict__ idx3,
                            const float* __restrict__ lw, float* __restrict__ out)
{
  int r = blockIdx.x;
  int i = r / 3, k = r - i * 3;
  int ai = idx3[i * 3 + 0];
  int bi = idx3[i * 3 + k];
  float w = lw[r];
  int t = threadIdx.x;
  float4 av = *(const float4*)&X[ai * 512 + t * 4];
  float4 bv = *(const float4*)&X[bi * 512 + t * 4];
  float4 o;
  o.x = av.x + w * (bv.x - av.x);
  o.y = av.y + w * (bv.y - av.y);
  o.z = av.z + w * (bv.z - av.z);
  o.w = av.w + w * (bv.w - av.w);
  *(float4*)&out[(size_t)r * 512 + t * 4] = o;
}

__global__ void write_lbl(const int* __restrict__ lbl, float* __restrict__ out,
                          int n_in, int n_total)
{
  int i = blockIdx.x * blockDim.x + threadIdx.x;
  if (i < n_total) out[i] = (i < n_in) ? (float)lbl[i] : 1.0f;
}

// ---------------- launch ----------------
extern "C" void kernel_launch(void* const* d_in, const int* in_sizes, int n_in,
                              void* d_out, int out_size, void* d_ws, size_t ws_size,
                              hipStream_t stream)
{
  const float* fea   = (const float*)d_in[0];
  const int*   lbl   = (const int*)d_in[1];
  const float* W1    = (const float*)d_in[2];
  const float* b1    = (const float*)d_in[3];
  const float* g1    = (const float*)d_in[4];
  const float* beta1 = (const float*)d_in[5];
  const float* W2    = (const float*)d_in[6];
  const float* b2    = (const float*)d_in[7];
  const float* g2    = (const float*)d_in[8];
  const float* beta2 = (const float*)d_in[9];
  const float* lerp_w = (const float*)d_in[10];

  int bs = in_sizes[0] / 512;       // 32768
  int P  = in_sizes[10] / 3;        // 8192
  int n_total = bs + 3 * P;         // 57344

  float* out_f = (float*)d_out;
  float* Hout = out_f;
  float* newfea = out_f + (size_t)bs * 512;
  float* lbl_out = out_f + (size_t)n_total * 512;

  const size_t MB = 1024 * 1024;
  const size_t KB = 1024;
  char* ws = (char*)d_ws;
  float* Y1 = (float*)ws;                                  // 64MB fp32 y1 -> h1
  float* X  = (float*)(ws + 64 * MB);                      // 16MB (after weights dead)
  unsigned short* W1h = (unsigned short*)(ws + 64 * MB);
  unsigned short* W1m = (unsigned short*)(ws + 64 * MB + 512 * KB);
  unsigned short* W1l = (unsigned short*)(ws + 64 * MB + 1024 * KB);
  unsigned short* W2h = (unsigned short*)(ws + 64 * MB + 1536 * KB);
  unsigned short* W2m = (unsigned short*)(ws + 64 * MB + 2048 * KB);
  unsigned short* W2l = (unsigned short*)(ws + 64 * MB + 2560 * KB);
  float* partial = (float*)(ws + 80 * MB);                 // 2MB
  float* scale = (float*)(ws + 82 * MB);
  float* shiftv = scale + 512;
  float* sq = shiftv + 512;
  int* pos = (int*)(sq + 8192);
  int* idx3 = pos + 8192;
  int* cnt = idx3 + 3 * 8192;                              // 32 ints
  float* partial2 = (float*)(ws + 83 * MB);                // 64KB
  // overlays in dead Y1 region (used only after gemm2):
  unsigned short* Xh = (unsigned short*)ws;                // 8MB
  float* p8v = (float*)(ws + 8 * MB);                      // 16MB (8192 x 64 x 8)
  int*   p8j = (int*)(ws + 24 * MB);                       // 16MB
  int*   cand = (int*)(ws + 40 * MB);                      // 256KB

  dim3 wgrid(8, 8);
  split_w_t3<<<wgrid, 256, 0, stream>>>(W1, W1h, W1m, W1l);
  split_w_t3<<<wgrid, 256, 0, stream>>>(W2, W2h, W2m, W2l);

  dim3 ggrid(bs / 128, 4);
  int nslot = (bs / 128) * 2;          // 512
  dim3 rgrid(16, 2);

  gemm_split3<<<ggrid, 256, 0, stream>>>(fea, W1h, W1m, W1l, b1, Y1, partial);
  bn_reduce1<<<rgrid, 256, 0, stream>>>(partial, partial2, nslot);
  bn_finalize<<<2, 256, 0, stream>>>(partial2, g1, beta1, scale, shiftv, bs);
  bn_swish<<<(bs * 512 / 4 + 255) / 256, 256, 0, stream>>>(Y1, scale, shiftv, Y1, bs * 512 / 4);

  gemm_split3<<<ggrid, 256, 0, stream>>>(Y1, W2h, W2m, W2l, b2, Hout, partial);
  bn_reduce1<<<rgrid, 256, 0, stream>>>(partial, partial2, nslot);
  bn_finalize<<<2, 256, 0, stream>>>(partial2, g2, beta2, scale, shiftv, bs);
  bn_swish<<<(bs * 512 / 4 + 255) / 256, 256, 0, stream>>>(Hout, scale, shiftv, Hout, bs * 512 / 4);

  int nb = (bs + 1023) / 1024;         // 32
  pos_count<<<nb, 1024, 0, stream>>>(lbl, bs, cnt, pos, P);
  pos_prefix<<<1, 64, 0, stream>>>(cnt, nb);
  pos_scatter<<<nb, 1024, 0, stream>>>(lbl, bs, cnt, pos, P);
  gather_sq<<<P, 128, 0, stream>>>(Hout, pos, X, Xh, sq);

  int nbk = P / 128;                    // 64
  int ntri = nbk * (nbk + 1) / 2;       // 2080
  gram_sym<<<ntri, 256, 0, stream>>>(Xh, sq, p8v, p8j);
  merge8w<<<(P + 3) / 4, 256, 0, stream>>>(p8v, p8j, cand, P);
  rescore<<<P, 64, 0, stream>>>(X, sq, cand, idx3);

  make_newfea<<<3 * P, 128, 0, stream>>>(X, idx3, lerp_w, newfea);
  write_lbl<<<(n_total + 255) / 256, 256, 0, stream>>>(lbl, lbl_out, bs, n_total);
}